// Round 2
// baseline (1002.141 us; speedup 1.0000x reference)
//
#include <hip/hip_runtime.h>
#include <math.h>

#define SEQ    2048
#define NBTOT  16
#define NCH    32
#define CHL    64            // NCH*CHL == SEQ

__device__ __forceinline__ float silu_(float x) { return x / (1.f + __expf(-x)); }
__device__ __forceinline__ float softplus_(float x) {
  return fmaxf(x, 0.f) + log1pf(__expf(-fabsf(x)));
}
__device__ __forceinline__ float wsum_(float v) {
#pragma unroll
  for (int off = 32; off > 0; off >>= 1) v += __shfl_xor(v, off, 64);
  return v;
}

// ---------------------------------------------------------------------------
// Generic f32 GEMM: C[M,N] = A[M,K] @ W[N,K]^T (+bias)(+res)(relu)
// BM=BN=128, BK=16, 256 threads, 8x8 per thread. M mult of 128; N masked.
// ---------------------------------------------------------------------------
template <bool BIAS, bool RELU, bool RES>
__global__ __launch_bounds__(256) void gemm_f32(
    const float* __restrict__ A, const float* __restrict__ W,
    const float* __restrict__ bias, const float* __restrict__ res,
    float* __restrict__ C, int M, int N, int K) {
  __shared__ __align__(16) float As[16][128];
  __shared__ __align__(16) float Bs[16][128];
  const int tid = threadIdx.x;
  const int tx = tid & 15;
  const int ty = tid >> 4;
  const int m0 = blockIdx.y * 128;
  const int n0 = blockIdx.x * 128;

  float acc[8][8];
#pragma unroll
  for (int i = 0; i < 8; ++i)
#pragma unroll
    for (int j = 0; j < 8; ++j) acc[i][j] = 0.f;

  for (int k0 = 0; k0 < K; k0 += 16) {
#pragma unroll
    for (int it = 0; it < 2; ++it) {
      int q = tid + it * 256;
      int i = q >> 2;
      int j4 = (q & 3) << 2;
      float4 av = *reinterpret_cast<const float4*>(
          &A[(size_t)(m0 + i) * K + k0 + j4]);
      As[j4 + 0][i] = av.x; As[j4 + 1][i] = av.y;
      As[j4 + 2][i] = av.z; As[j4 + 3][i] = av.w;
      float4 bv = make_float4(0.f, 0.f, 0.f, 0.f);
      if (n0 + i < N)
        bv = *reinterpret_cast<const float4*>(
            &W[(size_t)(n0 + i) * K + k0 + j4]);
      Bs[j4 + 0][i] = bv.x; Bs[j4 + 1][i] = bv.y;
      Bs[j4 + 2][i] = bv.z; Bs[j4 + 3][i] = bv.w;
    }
    __syncthreads();
#pragma unroll
    for (int k = 0; k < 16; ++k) {
      const float4* ar = reinterpret_cast<const float4*>(&As[k][0]);
      const float4* br = reinterpret_cast<const float4*>(&Bs[k][0]);
      float4 a0 = ar[ty * 2], a1 = ar[ty * 2 + 1];
      float4 b0 = br[tx * 2], b1 = br[tx * 2 + 1];
      float av[8] = {a0.x, a0.y, a0.z, a0.w, a1.x, a1.y, a1.z, a1.w};
      float bv[8] = {b0.x, b0.y, b0.z, b0.w, b1.x, b1.y, b1.z, b1.w};
#pragma unroll
      for (int i = 0; i < 8; ++i)
#pragma unroll
        for (int j = 0; j < 8; ++j)
          acc[i][j] = fmaf(av[i], bv[j], acc[i][j]);
    }
    __syncthreads();
  }

#pragma unroll
  for (int jq = 0; jq < 2; ++jq) {
    int col = n0 + tx * 8 + jq * 4;
    if (col >= N) continue;
    float4 bq = make_float4(0.f, 0.f, 0.f, 0.f);
    if (BIAS) bq = *reinterpret_cast<const float4*>(&bias[col]);
#pragma unroll
    for (int i = 0; i < 8; ++i) {
      int row = m0 + ty * 8 + i;
      float4 o;
      o.x = acc[i][jq * 4 + 0]; o.y = acc[i][jq * 4 + 1];
      o.z = acc[i][jq * 4 + 2]; o.w = acc[i][jq * 4 + 3];
      if (BIAS) { o.x += bq.x; o.y += bq.y; o.z += bq.z; o.w += bq.w; }
      if (RES) {
        float4 r = *reinterpret_cast<const float4*>(
            &res[(size_t)row * N + col]);
        o.x += r.x; o.y += r.y; o.z += r.z; o.w += r.w;
      }
      if (RELU) {
        o.x = fmaxf(o.x, 0.f); o.y = fmaxf(o.y, 0.f);
        o.z = fmaxf(o.z, 0.f); o.w = fmaxf(o.w, 0.f);
      }
      *reinterpret_cast<float4*>(&C[(size_t)row * N + col]) = o;
    }
  }
}

// ---------------------------------------------------------------------------
// Depthwise causal conv (D_CONV=4) over l + SiLU. xipre,xi: (rows, 512).
// ---------------------------------------------------------------------------
__global__ __launch_bounds__(256) void conv_silu_k(
    const float* __restrict__ xipre, const float* __restrict__ cw,
    const float* __restrict__ cb, float* __restrict__ xi) {
  int idx = blockIdx.x * 256 + threadIdx.x;  // r*512 + c
  int c = idx & 511;
  int r = idx >> 9;
  int l = r & (SEQ - 1);
  float w0 = cw[c * 4 + 0], w1 = cw[c * 4 + 1];
  float w2 = cw[c * 4 + 2], w3 = cw[c * 4 + 3];
  const float* p = xipre + idx;
  float acc = cb[c] + w3 * p[0];
  if (l >= 1) acc = fmaf(w2, p[-512], acc);
  if (l >= 2) acc = fmaf(w1, p[-1024], acc);
  if (l >= 3) acc = fmaf(w0, p[-1536], acc);
  xi[idx] = silu_(acc);
}

// ---------------------------------------------------------------------------
// Chunked selective scan; delta computed inline from xdbl[:, :16] @ Wdt^T.
// pass1: per-(b,d,chunk) partials (h_in=0) -> ap (prod a), hp (partial h)
// pass2: per-(b,d,n) chunk prefix          -> Hc (state entering chunk)
// pass3: replay with correct h_in, emit y = (h.C + u*Dp) * silu(z)
// ---------------------------------------------------------------------------
__global__ __launch_bounds__(512) void scan_p1(
    const float* __restrict__ u, const float* __restrict__ xdbl,
    const float* __restrict__ A_log, const float* __restrict__ wdt,
    const float* __restrict__ bdt, float* __restrict__ ap,
    float* __restrict__ hp) {
  int d = threadIdx.x, c = blockIdx.x, b = blockIdx.y;
  __shared__ float Bsh[CHL][16];
  __shared__ float dtsh[CHL][16];
  int l0 = c * CHL;
  for (int t = threadIdx.x; t < CHL * 16; t += 512) {
    int i = t >> 4, n = t & 15;
    size_t ro = (size_t)(b * SEQ + l0 + i) * 48;
    dtsh[i][n] = xdbl[ro + n];
    Bsh[i][n] = xdbl[ro + 16 + n];
  }
  float A[16], wdtr[16];
  {
    const float4* aq = reinterpret_cast<const float4*>(&A_log[d * 16]);
    const float4* wq = reinterpret_cast<const float4*>(&wdt[d * 16]);
#pragma unroll
    for (int q = 0; q < 4; ++q) {
      float4 v = aq[q];
      A[q * 4 + 0] = -__expf(v.x); A[q * 4 + 1] = -__expf(v.y);
      A[q * 4 + 2] = -__expf(v.z); A[q * 4 + 3] = -__expf(v.w);
      float4 w = wq[q];
      wdtr[q * 4 + 0] = w.x; wdtr[q * 4 + 1] = w.y;
      wdtr[q * 4 + 2] = w.z; wdtr[q * 4 + 3] = w.w;
    }
  }
  float bdtd = bdt[d];
  __syncthreads();
  float h[16], apd[16];
#pragma unroll
  for (int n = 0; n < 16; ++n) { h[n] = 0.f; apd[n] = 1.f; }
  size_t base = (size_t)(b * SEQ + l0) * 512 + d;
  for (int i = 0; i < CHL; ++i) {
    float dl = bdtd;
#pragma unroll
    for (int q = 0; q < 16; ++q) dl = fmaf(dtsh[i][q], wdtr[q], dl);
    dl = softplus_(dl);
    float ul = u[base + (size_t)i * 512];
    float du = dl * ul;
#pragma unroll
    for (int n = 0; n < 16; ++n) {
      float a = __expf(dl * A[n]);
      h[n] = fmaf(a, h[n], du * Bsh[i][n]);
      apd[n] *= a;
    }
  }
  size_t o = ((size_t)((b * NCH + c) * 512) + d) * 16;
  float4* apq = reinterpret_cast<float4*>(ap + o);
  float4* hpq = reinterpret_cast<float4*>(hp + o);
#pragma unroll
  for (int q = 0; q < 4; ++q) {
    apq[q] = make_float4(apd[q*4], apd[q*4+1], apd[q*4+2], apd[q*4+3]);
    hpq[q] = make_float4(h[q*4], h[q*4+1], h[q*4+2], h[q*4+3]);
  }
}

__global__ __launch_bounds__(256) void scan_p2(
    const float* __restrict__ ap, const float* __restrict__ hp,
    float* __restrict__ Hc) {
  int g = blockIdx.x * 256 + threadIdx.x;  // (b_local, d*16+n)
  int b = g >> 13;
  int dn = g & 8191;
  float H = 0.f;
  for (int c = 0; c < NCH; ++c) {
    size_t idx = ((size_t)(b * NCH + c) << 13) + dn;
    Hc[idx] = H;
    H = fmaf(ap[idx], H, hp[idx]);
  }
}

__global__ __launch_bounds__(512) void scan_p3(
    const float* u,  // aliases y (same-thread read-before-write)
    const float* __restrict__ xdbl, const float* __restrict__ A_log,
    const float* __restrict__ wdt, const float* __restrict__ bdt,
    const float* __restrict__ Hc, const float* __restrict__ Dp,
    const float* __restrict__ z, float* y) {
  int d = threadIdx.x, c = blockIdx.x, b = blockIdx.y;
  __shared__ float Bsh[CHL][16];
  __shared__ float Csh[CHL][16];
  __shared__ float dtsh[CHL][16];
  int l0 = c * CHL;
  for (int t = threadIdx.x; t < CHL * 16; t += 512) {
    int i = t >> 4, n = t & 15;
    size_t ro = (size_t)(b * SEQ + l0 + i) * 48;
    dtsh[i][n] = xdbl[ro + n];
    Bsh[i][n] = xdbl[ro + 16 + n];
    Csh[i][n] = xdbl[ro + 32 + n];
  }
  float A[16], h[16], wdtr[16];
  {
    const float4* aq = reinterpret_cast<const float4*>(&A_log[d * 16]);
    const float4* wq = reinterpret_cast<const float4*>(&wdt[d * 16]);
#pragma unroll
    for (int q = 0; q < 4; ++q) {
      float4 v = aq[q];
      A[q * 4 + 0] = -__expf(v.x); A[q * 4 + 1] = -__expf(v.y);
      A[q * 4 + 2] = -__expf(v.z); A[q * 4 + 3] = -__expf(v.w);
      float4 w = wq[q];
      wdtr[q * 4 + 0] = w.x; wdtr[q * 4 + 1] = w.y;
      wdtr[q * 4 + 2] = w.z; wdtr[q * 4 + 3] = w.w;
    }
    size_t o = ((size_t)((b * NCH + c) * 512) + d) * 16;
    const float4* hq = reinterpret_cast<const float4*>(Hc + o);
#pragma unroll
    for (int q = 0; q < 4; ++q) {
      float4 v = hq[q];
      h[q * 4 + 0] = v.x; h[q * 4 + 1] = v.y;
      h[q * 4 + 2] = v.z; h[q * 4 + 3] = v.w;
    }
  }
  float bdtd = bdt[d];
  float Dpd = Dp[d];
  __syncthreads();
  size_t base = (size_t)(b * SEQ + l0) * 512 + d;
  for (int i = 0; i < CHL; ++i) {
    float dl = bdtd;
#pragma unroll
    for (int q = 0; q < 16; ++q) dl = fmaf(dtsh[i][q], wdtr[q], dl);
    dl = softplus_(dl);
    float ul = u[base + (size_t)i * 512];
    float du = dl * ul;
    float yv = 0.f;
#pragma unroll
    for (int n = 0; n < 16; ++n) {
      float a = __expf(dl * A[n]);
      h[n] = fmaf(a, h[n], du * Bsh[i][n]);
      yv = fmaf(h[n], Csh[i][n], yv);
    }
    float zv = z[base + (size_t)i * 512];
    y[base + (size_t)i * 512] = (yv + ul * Dpd) * silu_(zv);
  }
}

// ---------------------------------------------------------------------------
// LayerNorm over rows of 256 (one wave per row, 4 rows per block).
// ---------------------------------------------------------------------------
__global__ __launch_bounds__(256) void ln_k(
    const float* __restrict__ in, const float* __restrict__ g,
    const float* __restrict__ bb, float* __restrict__ out) {
  int row = (blockIdx.x * 256 + threadIdx.x) >> 6;
  int lane = threadIdx.x & 63;
  float4 v = *reinterpret_cast<const float4*>(&in[(size_t)row * 256 + lane * 4]);
  float mu = wsum_(v.x + v.y + v.z + v.w) * (1.f / 256.f);
  float a0 = v.x - mu, a1 = v.y - mu, a2 = v.z - mu, a3 = v.w - mu;
  float var = wsum_(a0 * a0 + a1 * a1 + a2 * a2 + a3 * a3) * (1.f / 256.f);
  float rs = rsqrtf(var + 1e-5f);
  float4 gg = *reinterpret_cast<const float4*>(&g[lane * 4]);
  float4 bq = *reinterpret_cast<const float4*>(&bb[lane * 4]);
  float4 o;
  o.x = a0 * rs * gg.x + bq.x; o.y = a1 * rs * gg.y + bq.y;
  o.z = a2 * rs * gg.z + bq.z; o.w = a3 * rs * gg.w + bq.w;
  *reinterpret_cast<float4*>(&out[(size_t)row * 256 + lane * 4]) = o;
}

// ---------------------------------------------------------------------------
// Final: LN2(t2) -> LN3 -> transpose (d,pn) -> + x_residual -> out.
// Block handles (b_local, nv, half): 32 rows (pn) x 256 (d).
// ---------------------------------------------------------------------------
__global__ __launch_bounds__(256) void final_k(
    const float* __restrict__ t2, const float* __restrict__ g2v,
    const float* __restrict__ b2v, const float* __restrict__ g3v,
    const float* __restrict__ b3v, const float* __restrict__ x,
    float* __restrict__ out) {
  int bx = blockIdx.x;
  int half = bx & 1, nv = (bx >> 1) & 31, b = bx >> 6;
  int wave = threadIdx.x >> 6, lane = threadIdx.x & 63;
  __shared__ float sh[32][257];
  float4 gg2 = *reinterpret_cast<const float4*>(&g2v[lane * 4]);
  float4 bb2 = *reinterpret_cast<const float4*>(&b2v[lane * 4]);
  float4 gg3 = *reinterpret_cast<const float4*>(&g3v[lane * 4]);
  float4 bb3 = *reinterpret_cast<const float4*>(&b3v[lane * 4]);
#pragma unroll
  for (int i = 0; i < 8; ++i) {
    int pn = wave * 8 + i;
    int r = ((b * 32 + nv) << 6) + (half << 5) + pn;
    float4 v = *reinterpret_cast<const float4*>(&t2[(size_t)r * 256 + lane * 4]);
    float mu = wsum_(v.x + v.y + v.z + v.w) * (1.f / 256.f);
    float a0 = v.x - mu, a1 = v.y - mu, a2 = v.z - mu, a3 = v.w - mu;
    float var = wsum_(a0 * a0 + a1 * a1 + a2 * a2 + a3 * a3) * (1.f / 256.f);
    float rs = rsqrtf(var + 1e-5f);
    a0 = a0 * rs * gg2.x + bb2.x; a1 = a1 * rs * gg2.y + bb2.y;
    a2 = a2 * rs * gg2.z + bb2.z; a3 = a3 * rs * gg2.w + bb2.w;
    mu = wsum_(a0 + a1 + a2 + a3) * (1.f / 256.f);
    float c0 = a0 - mu, c1 = a1 - mu, c2 = a2 - mu, c3 = a3 - mu;
    var = wsum_(c0 * c0 + c1 * c1 + c2 * c2 + c3 * c3) * (1.f / 256.f);
    rs = rsqrtf(var + 1e-5f);
    sh[pn][lane * 4 + 0] = c0 * rs * gg3.x + bb3.x;
    sh[pn][lane * 4 + 1] = c1 * rs * gg3.y + bb3.y;
    sh[pn][lane * 4 + 2] = c2 * rs * gg3.z + bb3.z;
    sh[pn][lane * 4 + 3] = c3 * rs * gg3.w + bb3.w;
  }
  __syncthreads();
  int pnl = threadIdx.x & 31;
  int dbase = threadIdx.x >> 5;
  size_t obase = (size_t)((b * 32 + nv) * 256) * 64 + (half << 5) + pnl;
#pragma unroll
  for (int k = 0; k < 32; ++k) {
    int dd = dbase + (k << 3);
    size_t oi = obase + (size_t)dd * 64;
    out[oi] = sh[pnl][dd] + x[oi];
  }
}

// ---------------------------------------------------------------------------
extern "C" void kernel_launch(void* const* d_in, const int* in_sizes, int n_in,
                              void* d_out, int out_size, void* d_ws,
                              size_t ws_size, hipStream_t stream) {
  const float* x    = (const float*)d_in[0];
  const float* w_in = (const float*)d_in[1];
  const float* b_in = (const float*)d_in[2];
  const float* cw   = (const float*)d_in[3];
  const float* cb   = (const float*)d_in[4];
  const float* wx   = (const float*)d_in[5];
  const float* wdt  = (const float*)d_in[6];
  const float* bdt  = (const float*)d_in[7];
  const float* alog = (const float*)d_in[8];
  const float* Dp   = (const float*)d_in[9];
  const float* wout = (const float*)d_in[10];
  const float* g1   = (const float*)d_in[11];
  const float* b1   = (const float*)d_in[12];
  const float* wf1  = (const float*)d_in[13];
  const float* bf1  = (const float*)d_in[14];
  const float* wf2  = (const float*)d_in[15];
  const float* bf2  = (const float*)d_in[16];
  const float* g2   = (const float*)d_in[17];
  const float* b2   = (const float*)d_in[18];
  const float* g3   = (const float*)d_in[19];
  const float* b3   = (const float*)d_in[20];
  float* out = (float*)d_out;

  // Per-batch workspace: xipre(4MB) + z(4MB) + xi(4MB) + xdbl(0.375MB)
  const size_t XIPRE_B = (size_t)SEQ * 512 * 4;     // 4,194,304
  const size_t XDBL_B  = (size_t)SEQ * 48 * 4;      //   393,216
  const size_t PB = 3 * XIPRE_B + XDBL_B;           // 12,976,128
  int nb = (int)(ws_size / PB);
  if (nb < 1) return;           // cannot run (ws too small even for 1 batch)
  if (nb > NBTOT) nb = NBTOT;

  dim3 blk(256);
  for (int b0 = 0; b0 < NBTOT; b0 += nb) {
    int bn = (NBTOT - b0 < nb) ? (NBTOT - b0) : nb;
    char* g = (char*)d_ws;
    float* xipre = (float*)(g);
    float* zb    = (float*)(g + (size_t)bn * XIPRE_B);
    float* xi    = (float*)(g + (size_t)bn * XIPRE_B * 2);
    float* xdbl  = (float*)(g + (size_t)bn * XIPRE_B * 3);
    // scan scratch reuses xipre region after conv (3 x bn x 1 MB <= bn x 4 MB)
    float* ap = xipre;
    float* hp = (float*)(g + (size_t)bn * 1048576);
    float* Hc = (float*)(g + (size_t)bn * 2097152);
    // post-scan reuse:
    float* res  = xipre;                            // bn*2 MB
    float* h1   = (float*)(g + (size_t)bn * 2097152); // bn*2 MB (over Hc)
    float* ffny = zb;                               // bn*4 MB
    float* t2   = xi;                               // bn*2 MB
    const float* xg = x + (size_t)b0 * SEQ * 256;
    float* outg = out + (size_t)b0 * SEQ * 256;
    int M = bn * SEQ;

    // 1. in_proj split halves: xipre = X@Win[0:512]^T, z = X@Win[512:]^T
    gemm_f32<true, false, false><<<dim3(4, bn * 16), blk, 0, stream>>>(
        xg, w_in, b_in, nullptr, xipre, M, 512, 256);
    gemm_f32<true, false, false><<<dim3(4, bn * 16), blk, 0, stream>>>(
        xg, w_in + (size_t)512 * 256, b_in + 512, nullptr, zb, M, 512, 256);
    // 2. depthwise causal conv + SiLU
    conv_silu_k<<<dim3(M * 2), blk, 0, stream>>>(xipre, cw, cb, xi);
    // 3. x_proj: x_dbl = xi @ Wx^T   (N=48, K=512)
    gemm_f32<false, false, false><<<dim3(1, bn * 16), blk, 0, stream>>>(
        xi, wx, nullptr, nullptr, xdbl, M, 48, 512);
    // 4-6. chunked selective scan (y in-place over xi)
    scan_p1<<<dim3(NCH, bn), dim3(512), 0, stream>>>(xi, xdbl, alog, wdt, bdt,
                                                     ap, hp);
    scan_p2<<<dim3(bn * 32), blk, 0, stream>>>(ap, hp, Hc);
    scan_p3<<<dim3(NCH, bn), dim3(512), 0, stream>>>(xi, xdbl, alog, wdt, bdt,
                                                     Hc, Dp, zb, xi);
    // 7. out_proj + residual(x)      (N=256, K=512)
    gemm_f32<false, false, true><<<dim3(2, bn * 16), blk, 0, stream>>>(
        xi, wout, nullptr, xg, res, M, 256, 512);
    // 8. LN1
    ln_k<<<dim3(M / 4), blk, 0, stream>>>(res, g1, b1, h1);
    // 9. ffn1 + relu                 (N=512, K=256)
    gemm_f32<true, true, false><<<dim3(4, bn * 16), blk, 0, stream>>>(
        h1, wf1, bf1, nullptr, ffny, M, 512, 256);
    // 10. ffn2 + bias + residual(h1) (N=256, K=512)
    gemm_f32<true, false, true><<<dim3(2, bn * 16), blk, 0, stream>>>(
        ffny, wf2, bf2, h1, t2, M, 256, 512);
    // 11. LN2 -> LN3 -> transpose -> +x
    final_k<<<dim3(bn * 64), blk, 0, stream>>>(t2, g2, b2, g3, b3, xg, outg);
  }
}

// Round 3
// 500.533 us; speedup vs baseline: 2.0021x; 2.0021x over previous
//
#include <hip/hip_runtime.h>
#include <hip/hip_bf16.h>
#include <math.h>

#define SEQ    2048
#define NBTOT  16
#define NCH    32
#define CHL    64            // NCH*CHL == SEQ

typedef __attribute__((ext_vector_type(8))) __bf16 bf16x8;
typedef __attribute__((ext_vector_type(4))) float f32x4;

#define GLOAD16(gp, lp)                                                   \
  __builtin_amdgcn_global_load_lds(                                       \
      (const __attribute__((address_space(1))) unsigned int*)(gp),        \
      (__attribute__((address_space(3))) unsigned int*)(lp), 16, 0, 0)

__device__ __forceinline__ float silu_(float x) { return x / (1.f + __expf(-x)); }
__device__ __forceinline__ float softplus_(float x) {
  return fmaxf(x, 0.f) + log1pf(__expf(-fabsf(x)));
}
__device__ __forceinline__ float wsum_(float v) {
#pragma unroll
  for (int off = 32; off > 0; off >>= 1) v += __shfl_xor(v, off, 64);
  return v;
}

// ---------------------------------------------------------------------------
// bf16 MFMA GEMM (m97 structure): C[M,N] = A[M,K] @ W[N,K]^T (+bias)(+res)(relu)
// BM=BN=128, BK=64, 256 threads (4 waves, each 64x64 = 4x4 frags of 16x16x32).
// W must have >= gridDim.x*128 rows (zero-padded if N not mult of 128).
// Outputs: f32 C and/or bf16 Cb (both row-stride N, cols >= N masked).
// ---------------------------------------------------------------------------
template <bool BIAS, bool RELU, bool RES, bool F32OUT, bool BF16OUT>
__global__ __launch_bounds__(256) void gemm_bf16(
    const __hip_bfloat16* __restrict__ A, const __hip_bfloat16* __restrict__ W,
    const float* __restrict__ bias, const float* __restrict__ res,
    float* __restrict__ C, __hip_bfloat16* __restrict__ Cb, int N, int K) {
  __shared__ __align__(16) short Als[128 * 64];
  __shared__ __align__(16) short Bls[128 * 64];
  const int tid = threadIdx.x;
  const int lane = tid & 63;
  const int wid = tid >> 6;
  const int m0 = blockIdx.y * 128;
  const int n0 = blockIdx.x * 128;
  const int wm = (wid >> 1) * 64;
  const int wn = (wid & 1) * 64;
  const int lr = lane & 15;
  const int lk = lane >> 4;  // 0..3

  f32x4 acc[4][4];
#pragma unroll
  for (int m = 0; m < 4; ++m)
#pragma unroll
    for (int n = 0; n < 4; ++n) acc[m][n] = (f32x4){0.f, 0.f, 0.f, 0.f};

  // staging: wave w owns rows [w*32, w*32+32); call i stages 8 rows (1 KB).
  const int srow = wid * 32 + (lane >> 3);
  const int scol = (lane & 7) * 8;  // bf16 col
  const __hip_bfloat16* Ag = A + (size_t)(m0 + srow) * K + scol;
  const __hip_bfloat16* Wg = W + (size_t)(n0 + srow) * K + scol;
  short* Alb = Als + wid * 2048;
  short* Blb = Bls + wid * 2048;

  for (int kt = 0; kt < K; kt += 64) {
#pragma unroll
    for (int i = 0; i < 4; ++i) {
      GLOAD16(Ag + (size_t)(i * 8) * K + kt, Alb + i * 512);
      GLOAD16(Wg + (size_t)(i * 8) * K + kt, Blb + i * 512);
    }
    __syncthreads();  // compiler emits vmcnt(0) drain before barrier
    const bf16x8* Af = reinterpret_cast<const bf16x8*>(Als);
    const bf16x8* Bf = reinterpret_cast<const bf16x8*>(Bls);
#pragma unroll
    for (int ks = 0; ks < 2; ++ks) {
      bf16x8 av[4], bv[4];
#pragma unroll
      for (int m = 0; m < 4; ++m)
        av[m] = Af[(wm + m * 16 + lr) * 8 + ks * 4 + lk];
#pragma unroll
      for (int n = 0; n < 4; ++n)
        bv[n] = Bf[(wn + n * 16 + lr) * 8 + ks * 4 + lk];
#pragma unroll
      for (int m = 0; m < 4; ++m)
#pragma unroll
        for (int n = 0; n < 4; ++n)
          acc[m][n] = __builtin_amdgcn_mfma_f32_16x16x32_bf16(
              av[m], bv[n], acc[m][n], 0, 0, 0);
    }
    __syncthreads();
  }

  // epilogue: C/D map col=lane&15, row=(lane>>4)*4+reg (m89-verified)
#pragma unroll
  for (int n = 0; n < 4; ++n) {
    int col = n0 + wn + n * 16 + lr;
    if (col >= N) continue;
    float bval = BIAS ? bias[col] : 0.f;
#pragma unroll
    for (int m = 0; m < 4; ++m) {
      int row0 = m0 + wm + m * 16 + lk * 4;
#pragma unroll
      for (int r = 0; r < 4; ++r) {
        size_t off = (size_t)(row0 + r) * N + col;
        float v = acc[m][n][r];
        if (BIAS) v += bval;
        if (RES) v += res[off];
        if (RELU) v = fmaxf(v, 0.f);
        if (F32OUT) C[off] = v;
        if (BF16OUT) Cb[off] = __float2bfloat16(v);
      }
    }
  }
}

// ---------------------------------------------------------------------------
// f32 -> bf16 cast (4 elems/thread)
// ---------------------------------------------------------------------------
__global__ __launch_bounds__(256) void cast_bf16_k(
    const float* __restrict__ src, __hip_bfloat16* __restrict__ dst, int n4) {
  int i = blockIdx.x * 256 + threadIdx.x;
  if (i >= n4) return;
  float4 v = reinterpret_cast<const float4*>(src)[i];
  union { __hip_bfloat16 h[4]; short4 s4; } u;
  u.h[0] = __float2bfloat16(v.x); u.h[1] = __float2bfloat16(v.y);
  u.h[2] = __float2bfloat16(v.z); u.h[3] = __float2bfloat16(v.w);
  reinterpret_cast<short4*>(dst)[i] = u.s4;
}

// x_proj_w (48x512) -> zero-padded bf16 (128x512)
__global__ __launch_bounds__(256) void pad_wx_k(
    const float* __restrict__ src, __hip_bfloat16* __restrict__ dst) {
  int i = blockIdx.x * 256 + threadIdx.x;  // 16384 quads
  int row = i >> 7;
  union { __hip_bfloat16 h[4]; short4 s4; } u;
  if (row < 48) {
    float4 v = reinterpret_cast<const float4*>(src)[i];
    u.h[0] = __float2bfloat16(v.x); u.h[1] = __float2bfloat16(v.y);
    u.h[2] = __float2bfloat16(v.z); u.h[3] = __float2bfloat16(v.w);
  } else {
    u.h[0] = u.h[1] = u.h[2] = u.h[3] = __float2bfloat16(0.f);
  }
  reinterpret_cast<short4*>(dst)[i] = u.s4;
}

// ---------------------------------------------------------------------------
// Depthwise causal conv (D_CONV=4) + SiLU; in f32, out bf16.
// ---------------------------------------------------------------------------
__global__ __launch_bounds__(256) void conv_silu_k(
    const float* __restrict__ xipre, const float* __restrict__ cw,
    const float* __restrict__ cb, __hip_bfloat16* __restrict__ xi) {
  int idx = blockIdx.x * 256 + threadIdx.x;  // r*512 + c
  int c = idx & 511;
  int r = idx >> 9;
  int l = r & (SEQ - 1);
  float w0 = cw[c * 4 + 0], w1 = cw[c * 4 + 1];
  float w2 = cw[c * 4 + 2], w3 = cw[c * 4 + 3];
  const float* p = xipre + idx;
  float acc = cb[c] + w3 * p[0];
  if (l >= 1) acc = fmaf(w2, p[-512], acc);
  if (l >= 2) acc = fmaf(w1, p[-1024], acc);
  if (l >= 3) acc = fmaf(w0, p[-1536], acc);
  xi[idx] = __float2bfloat16(silu_(acc));
}

// ---------------------------------------------------------------------------
// Chunked selective scan; delta inline from xdbl[:, :16] @ Wdt^T + softplus.
// ---------------------------------------------------------------------------
__global__ __launch_bounds__(512) void scan_p1(
    const __hip_bfloat16* __restrict__ u, const float* __restrict__ xdbl,
    const float* __restrict__ A_log, const float* __restrict__ wdt,
    const float* __restrict__ bdt, float* __restrict__ ap,
    float* __restrict__ hp) {
  int d = threadIdx.x, c = blockIdx.x, b = blockIdx.y;
  __shared__ float Bsh[CHL][16];
  __shared__ float dtsh[CHL][16];
  int l0 = c * CHL;
  for (int t = threadIdx.x; t < CHL * 16; t += 512) {
    int i = t >> 4, n = t & 15;
    size_t ro = (size_t)(b * SEQ + l0 + i) * 48;
    dtsh[i][n] = xdbl[ro + n];
    Bsh[i][n] = xdbl[ro + 16 + n];
  }
  float A[16], wdtr[16];
  {
    const float4* aq = reinterpret_cast<const float4*>(&A_log[d * 16]);
    const float4* wq = reinterpret_cast<const float4*>(&wdt[d * 16]);
#pragma unroll
    for (int q = 0; q < 4; ++q) {
      float4 v = aq[q];
      A[q * 4 + 0] = -__expf(v.x); A[q * 4 + 1] = -__expf(v.y);
      A[q * 4 + 2] = -__expf(v.z); A[q * 4 + 3] = -__expf(v.w);
      float4 w = wq[q];
      wdtr[q * 4 + 0] = w.x; wdtr[q * 4 + 1] = w.y;
      wdtr[q * 4 + 2] = w.z; wdtr[q * 4 + 3] = w.w;
    }
  }
  float bdtd = bdt[d];
  __syncthreads();
  float h[16], apd[16];
#pragma unroll
  for (int n = 0; n < 16; ++n) { h[n] = 0.f; apd[n] = 1.f; }
  size_t base = (size_t)(b * SEQ + l0) * 512 + d;
  for (int i = 0; i < CHL; ++i) {
    float dl = bdtd;
#pragma unroll
    for (int q = 0; q < 16; ++q) dl = fmaf(dtsh[i][q], wdtr[q], dl);
    dl = softplus_(dl);
    float ul = __bfloat162float(u[base + (size_t)i * 512]);
    float du = dl * ul;
#pragma unroll
    for (int n = 0; n < 16; ++n) {
      float a = __expf(dl * A[n]);
      h[n] = fmaf(a, h[n], du * Bsh[i][n]);
      apd[n] *= a;
    }
  }
  size_t o = ((size_t)((b * NCH + c) * 512) + d) * 16;
  float4* apq = reinterpret_cast<float4*>(ap + o);
  float4* hpq = reinterpret_cast<float4*>(hp + o);
#pragma unroll
  for (int q = 0; q < 4; ++q) {
    apq[q] = make_float4(apd[q*4], apd[q*4+1], apd[q*4+2], apd[q*4+3]);
    hpq[q] = make_float4(h[q*4], h[q*4+1], h[q*4+2], h[q*4+3]);
  }
}

__global__ __launch_bounds__(256) void scan_p2(
    const float* __restrict__ ap, const float* __restrict__ hp,
    float* __restrict__ Hc) {
  int g = blockIdx.x * 256 + threadIdx.x;  // (b_local, d*16+n)
  int b = g >> 13;
  int dn = g & 8191;
  float H = 0.f;
  for (int c = 0; c < NCH; ++c) {
    size_t idx = ((size_t)(b * NCH + c) << 13) + dn;
    Hc[idx] = H;
    H = fmaf(ap[idx], H, hp[idx]);
  }
}

__global__ __launch_bounds__(512) void scan_p3(
    const __hip_bfloat16* u,  // aliases y (same-thread read-before-write)
    const float* __restrict__ xdbl, const float* __restrict__ A_log,
    const float* __restrict__ wdt, const float* __restrict__ bdt,
    const float* __restrict__ Hc, const float* __restrict__ Dp,
    const __hip_bfloat16* __restrict__ z, __hip_bfloat16* y) {
  int d = threadIdx.x, c = blockIdx.x, b = blockIdx.y;
  __shared__ float Bsh[CHL][16];
  __shared__ float Csh[CHL][16];
  __shared__ float dtsh[CHL][16];
  int l0 = c * CHL;
  for (int t = threadIdx.x; t < CHL * 16; t += 512) {
    int i = t >> 4, n = t & 15;
    size_t ro = (size_t)(b * SEQ + l0 + i) * 48;
    dtsh[i][n] = xdbl[ro + n];
    Bsh[i][n] = xdbl[ro + 16 + n];
    Csh[i][n] = xdbl[ro + 32 + n];
  }
  float A[16], h[16], wdtr[16];
  {
    const float4* aq = reinterpret_cast<const float4*>(&A_log[d * 16]);
    const float4* wq = reinterpret_cast<const float4*>(&wdt[d * 16]);
#pragma unroll
    for (int q = 0; q < 4; ++q) {
      float4 v = aq[q];
      A[q * 4 + 0] = -__expf(v.x); A[q * 4 + 1] = -__expf(v.y);
      A[q * 4 + 2] = -__expf(v.z); A[q * 4 + 3] = -__expf(v.w);
      float4 w = wq[q];
      wdtr[q * 4 + 0] = w.x; wdtr[q * 4 + 1] = w.y;
      wdtr[q * 4 + 2] = w.z; wdtr[q * 4 + 3] = w.w;
    }
    size_t o = ((size_t)((b * NCH + c) * 512) + d) * 16;
    const float4* hq = reinterpret_cast<const float4*>(Hc + o);
#pragma unroll
    for (int q = 0; q < 4; ++q) {
      float4 v = hq[q];
      h[q * 4 + 0] = v.x; h[q * 4 + 1] = v.y;
      h[q * 4 + 2] = v.z; h[q * 4 + 3] = v.w;
    }
  }
  float bdtd = bdt[d];
  float Dpd = Dp[d];
  __syncthreads();
  size_t base = (size_t)(b * SEQ + l0) * 512 + d;
  for (int i = 0; i < CHL; ++i) {
    float dl = bdtd;
#pragma unroll
    for (int q = 0; q < 16; ++q) dl = fmaf(dtsh[i][q], wdtr[q], dl);
    dl = softplus_(dl);
    float ul = __bfloat162float(u[base + (size_t)i * 512]);
    float du = dl * ul;
    float yv = 0.f;
#pragma unroll
    for (int n = 0; n < 16; ++n) {
      float a = __expf(dl * A[n]);
      h[n] = fmaf(a, h[n], du * Bsh[i][n]);
      yv = fmaf(h[n], Csh[i][n], yv);
    }
    float zv = __bfloat162float(z[base + (size_t)i * 512]);
    y[base + (size_t)i * 512] = __float2bfloat16((yv + ul * Dpd) * silu_(zv));
  }
}

// ---------------------------------------------------------------------------
// LayerNorm rows of 256 (1 wave/row); emits f32 and bf16.
// ---------------------------------------------------------------------------
__global__ __launch_bounds__(256) void ln_k(
    const float* __restrict__ in, const float* __restrict__ g,
    const float* __restrict__ bb, float* __restrict__ out,
    __hip_bfloat16* __restrict__ outb) {
  int row = (blockIdx.x * 256 + threadIdx.x) >> 6;
  int lane = threadIdx.x & 63;
  float4 v = *reinterpret_cast<const float4*>(&in[(size_t)row * 256 + lane * 4]);
  float mu = wsum_(v.x + v.y + v.z + v.w) * (1.f / 256.f);
  float a0 = v.x - mu, a1 = v.y - mu, a2 = v.z - mu, a3 = v.w - mu;
  float var = wsum_(a0 * a0 + a1 * a1 + a2 * a2 + a3 * a3) * (1.f / 256.f);
  float rs = rsqrtf(var + 1e-5f);
  float4 gg = *reinterpret_cast<const float4*>(&g[lane * 4]);
  float4 bq = *reinterpret_cast<const float4*>(&bb[lane * 4]);
  float4 o;
  o.x = a0 * rs * gg.x + bq.x; o.y = a1 * rs * gg.y + bq.y;
  o.z = a2 * rs * gg.z + bq.z; o.w = a3 * rs * gg.w + bq.w;
  *reinterpret_cast<float4*>(&out[(size_t)row * 256 + lane * 4]) = o;
  union { __hip_bfloat16 h[4]; short4 s4; } u;
  u.h[0] = __float2bfloat16(o.x); u.h[1] = __float2bfloat16(o.y);
  u.h[2] = __float2bfloat16(o.z); u.h[3] = __float2bfloat16(o.w);
  reinterpret_cast<short4*>(outb)[row * 64 + lane] = u.s4;
}

// ---------------------------------------------------------------------------
// Final: LN2(t2) -> LN3 -> transpose (d,pn) -> + x_residual -> out.
// ---------------------------------------------------------------------------
__global__ __launch_bounds__(256) void final_k(
    const float* __restrict__ t2, const float* __restrict__ g2v,
    const float* __restrict__ b2v, const float* __restrict__ g3v,
    const float* __restrict__ b3v, const float* __restrict__ x,
    float* __restrict__ out) {
  int bx = blockIdx.x;
  int half = bx & 1, nv = (bx >> 1) & 31, b = bx >> 6;
  int wave = threadIdx.x >> 6, lane = threadIdx.x & 63;
  __shared__ float sh[32][257];
  float4 gg2 = *reinterpret_cast<const float4*>(&g2v[lane * 4]);
  float4 bb2 = *reinterpret_cast<const float4*>(&b2v[lane * 4]);
  float4 gg3 = *reinterpret_cast<const float4*>(&g3v[lane * 4]);
  float4 bb3 = *reinterpret_cast<const float4*>(&b3v[lane * 4]);
#pragma unroll
  for (int i = 0; i < 8; ++i) {
    int pn = wave * 8 + i;
    int r = ((b * 32 + nv) << 6) + (half << 5) + pn;
    float4 v = *reinterpret_cast<const float4*>(&t2[(size_t)r * 256 + lane * 4]);
    float mu = wsum_(v.x + v.y + v.z + v.w) * (1.f / 256.f);
    float a0 = v.x - mu, a1 = v.y - mu, a2 = v.z - mu, a3 = v.w - mu;
    float var = wsum_(a0 * a0 + a1 * a1 + a2 * a2 + a3 * a3) * (1.f / 256.f);
    float rs = rsqrtf(var + 1e-5f);
    a0 = a0 * rs * gg2.x + bb2.x; a1 = a1 * rs * gg2.y + bb2.y;
    a2 = a2 * rs * gg2.z + bb2.z; a3 = a3 * rs * gg2.w + bb2.w;
    mu = wsum_(a0 + a1 + a2 + a3) * (1.f / 256.f);
    float c0 = a0 - mu, c1 = a1 - mu, c2 = a2 - mu, c3 = a3 - mu;
    var = wsum_(c0 * c0 + c1 * c1 + c2 * c2 + c3 * c3) * (1.f / 256.f);
    rs = rsqrtf(var + 1e-5f);
    sh[pn][lane * 4 + 0] = c0 * rs * gg3.x + bb3.x;
    sh[pn][lane * 4 + 1] = c1 * rs * gg3.y + bb3.y;
    sh[pn][lane * 4 + 2] = c2 * rs * gg3.z + bb3.z;
    sh[pn][lane * 4 + 3] = c3 * rs * gg3.w + bb3.w;
  }
  __syncthreads();
  int pnl = threadIdx.x & 31;
  int dbase = threadIdx.x >> 5;
  size_t obase = (size_t)((b * 32 + nv) * 256) * 64 + (half << 5) + pnl;
#pragma unroll
  for (int k = 0; k < 32; ++k) {
    int dd = dbase + (k << 3);
    size_t oi = obase + (size_t)dd * 64;
    out[oi] = sh[pnl][dd] + x[oi];
  }
}

// ---------------------------------------------------------------------------
extern "C" void kernel_launch(void* const* d_in, const int* in_sizes, int n_in,
                              void* d_out, int out_size, void* d_ws,
                              size_t ws_size, hipStream_t stream) {
  const float* x    = (const float*)d_in[0];
  const float* w_in = (const float*)d_in[1];
  const float* b_in = (const float*)d_in[2];
  const float* cw   = (const float*)d_in[3];
  const float* cb   = (const float*)d_in[4];
  const float* wx   = (const float*)d_in[5];
  const float* wdt  = (const float*)d_in[6];
  const float* bdt  = (const float*)d_in[7];
  const float* alog = (const float*)d_in[8];
  const float* Dp   = (const float*)d_in[9];
  const float* wout = (const float*)d_in[10];
  const float* g1   = (const float*)d_in[11];
  const float* b1   = (const float*)d_in[12];
  const float* wf1  = (const float*)d_in[13];
  const float* bf1  = (const float*)d_in[14];
  const float* wf2  = (const float*)d_in[15];
  const float* bf2  = (const float*)d_in[16];
  const float* g2   = (const float*)d_in[17];
  const float* b2   = (const float*)d_in[18];
  const float* g3   = (const float*)d_in[19];
  const float* b3   = (const float*)d_in[20];
  float* out = (float*)d_out;

  const size_t MB1 = 1048576;
  // shared bf16 weights at head of ws
  char* g = (char*)d_ws;
  __hip_bfloat16* wbf_in  = (__hip_bfloat16*)(g);              // 512 KB
  __hip_bfloat16* wbf_out = (__hip_bfloat16*)(g + 524288);     // 256 KB
  __hip_bfloat16* wbf_f1  = (__hip_bfloat16*)(g + 786432);     // 256 KB
  __hip_bfloat16* wbf_f2  = (__hip_bfloat16*)(g + 1048576);    // 256 KB
  __hip_bfloat16* wbf_xp  = (__hip_bfloat16*)(g + 1310720);    // 128 KB
  const size_t SHARED = 1572864;

  // per-batch: xipre f32 4MB | zbf 2MB | xibf 2MB | xdbl 384KB = 8781824 B
  const size_t PB = 4 * MB1 + 2 * MB1 + 2 * MB1 + 393216;
  int nb = (int)((ws_size - SHARED) / PB);
  if (ws_size <= SHARED || nb < 1) return;
  if (nb > NBTOT) nb = NBTOT;

  dim3 blk(256);
  // weight casts (once per launch)
  cast_bf16_k<<<dim3(256), blk, 0, stream>>>(w_in, wbf_in, 65536);
  cast_bf16_k<<<dim3(128), blk, 0, stream>>>(wout, wbf_out, 32768);
  cast_bf16_k<<<dim3(128), blk, 0, stream>>>(wf1, wbf_f1, 32768);
  cast_bf16_k<<<dim3(128), blk, 0, stream>>>(wf2, wbf_f2, 32768);
  pad_wx_k<<<dim3(64), blk, 0, stream>>>(wx, wbf_xp);

  for (int b0 = 0; b0 < NBTOT; b0 += nb) {
    int bn = (NBTOT - b0 < nb) ? (NBTOT - b0) : nb;
    char* base = g + SHARED;
    float* xipre = (float*)(base);                             // [A] bn*4MB
    __hip_bfloat16* zbf  = (__hip_bfloat16*)(base + (size_t)bn * 4 * MB1);  // [B]
    __hip_bfloat16* xibf = (__hip_bfloat16*)(base + (size_t)bn * 6 * MB1);  // [C]
    float* xdbl  = (float*)(base + (size_t)bn * 8 * MB1);      // [E]
    // overlays
    __hip_bfloat16* xbf = xibf;                       // [C+0,bn*1MB) pre-conv
    float* ap = xipre;                                // [A+0, bn*1MB)
    float* hp = (float*)(base + (size_t)bn * 1 * MB1);
    float* Hc = (float*)(base + (size_t)bn * 2 * MB1);
    __hip_bfloat16* ybf = xibf;                       // p3 in-place
    float* res = (float*)(base + (size_t)bn * 4 * MB1);        // [B] post-p3
    float* h1  = xipre;                               // [A+0, bn*2MB) post-ln
    __hip_bfloat16* h1bf = (__hip_bfloat16*)(base + (size_t)bn * 2 * MB1);
    __hip_bfloat16* ffnybf = xibf;                    // [C] post-out_proj
    float* t2  = res;                                 // [B] post-ln (res dead)

    const float* xg = x + (size_t)b0 * SEQ * 256;
    float* outg = out + (size_t)b0 * SEQ * 256;
    int M = bn * SEQ;
    int MT = M / 128;

    // 0. cast x slice -> bf16
    cast_bf16_k<<<dim3(M * 64 / 256), blk, 0, stream>>>(xg, xbf, M * 64);
    // 1. in_proj halves (N=512, K=256): xipre f32 ; z bf16
    gemm_bf16<true, false, false, true, false><<<dim3(4, MT), blk, 0, stream>>>(
        xbf, wbf_in, b_in, nullptr, xipre, nullptr, 512, 256);
    gemm_bf16<true, false, false, false, true><<<dim3(4, MT), blk, 0, stream>>>(
        xbf, wbf_in + (size_t)512 * 256, b_in + 512, nullptr, nullptr, zbf,
        512, 256);
    // 2. depthwise causal conv + SiLU -> bf16
    conv_silu_k<<<dim3(M * 2), blk, 0, stream>>>(xipre, cw, cb, xibf);
    // 3. x_proj (N=48 padded to 128, K=512)
    gemm_bf16<false, false, false, true, false><<<dim3(1, MT), blk, 0, stream>>>(
        xibf, wbf_xp, nullptr, nullptr, xdbl, nullptr, 48, 512);
    // 4-6. chunked selective scan (y bf16 in-place over xibf)
    scan_p1<<<dim3(NCH, bn), dim3(512), 0, stream>>>(xibf, xdbl, alog, wdt,
                                                     bdt, ap, hp);
    scan_p2<<<dim3(bn * 32), blk, 0, stream>>>(ap, hp, Hc);
    scan_p3<<<dim3(NCH, bn), dim3(512), 0, stream>>>(xibf, xdbl, alog, wdt,
                                                     bdt, Hc, Dp, zbf, ybf);
    // 7. out_proj + residual(x) (N=256, K=512) -> res f32
    gemm_bf16<false, false, true, true, false><<<dim3(2, MT), blk, 0, stream>>>(
        ybf, wbf_out, nullptr, xg, res, nullptr, 256, 512);
    // 8. LN1 -> h1 f32 + bf16
    ln_k<<<dim3(M / 4), blk, 0, stream>>>(res, g1, b1, h1, h1bf);
    // 9. ffn1 + relu (N=512, K=256) -> bf16
    gemm_bf16<true, true, false, false, true><<<dim3(4, MT), blk, 0, stream>>>(
        h1bf, wbf_f1, bf1, nullptr, nullptr, ffnybf, 512, 256);
    // 10. ffn2 + bias + residual(h1) (N=256, K=512) -> t2 f32
    gemm_bf16<true, false, true, true, false><<<dim3(2, MT), blk, 0, stream>>>(
        ffnybf, wbf_f2, bf2, h1, t2, nullptr, 256, 512);
    // 11. LN2 -> LN3 -> transpose -> +x
    final_k<<<dim3(bn * 64), blk, 0, stream>>>(t2, g2, b2, g3, b3, xg, outg);
  }
}

// Round 4
// 400.052 us; speedup vs baseline: 2.5050x; 1.2512x over previous
//
#include <hip/hip_runtime.h>
#include <hip/hip_bf16.h>
#include <math.h>

#define SEQ    2048
#define NBTOT  16
#define NCH    32
#define CHL    64            // NCH*CHL == SEQ

#define L2E 1.4426950408889634f

typedef __attribute__((ext_vector_type(8))) __bf16 bf16x8;
typedef __attribute__((ext_vector_type(4))) float f32x4;

#define GLOAD16(gp, lp)                                                   \
  __builtin_amdgcn_global_load_lds(                                       \
      (const __attribute__((address_space(1))) unsigned int*)(gp),        \
      (__attribute__((address_space(3))) unsigned int*)(lp), 16, 0, 0)

__device__ __forceinline__ float exp2_(float x) {
  return __builtin_amdgcn_exp2f(x);
}
__device__ __forceinline__ float silu_(float x) {
  // x * sigmoid(x), native exp2 + rcp
  return x * __builtin_amdgcn_rcpf(1.f + exp2_(-x * L2E));
}
__device__ __forceinline__ float softplus_(float x) {
  // max(x,0) + log(1 + exp(-|x|)), native ops
  return fmaxf(x, 0.f) + __logf(1.f + exp2_(-fabsf(x) * L2E));
}
__device__ __forceinline__ float wsum_(float v) {
#pragma unroll
  for (int off = 32; off > 0; off >>= 1) v += __shfl_xor(v, off, 64);
  return v;
}

// ---------------------------------------------------------------------------
// bf16 MFMA GEMM (m97 structure): C[M,N] = A[M,K] @ W[N,K]^T (+bias)(+res)(relu)
// BM=BN=128, BK=64, 256 threads (4 waves, each 64x64 = 4x4 frags of 16x16x32).
// ---------------------------------------------------------------------------
template <bool BIAS, bool RELU, bool RES, bool F32OUT, bool BF16OUT>
__global__ __launch_bounds__(256) void gemm_bf16(
    const __hip_bfloat16* __restrict__ A, const __hip_bfloat16* __restrict__ W,
    const float* __restrict__ bias, const float* __restrict__ res,
    float* __restrict__ C, __hip_bfloat16* __restrict__ Cb, int N, int K) {
  __shared__ __align__(16) short Als[128 * 64];
  __shared__ __align__(16) short Bls[128 * 64];
  const int tid = threadIdx.x;
  const int lane = tid & 63;
  const int wid = tid >> 6;
  const int m0 = blockIdx.y * 128;
  const int n0 = blockIdx.x * 128;
  const int wm = (wid >> 1) * 64;
  const int wn = (wid & 1) * 64;
  const int lr = lane & 15;
  const int lk = lane >> 4;  // 0..3

  f32x4 acc[4][4];
#pragma unroll
  for (int m = 0; m < 4; ++m)
#pragma unroll
    for (int n = 0; n < 4; ++n) acc[m][n] = (f32x4){0.f, 0.f, 0.f, 0.f};

  const int srow = wid * 32 + (lane >> 3);
  const int scol = (lane & 7) * 8;
  const __hip_bfloat16* Ag = A + (size_t)(m0 + srow) * K + scol;
  const __hip_bfloat16* Wg = W + (size_t)(n0 + srow) * K + scol;
  short* Alb = Als + wid * 2048;
  short* Blb = Bls + wid * 2048;

  for (int kt = 0; kt < K; kt += 64) {
#pragma unroll
    for (int i = 0; i < 4; ++i) {
      GLOAD16(Ag + (size_t)(i * 8) * K + kt, Alb + i * 512);
      GLOAD16(Wg + (size_t)(i * 8) * K + kt, Blb + i * 512);
    }
    __syncthreads();
    const bf16x8* Af = reinterpret_cast<const bf16x8*>(Als);
    const bf16x8* Bf = reinterpret_cast<const bf16x8*>(Bls);
#pragma unroll
    for (int ks = 0; ks < 2; ++ks) {
      bf16x8 av[4], bv[4];
#pragma unroll
      for (int m = 0; m < 4; ++m)
        av[m] = Af[(wm + m * 16 + lr) * 8 + ks * 4 + lk];
#pragma unroll
      for (int n = 0; n < 4; ++n)
        bv[n] = Bf[(wn + n * 16 + lr) * 8 + ks * 4 + lk];
#pragma unroll
      for (int m = 0; m < 4; ++m)
#pragma unroll
        for (int n = 0; n < 4; ++n)
          acc[m][n] = __builtin_amdgcn_mfma_f32_16x16x32_bf16(
              av[m], bv[n], acc[m][n], 0, 0, 0);
    }
    __syncthreads();
  }

#pragma unroll
  for (int n = 0; n < 4; ++n) {
    int col = n0 + wn + n * 16 + lr;
    if (col >= N) continue;
    float bval = BIAS ? bias[col] : 0.f;
#pragma unroll
    for (int m = 0; m < 4; ++m) {
      int row0 = m0 + wm + m * 16 + lk * 4;
#pragma unroll
      for (int r = 0; r < 4; ++r) {
        size_t off = (size_t)(row0 + r) * N + col;
        float v = acc[m][n][r];
        if (BIAS) v += bval;
        if (RES) v += res[off];
        if (RELU) v = fmaxf(v, 0.f);
        if (F32OUT) C[off] = v;
        if (BF16OUT) Cb[off] = __float2bfloat16(v);
      }
    }
  }
}

// ---------------------------------------------------------------------------
__global__ __launch_bounds__(256) void cast_bf16_k(
    const float* __restrict__ src, __hip_bfloat16* __restrict__ dst, int n4) {
  int i = blockIdx.x * 256 + threadIdx.x;
  if (i >= n4) return;
  float4 v = reinterpret_cast<const float4*>(src)[i];
  union { __hip_bfloat16 h[4]; short4 s4; } u;
  u.h[0] = __float2bfloat16(v.x); u.h[1] = __float2bfloat16(v.y);
  u.h[2] = __float2bfloat16(v.z); u.h[3] = __float2bfloat16(v.w);
  reinterpret_cast<short4*>(dst)[i] = u.s4;
}

__global__ __launch_bounds__(256) void pad_wx_k(
    const float* __restrict__ src, __hip_bfloat16* __restrict__ dst) {
  int i = blockIdx.x * 256 + threadIdx.x;
  int row = i >> 7;
  union { __hip_bfloat16 h[4]; short4 s4; } u;
  if (row < 48) {
    float4 v = reinterpret_cast<const float4*>(src)[i];
    u.h[0] = __float2bfloat16(v.x); u.h[1] = __float2bfloat16(v.y);
    u.h[2] = __float2bfloat16(v.z); u.h[3] = __float2bfloat16(v.w);
  } else {
    u.h[0] = u.h[1] = u.h[2] = u.h[3] = __float2bfloat16(0.f);
  }
  reinterpret_cast<short4*>(dst)[i] = u.s4;
}

// ---------------------------------------------------------------------------
__global__ __launch_bounds__(256) void conv_silu_k(
    const float* __restrict__ xipre, const float* __restrict__ cw,
    const float* __restrict__ cb, __hip_bfloat16* __restrict__ xi) {
  int idx = blockIdx.x * 256 + threadIdx.x;
  int c = idx & 511;
  int r = idx >> 9;
  int l = r & (SEQ - 1);
  float w0 = cw[c * 4 + 0], w1 = cw[c * 4 + 1];
  float w2 = cw[c * 4 + 2], w3 = cw[c * 4 + 3];
  const float* p = xipre + idx;
  float acc = cb[c] + w3 * p[0];
  if (l >= 1) acc = fmaf(w2, p[-512], acc);
  if (l >= 2) acc = fmaf(w1, p[-1024], acc);
  if (l >= 3) acc = fmaf(w0, p[-1536], acc);
  xi[idx] = __float2bfloat16(silu_(acc));
}

// ---------------------------------------------------------------------------
// Chunked selective scan.
// p1: computes delta inline (dt dot), writes delta bf16 for p3; partials
//     with h_in=0; ap via exp2(A2 * sum(dl)).
// p2: chunk prefix. p3: replay with h_in, reads precomputed delta.
// ---------------------------------------------------------------------------
__global__ __launch_bounds__(512) void scan_p1(
    const __hip_bfloat16* __restrict__ u, const float* __restrict__ xdbl,
    const float* __restrict__ A_log, const float* __restrict__ wdt,
    const float* __restrict__ bdt, float* __restrict__ ap,
    float* __restrict__ hp, __hip_bfloat16* __restrict__ deltab) {
  int d = threadIdx.x, c = blockIdx.x, b = blockIdx.y;
  __shared__ float Bsh[CHL][16];
  __shared__ float dtsh[CHL][16];
  int l0 = c * CHL;
  for (int t = threadIdx.x; t < CHL * 16; t += 512) {
    int i = t >> 4, n = t & 15;
    size_t ro = (size_t)(b * SEQ + l0 + i) * 48;
    dtsh[i][n] = xdbl[ro + n];
    Bsh[i][n] = xdbl[ro + 16 + n];
  }
  float A2[16], wdtr[16];
  {
    const float4* aq = reinterpret_cast<const float4*>(&A_log[d * 16]);
    const float4* wq = reinterpret_cast<const float4*>(&wdt[d * 16]);
#pragma unroll
    for (int q = 0; q < 4; ++q) {
      float4 v = aq[q];
      A2[q * 4 + 0] = -exp2_(v.x * L2E) * L2E;
      A2[q * 4 + 1] = -exp2_(v.y * L2E) * L2E;
      A2[q * 4 + 2] = -exp2_(v.z * L2E) * L2E;
      A2[q * 4 + 3] = -exp2_(v.w * L2E) * L2E;
      float4 w = wq[q];
      wdtr[q * 4 + 0] = w.x; wdtr[q * 4 + 1] = w.y;
      wdtr[q * 4 + 2] = w.z; wdtr[q * 4 + 3] = w.w;
    }
  }
  float bdtd = bdt[d];
  __syncthreads();
  float h[16];
#pragma unroll
  for (int n = 0; n < 16; ++n) h[n] = 0.f;
  float dlsum = 0.f;
  size_t base = (size_t)(b * SEQ + l0) * 512 + d;
  for (int i = 0; i < CHL; ++i) {
    float dl = bdtd;
    const float4* dt4 = reinterpret_cast<const float4*>(&dtsh[i][0]);
#pragma unroll
    for (int q = 0; q < 4; ++q) {
      float4 t = dt4[q];
      dl = fmaf(t.x, wdtr[q * 4 + 0], dl);
      dl = fmaf(t.y, wdtr[q * 4 + 1], dl);
      dl = fmaf(t.z, wdtr[q * 4 + 2], dl);
      dl = fmaf(t.w, wdtr[q * 4 + 3], dl);
    }
    dl = softplus_(dl);
    deltab[base + (size_t)i * 512] = __float2bfloat16(dl);
    dlsum += dl;
    float ul = __bfloat162float(u[base + (size_t)i * 512]);
    float du = dl * ul;
    const float4* B4 = reinterpret_cast<const float4*>(&Bsh[i][0]);
#pragma unroll
    for (int q = 0; q < 4; ++q) {
      float4 Bv = B4[q];
      h[q*4+0] = fmaf(exp2_(dl * A2[q*4+0]), h[q*4+0], du * Bv.x);
      h[q*4+1] = fmaf(exp2_(dl * A2[q*4+1]), h[q*4+1], du * Bv.y);
      h[q*4+2] = fmaf(exp2_(dl * A2[q*4+2]), h[q*4+2], du * Bv.z);
      h[q*4+3] = fmaf(exp2_(dl * A2[q*4+3]), h[q*4+3], du * Bv.w);
    }
  }
  size_t o = ((size_t)((b * NCH + c) * 512) + d) * 16;
  float4* apq = reinterpret_cast<float4*>(ap + o);
  float4* hpq = reinterpret_cast<float4*>(hp + o);
#pragma unroll
  for (int q = 0; q < 4; ++q) {
    apq[q] = make_float4(exp2_(A2[q*4+0] * dlsum), exp2_(A2[q*4+1] * dlsum),
                         exp2_(A2[q*4+2] * dlsum), exp2_(A2[q*4+3] * dlsum));
    hpq[q] = make_float4(h[q*4], h[q*4+1], h[q*4+2], h[q*4+3]);
  }
}

__global__ __launch_bounds__(256) void scan_p2(
    const float* __restrict__ ap, const float* __restrict__ hp,
    float* __restrict__ Hc) {
  int g = blockIdx.x * 256 + threadIdx.x;
  int b = g >> 13;
  int dn = g & 8191;
  float H = 0.f;
  for (int c = 0; c < NCH; ++c) {
    size_t idx = ((size_t)(b * NCH + c) << 13) + dn;
    float a = ap[idx], p = hp[idx];
    Hc[idx] = H;
    H = fmaf(a, H, p);
  }
}

__global__ __launch_bounds__(512) void scan_p3(
    const __hip_bfloat16* u,  // aliases y (same-thread read-before-write)
    const float* __restrict__ xdbl, const float* __restrict__ A_log,
    const __hip_bfloat16* __restrict__ deltab, const float* __restrict__ Hc,
    const float* __restrict__ Dp, const __hip_bfloat16* __restrict__ z,
    __hip_bfloat16* y) {
  int d = threadIdx.x, c = blockIdx.x, b = blockIdx.y;
  __shared__ float Bsh[CHL][16];
  __shared__ float Csh[CHL][16];
  int l0 = c * CHL;
  for (int t = threadIdx.x; t < CHL * 16; t += 512) {
    int i = t >> 4, n = t & 15;
    size_t ro = (size_t)(b * SEQ + l0 + i) * 48;
    Bsh[i][n] = xdbl[ro + 16 + n];
    Csh[i][n] = xdbl[ro + 32 + n];
  }
  float A2[16], h[16];
  {
    const float4* aq = reinterpret_cast<const float4*>(&A_log[d * 16]);
#pragma unroll
    for (int q = 0; q < 4; ++q) {
      float4 v = aq[q];
      A2[q * 4 + 0] = -exp2_(v.x * L2E) * L2E;
      A2[q * 4 + 1] = -exp2_(v.y * L2E) * L2E;
      A2[q * 4 + 2] = -exp2_(v.z * L2E) * L2E;
      A2[q * 4 + 3] = -exp2_(v.w * L2E) * L2E;
    }
    size_t o = ((size_t)((b * NCH + c) * 512) + d) * 16;
    const float4* hq = reinterpret_cast<const float4*>(Hc + o);
#pragma unroll
    for (int q = 0; q < 4; ++q) {
      float4 v = hq[q];
      h[q * 4 + 0] = v.x; h[q * 4 + 1] = v.y;
      h[q * 4 + 2] = v.z; h[q * 4 + 3] = v.w;
    }
  }
  float Dpd = Dp[d];
  __syncthreads();
  size_t base = (size_t)(b * SEQ + l0) * 512 + d;
  for (int i = 0; i < CHL; ++i) {
    float dl = __bfloat162float(deltab[base + (size_t)i * 512]);
    float ul = __bfloat162float(u[base + (size_t)i * 512]);
    float du = dl * ul;
    float yv = 0.f;
    const float4* B4 = reinterpret_cast<const float4*>(&Bsh[i][0]);
    const float4* C4 = reinterpret_cast<const float4*>(&Csh[i][0]);
#pragma unroll
    for (int q = 0; q < 4; ++q) {
      float4 Bv = B4[q];
      float4 Cv = C4[q];
      h[q*4+0] = fmaf(exp2_(dl * A2[q*4+0]), h[q*4+0], du * Bv.x);
      h[q*4+1] = fmaf(exp2_(dl * A2[q*4+1]), h[q*4+1], du * Bv.y);
      h[q*4+2] = fmaf(exp2_(dl * A2[q*4+2]), h[q*4+2], du * Bv.z);
      h[q*4+3] = fmaf(exp2_(dl * A2[q*4+3]), h[q*4+3], du * Bv.w);
      yv = fmaf(h[q*4+0], Cv.x, yv);
      yv = fmaf(h[q*4+1], Cv.y, yv);
      yv = fmaf(h[q*4+2], Cv.z, yv);
      yv = fmaf(h[q*4+3], Cv.w, yv);
    }
    float zv = __bfloat162float(z[base + (size_t)i * 512]);
    y[base + (size_t)i * 512] =
        __float2bfloat16((yv + ul * Dpd) * silu_(zv));
  }
}

// ---------------------------------------------------------------------------
__global__ __launch_bounds__(256) void ln_k(
    const float* __restrict__ in, const float* __restrict__ g,
    const float* __restrict__ bb, float* __restrict__ out,
    __hip_bfloat16* __restrict__ outb) {
  int row = (blockIdx.x * 256 + threadIdx.x) >> 6;
  int lane = threadIdx.x & 63;
  float4 v = *reinterpret_cast<const float4*>(&in[(size_t)row * 256 + lane * 4]);
  float mu = wsum_(v.x + v.y + v.z + v.w) * (1.f / 256.f);
  float a0 = v.x - mu, a1 = v.y - mu, a2 = v.z - mu, a3 = v.w - mu;
  float var = wsum_(a0 * a0 + a1 * a1 + a2 * a2 + a3 * a3) * (1.f / 256.f);
  float rs = __builtin_amdgcn_rsqf(var + 1e-5f);
  float4 gg = *reinterpret_cast<const float4*>(&g[lane * 4]);
  float4 bq = *reinterpret_cast<const float4*>(&bb[lane * 4]);
  float4 o;
  o.x = a0 * rs * gg.x + bq.x; o.y = a1 * rs * gg.y + bq.y;
  o.z = a2 * rs * gg.z + bq.z; o.w = a3 * rs * gg.w + bq.w;
  *reinterpret_cast<float4*>(&out[(size_t)row * 256 + lane * 4]) = o;
  union { __hip_bfloat16 h[4]; short4 s4; } u;
  u.h[0] = __float2bfloat16(o.x); u.h[1] = __float2bfloat16(o.y);
  u.h[2] = __float2bfloat16(o.z); u.h[3] = __float2bfloat16(o.w);
  reinterpret_cast<short4*>(outb)[row * 64 + lane] = u.s4;
}

// ---------------------------------------------------------------------------
__global__ __launch_bounds__(256) void final_k(
    const float* __restrict__ t2, const float* __restrict__ g2v,
    const float* __restrict__ b2v, const float* __restrict__ g3v,
    const float* __restrict__ b3v, const float* __restrict__ x,
    float* __restrict__ out) {
  int bx = blockIdx.x;
  int half = bx & 1, nv = (bx >> 1) & 31, b = bx >> 6;
  int wave = threadIdx.x >> 6, lane = threadIdx.x & 63;
  __shared__ float sh[32][257];
  float4 gg2 = *reinterpret_cast<const float4*>(&g2v[lane * 4]);
  float4 bb2 = *reinterpret_cast<const float4*>(&b2v[lane * 4]);
  float4 gg3 = *reinterpret_cast<const float4*>(&g3v[lane * 4]);
  float4 bb3 = *reinterpret_cast<const float4*>(&b3v[lane * 4]);
#pragma unroll
  for (int i = 0; i < 8; ++i) {
    int pn = wave * 8 + i;
    int r = ((b * 32 + nv) << 6) + (half << 5) + pn;
    float4 v = *reinterpret_cast<const float4*>(&t2[(size_t)r * 256 + lane * 4]);
    float mu = wsum_(v.x + v.y + v.z + v.w) * (1.f / 256.f);
    float a0 = v.x - mu, a1 = v.y - mu, a2 = v.z - mu, a3 = v.w - mu;
    float var = wsum_(a0 * a0 + a1 * a1 + a2 * a2 + a3 * a3) * (1.f / 256.f);
    float rs = __builtin_amdgcn_rsqf(var + 1e-5f);
    a0 = a0 * rs * gg2.x + bb2.x; a1 = a1 * rs * gg2.y + bb2.y;
    a2 = a2 * rs * gg2.z + bb2.z; a3 = a3 * rs * gg2.w + bb2.w;
    mu = wsum_(a0 + a1 + a2 + a3) * (1.f / 256.f);
    float c0 = a0 - mu, c1 = a1 - mu, c2 = a2 - mu, c3 = a3 - mu;
    var = wsum_(c0 * c0 + c1 * c1 + c2 * c2 + c3 * c3) * (1.f / 256.f);
    rs = __builtin_amdgcn_rsqf(var + 1e-5f);
    sh[pn][lane * 4 + 0] = c0 * rs * gg3.x + bb3.x;
    sh[pn][lane * 4 + 1] = c1 * rs * gg3.y + bb3.y;
    sh[pn][lane * 4 + 2] = c2 * rs * gg3.z + bb3.z;
    sh[pn][lane * 4 + 3] = c3 * rs * gg3.w + bb3.w;
  }
  __syncthreads();
  int pnl = threadIdx.x & 31;
  int dbase = threadIdx.x >> 5;
  size_t obase = (size_t)((b * 32 + nv) * 256) * 64 + (half << 5) + pnl;
#pragma unroll
  for (int k = 0; k < 32; ++k) {
    int dd = dbase + (k << 3);
    size_t oi = obase + (size_t)dd * 64;
    out[oi] = sh[pnl][dd] + x[oi];
  }
}

// ---------------------------------------------------------------------------
extern "C" void kernel_launch(void* const* d_in, const int* in_sizes, int n_in,
                              void* d_out, int out_size, void* d_ws,
                              size_t ws_size, hipStream_t stream) {
  const float* x    = (const float*)d_in[0];
  const float* w_in = (const float*)d_in[1];
  const float* b_in = (const float*)d_in[2];
  const float* cw   = (const float*)d_in[3];
  const float* cb   = (const float*)d_in[4];
  const float* wx   = (const float*)d_in[5];
  const float* wdt  = (const float*)d_in[6];
  const float* bdt  = (const float*)d_in[7];
  const float* alog = (const float*)d_in[8];
  const float* Dp   = (const float*)d_in[9];
  const float* wout = (const float*)d_in[10];
  const float* g1   = (const float*)d_in[11];
  const float* b1   = (const float*)d_in[12];
  const float* wf1  = (const float*)d_in[13];
  const float* bf1  = (const float*)d_in[14];
  const float* wf2  = (const float*)d_in[15];
  const float* bf2  = (const float*)d_in[16];
  const float* g2   = (const float*)d_in[17];
  const float* b2   = (const float*)d_in[18];
  const float* g3   = (const float*)d_in[19];
  const float* b3   = (const float*)d_in[20];
  float* out = (float*)d_out;

  const size_t MB1 = 1048576;
  char* g = (char*)d_ws;
  __hip_bfloat16* wbf_in  = (__hip_bfloat16*)(g);              // 512 KB
  __hip_bfloat16* wbf_out = (__hip_bfloat16*)(g + 524288);     // 256 KB
  __hip_bfloat16* wbf_f1  = (__hip_bfloat16*)(g + 786432);     // 256 KB
  __hip_bfloat16* wbf_f2  = (__hip_bfloat16*)(g + 1048576);    // 256 KB
  __hip_bfloat16* wbf_xp  = (__hip_bfloat16*)(g + 1310720);    // 128 KB
  const size_t SHARED = 1572864;

  // per-batch: xipre 4MB | zbf 2MB | xibf 2MB | xdbl 384KB | delta 2MB
  const size_t PB = 4 * MB1 + 2 * MB1 + 2 * MB1 + 393216 + 2 * MB1;
  int nb = (int)((ws_size - SHARED) / PB);
  if (ws_size <= SHARED || nb < 1) return;
  if (nb > NBTOT) nb = NBTOT;

  dim3 blk(256);
  cast_bf16_k<<<dim3(256), blk, 0, stream>>>(w_in, wbf_in, 65536);
  cast_bf16_k<<<dim3(128), blk, 0, stream>>>(wout, wbf_out, 32768);
  cast_bf16_k<<<dim3(128), blk, 0, stream>>>(wf1, wbf_f1, 32768);
  cast_bf16_k<<<dim3(128), blk, 0, stream>>>(wf2, wbf_f2, 32768);
  pad_wx_k<<<dim3(64), blk, 0, stream>>>(wx, wbf_xp);

  for (int b0 = 0; b0 < NBTOT; b0 += nb) {
    int bn = (NBTOT - b0 < nb) ? (NBTOT - b0) : nb;
    char* base = g + SHARED;
    float* xipre = (float*)(base);                                       // [A]
    __hip_bfloat16* zbf  = (__hip_bfloat16*)(base + (size_t)bn * 4 * MB1);
    __hip_bfloat16* xibf = (__hip_bfloat16*)(base + (size_t)bn * 6 * MB1);
    float* xdbl  = (float*)(base + (size_t)bn * 8 * MB1);
    __hip_bfloat16* deltab =
        (__hip_bfloat16*)(base + (size_t)bn * 8 * MB1 + (size_t)bn * 393216);
    // overlays
    __hip_bfloat16* xbf = xibf;
    float* ap = xipre;
    float* hp = (float*)(base + (size_t)bn * 1 * MB1);
    float* Hc = (float*)(base + (size_t)bn * 2 * MB1);
    __hip_bfloat16* ybf = xibf;
    float* res = (float*)(base + (size_t)bn * 4 * MB1);
    float* h1  = xipre;
    __hip_bfloat16* h1bf = (__hip_bfloat16*)(base + (size_t)bn * 2 * MB1);
    __hip_bfloat16* ffnybf = xibf;
    float* t2  = res;

    const float* xg = x + (size_t)b0 * SEQ * 256;
    float* outg = out + (size_t)b0 * SEQ * 256;
    int M = bn * SEQ;
    int MT = M / 128;

    cast_bf16_k<<<dim3(M * 64 / 256), blk, 0, stream>>>(xg, xbf, M * 64);
    gemm_bf16<true, false, false, true, false><<<dim3(4, MT), blk, 0, stream>>>(
        xbf, wbf_in, b_in, nullptr, xipre, nullptr, 512, 256);
    gemm_bf16<true, false, false, false, true><<<dim3(4, MT), blk, 0, stream>>>(
        xbf, wbf_in + (size_t)512 * 256, b_in + 512, nullptr, nullptr, zbf,
        512, 256);
    conv_silu_k<<<dim3(M * 2), blk, 0, stream>>>(xipre, cw, cb, xibf);
    gemm_bf16<false, false, false, true, false><<<dim3(1, MT), blk, 0, stream>>>(
        xibf, wbf_xp, nullptr, nullptr, xdbl, nullptr, 48, 512);
    scan_p1<<<dim3(NCH, bn), dim3(512), 0, stream>>>(xibf, xdbl, alog, wdt,
                                                     bdt, ap, hp, deltab);
    scan_p2<<<dim3(bn * 32), blk, 0, stream>>>(ap, hp, Hc);
    scan_p3<<<dim3(NCH, bn), dim3(512), 0, stream>>>(xibf, xdbl, alog, deltab,
                                                     Hc, Dp, zbf, ybf);
    gemm_bf16<false, false, true, true, false><<<dim3(2, MT), blk, 0, stream>>>(
        ybf, wbf_out, nullptr, xg, res, nullptr, 256, 512);
    ln_k<<<dim3(M / 4), blk, 0, stream>>>(res, g1, b1, h1, h1bf);
    gemm_bf16<true, true, false, false, true><<<dim3(4, MT), blk, 0, stream>>>(
        h1bf, wbf_f1, bf1, nullptr, nullptr, ffnybf, 512, 256);
    gemm_bf16<true, false, true, true, false><<<dim3(2, MT), blk, 0, stream>>>(
        ffnybf, wbf_f2, bf2, h1, t2, nullptr, 256, 512);
    final_k<<<dim3(bn * 64), blk, 0, stream>>>(t2, g2, b2, g3, b3, xg, outg);
  }
}

// Round 5
// 367.300 us; speedup vs baseline: 2.7284x; 1.0892x over previous
//
#include <hip/hip_runtime.h>
#include <hip/hip_bf16.h>
#include <math.h>

#define SEQ    2048
#define NBTOT  16
#define NCH    32
#define CHL    64            // NCH*CHL == SEQ

#define L2E 1.4426950408889634f

typedef __attribute__((ext_vector_type(8))) __bf16 bf16x8;
typedef __attribute__((ext_vector_type(4))) float f32x4;

#define GLOAD16(gp, lp)                                                   \
  __builtin_amdgcn_global_load_lds(                                       \
      (const __attribute__((address_space(1))) unsigned int*)(gp),        \
      (__attribute__((address_space(3))) unsigned int*)(lp), 16, 0, 0)

__device__ __forceinline__ float exp2_(float x) {
  return __builtin_amdgcn_exp2f(x);
}
__device__ __forceinline__ float silu_(float x) {
  return x * __builtin_amdgcn_rcpf(1.f + exp2_(-x * L2E));
}
__device__ __forceinline__ float softplus_(float x) {
  return fmaxf(x, 0.f) + __logf(1.f + exp2_(-fabsf(x) * L2E));
}
__device__ __forceinline__ float wsum_(float v) {
#pragma unroll
  for (int off = 32; off > 0; off >>= 1) v += __shfl_xor(v, off, 64);
  return v;
}

// ---------------------------------------------------------------------------
// bf16 MFMA GEMM (m97 structure): C[M,N] = A[M,K] @ W[N,K]^T (+bias)(+res)(relu)
// BM=BN=128, BK=64, 256 threads (4 waves, each 64x64 = 4x4 frags of 16x16x32).
// ---------------------------------------------------------------------------
template <bool BIAS, bool RELU, bool RES, bool F32OUT, bool BF16OUT>
__global__ __launch_bounds__(256) void gemm_bf16(
    const __hip_bfloat16* __restrict__ A, const __hip_bfloat16* __restrict__ W,
    const float* __restrict__ bias, const float* __restrict__ res,
    float* __restrict__ C, __hip_bfloat16* __restrict__ Cb, int N, int K) {
  __shared__ __align__(16) short Als[128 * 64];
  __shared__ __align__(16) short Bls[128 * 64];
  const int tid = threadIdx.x;
  const int lane = tid & 63;
  const int wid = tid >> 6;
  const int m0 = blockIdx.y * 128;
  const int n0 = blockIdx.x * 128;
  const int wm = (wid >> 1) * 64;
  const int wn = (wid & 1) * 64;
  const int lr = lane & 15;
  const int lk = lane >> 4;  // 0..3

  f32x4 acc[4][4];
#pragma unroll
  for (int m = 0; m < 4; ++m)
#pragma unroll
    for (int n = 0; n < 4; ++n) acc[m][n] = (f32x4){0.f, 0.f, 0.f, 0.f};

  const int srow = wid * 32 + (lane >> 3);
  const int scol = (lane & 7) * 8;
  const __hip_bfloat16* Ag = A + (size_t)(m0 + srow) * K + scol;
  const __hip_bfloat16* Wg = W + (size_t)(n0 + srow) * K + scol;
  short* Alb = Als + wid * 2048;
  short* Blb = Bls + wid * 2048;

  for (int kt = 0; kt < K; kt += 64) {
#pragma unroll
    for (int i = 0; i < 4; ++i) {
      GLOAD16(Ag + (size_t)(i * 8) * K + kt, Alb + i * 512);
      GLOAD16(Wg + (size_t)(i * 8) * K + kt, Blb + i * 512);
    }
    __syncthreads();
    const bf16x8* Af = reinterpret_cast<const bf16x8*>(Als);
    const bf16x8* Bf = reinterpret_cast<const bf16x8*>(Bls);
#pragma unroll
    for (int ks = 0; ks < 2; ++ks) {
      bf16x8 av[4], bv[4];
#pragma unroll
      for (int m = 0; m < 4; ++m)
        av[m] = Af[(wm + m * 16 + lr) * 8 + ks * 4 + lk];
#pragma unroll
      for (int n = 0; n < 4; ++n)
        bv[n] = Bf[(wn + n * 16 + lr) * 8 + ks * 4 + lk];
#pragma unroll
      for (int m = 0; m < 4; ++m)
#pragma unroll
        for (int n = 0; n < 4; ++n)
          acc[m][n] = __builtin_amdgcn_mfma_f32_16x16x32_bf16(
              av[m], bv[n], acc[m][n], 0, 0, 0);
    }
    __syncthreads();
  }

#pragma unroll
  for (int n = 0; n < 4; ++n) {
    int col = n0 + wn + n * 16 + lr;
    if (col >= N) continue;
    float bval = BIAS ? bias[col] : 0.f;
#pragma unroll
    for (int m = 0; m < 4; ++m) {
      int row0 = m0 + wm + m * 16 + lk * 4;
#pragma unroll
      for (int r = 0; r < 4; ++r) {
        size_t off = (size_t)(row0 + r) * N + col;
        float v = acc[m][n][r];
        if (BIAS) v += bval;
        if (RES) v += res[off];
        if (RELU) v = fmaxf(v, 0.f);
        if (F32OUT) C[off] = v;
        if (BF16OUT) Cb[off] = __float2bfloat16(v);
      }
    }
  }
}

// ---------------------------------------------------------------------------
__global__ __launch_bounds__(256) void cast_bf16_k(
    const float* __restrict__ src, __hip_bfloat16* __restrict__ dst, int n4) {
  int i = blockIdx.x * 256 + threadIdx.x;
  if (i >= n4) return;
  float4 v = reinterpret_cast<const float4*>(src)[i];
  union { __hip_bfloat16 h[4]; short4 s4; } u;
  u.h[0] = __float2bfloat16(v.x); u.h[1] = __float2bfloat16(v.y);
  u.h[2] = __float2bfloat16(v.z); u.h[3] = __float2bfloat16(v.w);
  reinterpret_cast<short4*>(dst)[i] = u.s4;
}

__global__ __launch_bounds__(256) void pad_wx_k(
    const float* __restrict__ src, __hip_bfloat16* __restrict__ dst) {
  int i = blockIdx.x * 256 + threadIdx.x;
  int row = i >> 7;
  union { __hip_bfloat16 h[4]; short4 s4; } u;
  if (row < 48) {
    float4 v = reinterpret_cast<const float4*>(src)[i];
    u.h[0] = __float2bfloat16(v.x); u.h[1] = __float2bfloat16(v.y);
    u.h[2] = __float2bfloat16(v.z); u.h[3] = __float2bfloat16(v.w);
  } else {
    u.h[0] = u.h[1] = u.h[2] = u.h[3] = __float2bfloat16(0.f);
  }
  reinterpret_cast<short4*>(dst)[i] = u.s4;
}

// ---------------------------------------------------------------------------
// Vectorized depthwise causal conv (D_CONV=4) + SiLU, bf16 in/out.
// One thread = 8 channels of one row; wave = one row (uniform masking).
// ---------------------------------------------------------------------------
__global__ __launch_bounds__(256) void conv_silu_k(
    const __hip_bfloat16* __restrict__ xipre, const float* __restrict__ cw,
    const float* __restrict__ cb, __hip_bfloat16* __restrict__ xi) {
  int idx = blockIdx.x * 256 + threadIdx.x;  // r*64 + t
  int t = idx & 63;
  int r = idx >> 6;
  int l = r & (SEQ - 1);
  int c8 = t << 3;
  const __hip_bfloat16* p = xipre + (size_t)r * 512 + c8;
  union U8 { int4 v; __hip_bfloat16 h[8]; } x0, x1, x2, x3, o;
  const int4 z4 = make_int4(0, 0, 0, 0);
  x3.v = *reinterpret_cast<const int4*>(p);
  x2.v = (l >= 1) ? *reinterpret_cast<const int4*>(p - 512) : z4;
  x1.v = (l >= 2) ? *reinterpret_cast<const int4*>(p - 1024) : z4;
  x0.v = (l >= 3) ? *reinterpret_cast<const int4*>(p - 1536) : z4;
  const float4* cw4 = reinterpret_cast<const float4*>(cw);
#pragma unroll
  for (int j = 0; j < 8; ++j) {
    float4 w = cw4[c8 + j];
    float acc = cb[c8 + j];
    acc = fmaf(w.x, __bfloat162float(x0.h[j]), acc);
    acc = fmaf(w.y, __bfloat162float(x1.h[j]), acc);
    acc = fmaf(w.z, __bfloat162float(x2.h[j]), acc);
    acc = fmaf(w.w, __bfloat162float(x3.h[j]), acc);
    o.h[j] = __float2bfloat16(silu_(acc));
  }
  reinterpret_cast<int4*>(xi)[idx] = o.v;
}

// ---------------------------------------------------------------------------
// Chunked selective scan.
// ---------------------------------------------------------------------------
__global__ __launch_bounds__(512) void scan_p1(
    const __hip_bfloat16* __restrict__ u, const float* __restrict__ xdbl,
    const float* __restrict__ A_log, const float* __restrict__ wdt,
    const float* __restrict__ bdt, float* __restrict__ ap,
    float* __restrict__ hp, __hip_bfloat16* __restrict__ deltab) {
  int d = threadIdx.x, c = blockIdx.x, b = blockIdx.y;
  __shared__ float Bsh[CHL][16];
  __shared__ float dtsh[CHL][16];
  int l0 = c * CHL;
  for (int t = threadIdx.x; t < CHL * 16; t += 512) {
    int i = t >> 4, n = t & 15;
    size_t ro = (size_t)(b * SEQ + l0 + i) * 48;
    dtsh[i][n] = xdbl[ro + n];
    Bsh[i][n] = xdbl[ro + 16 + n];
  }
  float A2[16], wdtr[16];
  {
    const float4* aq = reinterpret_cast<const float4*>(&A_log[d * 16]);
    const float4* wq = reinterpret_cast<const float4*>(&wdt[d * 16]);
#pragma unroll
    for (int q = 0; q < 4; ++q) {
      float4 v = aq[q];
      A2[q * 4 + 0] = -exp2_(v.x * L2E) * L2E;
      A2[q * 4 + 1] = -exp2_(v.y * L2E) * L2E;
      A2[q * 4 + 2] = -exp2_(v.z * L2E) * L2E;
      A2[q * 4 + 3] = -exp2_(v.w * L2E) * L2E;
      float4 w = wq[q];
      wdtr[q * 4 + 0] = w.x; wdtr[q * 4 + 1] = w.y;
      wdtr[q * 4 + 2] = w.z; wdtr[q * 4 + 3] = w.w;
    }
  }
  float bdtd = bdt[d];
  __syncthreads();
  float h[16];
#pragma unroll
  for (int n = 0; n < 16; ++n) h[n] = 0.f;
  float dlsum = 0.f;
  size_t base = (size_t)(b * SEQ + l0) * 512 + d;
  for (int i = 0; i < CHL; ++i) {
    float dl = bdtd;
    const float4* dt4 = reinterpret_cast<const float4*>(&dtsh[i][0]);
#pragma unroll
    for (int q = 0; q < 4; ++q) {
      float4 t = dt4[q];
      dl = fmaf(t.x, wdtr[q * 4 + 0], dl);
      dl = fmaf(t.y, wdtr[q * 4 + 1], dl);
      dl = fmaf(t.z, wdtr[q * 4 + 2], dl);
      dl = fmaf(t.w, wdtr[q * 4 + 3], dl);
    }
    dl = softplus_(dl);
    deltab[base + (size_t)i * 512] = __float2bfloat16(dl);
    dlsum += dl;
    float ul = __bfloat162float(u[base + (size_t)i * 512]);
    float du = dl * ul;
    const float4* B4 = reinterpret_cast<const float4*>(&Bsh[i][0]);
#pragma unroll
    for (int q = 0; q < 4; ++q) {
      float4 Bv = B4[q];
      h[q*4+0] = fmaf(exp2_(dl * A2[q*4+0]), h[q*4+0], du * Bv.x);
      h[q*4+1] = fmaf(exp2_(dl * A2[q*4+1]), h[q*4+1], du * Bv.y);
      h[q*4+2] = fmaf(exp2_(dl * A2[q*4+2]), h[q*4+2], du * Bv.z);
      h[q*4+3] = fmaf(exp2_(dl * A2[q*4+3]), h[q*4+3], du * Bv.w);
    }
  }
  size_t o = ((size_t)((b * NCH + c) * 512) + d) * 16;
  float4* apq = reinterpret_cast<float4*>(ap + o);
  float4* hpq = reinterpret_cast<float4*>(hp + o);
#pragma unroll
  for (int q = 0; q < 4; ++q) {
    apq[q] = make_float4(exp2_(A2[q*4+0] * dlsum), exp2_(A2[q*4+1] * dlsum),
                         exp2_(A2[q*4+2] * dlsum), exp2_(A2[q*4+3] * dlsum));
    hpq[q] = make_float4(h[q*4], h[q*4+1], h[q*4+2], h[q*4+3]);
  }
}

__global__ __launch_bounds__(256) void scan_p2(
    const float* __restrict__ ap, const float* __restrict__ hp,
    float* __restrict__ Hc) {
  int g = blockIdx.x * 256 + threadIdx.x;
  int b = g >> 13;
  int dn = g & 8191;
  float H = 0.f;
  for (int c = 0; c < NCH; ++c) {
    size_t idx = ((size_t)(b * NCH + c) << 13) + dn;
    float a = ap[idx], p = hp[idx];
    Hc[idx] = H;
    H = fmaf(a, H, p);
  }
}

__global__ __launch_bounds__(512) void scan_p3(
    const __hip_bfloat16* u,  // aliases y (same-thread read-before-write)
    const float* __restrict__ xdbl, const float* __restrict__ A_log,
    const __hip_bfloat16* __restrict__ deltab, const float* __restrict__ Hc,
    const float* __restrict__ Dp, const __hip_bfloat16* __restrict__ z,
    __hip_bfloat16* y) {
  int d = threadIdx.x, c = blockIdx.x, b = blockIdx.y;
  __shared__ float Bsh[CHL][16];
  __shared__ float Csh[CHL][16];
  int l0 = c * CHL;
  for (int t = threadIdx.x; t < CHL * 16; t += 512) {
    int i = t >> 4, n = t & 15;
    size_t ro = (size_t)(b * SEQ + l0 + i) * 48;
    Bsh[i][n] = xdbl[ro + 16 + n];
    Csh[i][n] = xdbl[ro + 32 + n];
  }
  float A2[16], h[16];
  {
    const float4* aq = reinterpret_cast<const float4*>(&A_log[d * 16]);
#pragma unroll
    for (int q = 0; q < 4; ++q) {
      float4 v = aq[q];
      A2[q * 4 + 0] = -exp2_(v.x * L2E) * L2E;
      A2[q * 4 + 1] = -exp2_(v.y * L2E) * L2E;
      A2[q * 4 + 2] = -exp2_(v.z * L2E) * L2E;
      A2[q * 4 + 3] = -exp2_(v.w * L2E) * L2E;
    }
    size_t o = ((size_t)((b * NCH + c) * 512) + d) * 16;
    const float4* hq = reinterpret_cast<const float4*>(Hc + o);
#pragma unroll
    for (int q = 0; q < 4; ++q) {
      float4 v = hq[q];
      h[q * 4 + 0] = v.x; h[q * 4 + 1] = v.y;
      h[q * 4 + 2] = v.z; h[q * 4 + 3] = v.w;
    }
  }
  float Dpd = Dp[d];
  __syncthreads();
  size_t base = (size_t)(b * SEQ + l0) * 512 + d;
  for (int i = 0; i < CHL; ++i) {
    float dl = __bfloat162float(deltab[base + (size_t)i * 512]);
    float ul = __bfloat162float(u[base + (size_t)i * 512]);
    float du = dl * ul;
    float yv = 0.f;
    const float4* B4 = reinterpret_cast<const float4*>(&Bsh[i][0]);
    const float4* C4 = reinterpret_cast<const float4*>(&Csh[i][0]);
#pragma unroll
    for (int q = 0; q < 4; ++q) {
      float4 Bv = B4[q];
      float4 Cv = C4[q];
      h[q*4+0] = fmaf(exp2_(dl * A2[q*4+0]), h[q*4+0], du * Bv.x);
      h[q*4+1] = fmaf(exp2_(dl * A2[q*4+1]), h[q*4+1], du * Bv.y);
      h[q*4+2] = fmaf(exp2_(dl * A2[q*4+2]), h[q*4+2], du * Bv.z);
      h[q*4+3] = fmaf(exp2_(dl * A2[q*4+3]), h[q*4+3], du * Bv.w);
      yv = fmaf(h[q*4+0], Cv.x, yv);
      yv = fmaf(h[q*4+1], Cv.y, yv);
      yv = fmaf(h[q*4+2], Cv.z, yv);
      yv = fmaf(h[q*4+3], Cv.w, yv);
    }
    float zv = __bfloat162float(z[base + (size_t)i * 512]);
    y[base + (size_t)i * 512] =
        __float2bfloat16((yv + ul * Dpd) * silu_(zv));
  }
}

// ---------------------------------------------------------------------------
__global__ __launch_bounds__(256) void ln_k(
    const float* __restrict__ in, const float* __restrict__ g,
    const float* __restrict__ bb, float* __restrict__ out,
    __hip_bfloat16* __restrict__ outb) {
  int row = (blockIdx.x * 256 + threadIdx.x) >> 6;
  int lane = threadIdx.x & 63;
  float4 v = *reinterpret_cast<const float4*>(&in[(size_t)row * 256 + lane * 4]);
  float mu = wsum_(v.x + v.y + v.z + v.w) * (1.f / 256.f);
  float a0 = v.x - mu, a1 = v.y - mu, a2 = v.z - mu, a3 = v.w - mu;
  float var = wsum_(a0 * a0 + a1 * a1 + a2 * a2 + a3 * a3) * (1.f / 256.f);
  float rs = __builtin_amdgcn_rsqf(var + 1e-5f);
  float4 gg = *reinterpret_cast<const float4*>(&g[lane * 4]);
  float4 bq = *reinterpret_cast<const float4*>(&bb[lane * 4]);
  float4 o;
  o.x = a0 * rs * gg.x + bq.x; o.y = a1 * rs * gg.y + bq.y;
  o.z = a2 * rs * gg.z + bq.z; o.w = a3 * rs * gg.w + bq.w;
  *reinterpret_cast<float4*>(&out[(size_t)row * 256 + lane * 4]) = o;
  union { __hip_bfloat16 h[4]; short4 s4; } u;
  u.h[0] = __float2bfloat16(o.x); u.h[1] = __float2bfloat16(o.y);
  u.h[2] = __float2bfloat16(o.z); u.h[3] = __float2bfloat16(o.w);
  reinterpret_cast<short4*>(outb)[row * 64 + lane] = u.s4;
}

// ---------------------------------------------------------------------------
__global__ __launch_bounds__(256) void final_k(
    const float* __restrict__ t2, const float* __restrict__ g2v,
    const float* __restrict__ b2v, const float* __restrict__ g3v,
    const float* __restrict__ b3v, const float* __restrict__ x,
    float* __restrict__ out) {
  int bx = blockIdx.x;
  int half = bx & 1, nv = (bx >> 1) & 31, b = bx >> 6;
  int wave = threadIdx.x >> 6, lane = threadIdx.x & 63;
  __shared__ float sh[32][257];
  float4 gg2 = *reinterpret_cast<const float4*>(&g2v[lane * 4]);
  float4 bb2 = *reinterpret_cast<const float4*>(&b2v[lane * 4]);
  float4 gg3 = *reinterpret_cast<const float4*>(&g3v[lane * 4]);
  float4 bb3 = *reinterpret_cast<const float4*>(&b3v[lane * 4]);
#pragma unroll
  for (int i = 0; i < 8; ++i) {
    int pn = wave * 8 + i;
    int r = ((b * 32 + nv) << 6) + (half << 5) + pn;
    float4 v = *reinterpret_cast<const float4*>(&t2[(size_t)r * 256 + lane * 4]);
    float mu = wsum_(v.x + v.y + v.z + v.w) * (1.f / 256.f);
    float a0 = v.x - mu, a1 = v.y - mu, a2 = v.z - mu, a3 = v.w - mu;
    float var = wsum_(a0 * a0 + a1 * a1 + a2 * a2 + a3 * a3) * (1.f / 256.f);
    float rs = __builtin_amdgcn_rsqf(var + 1e-5f);
    a0 = a0 * rs * gg2.x + bb2.x; a1 = a1 * rs * gg2.y + bb2.y;
    a2 = a2 * rs * gg2.z + bb2.z; a3 = a3 * rs * gg2.w + bb2.w;
    mu = wsum_(a0 + a1 + a2 + a3) * (1.f / 256.f);
    float c0 = a0 - mu, c1 = a1 - mu, c2 = a2 - mu, c3 = a3 - mu;
    var = wsum_(c0 * c0 + c1 * c1 + c2 * c2 + c3 * c3) * (1.f / 256.f);
    rs = __builtin_amdgcn_rsqf(var + 1e-5f);
    sh[pn][lane * 4 + 0] = c0 * rs * gg3.x + bb3.x;
    sh[pn][lane * 4 + 1] = c1 * rs * gg3.y + bb3.y;
    sh[pn][lane * 4 + 2] = c2 * rs * gg3.z + bb3.z;
    sh[pn][lane * 4 + 3] = c3 * rs * gg3.w + bb3.w;
  }
  __syncthreads();
  int pnl = threadIdx.x & 31;
  int dbase = threadIdx.x >> 5;
  size_t obase = (size_t)((b * 32 + nv) * 256) * 64 + (half << 5) + pnl;
#pragma unroll
  for (int k = 0; k < 32; ++k) {
    int dd = dbase + (k << 3);
    size_t oi = obase + (size_t)dd * 64;
    out[oi] = sh[pnl][dd] + x[oi];
  }
}

// ---------------------------------------------------------------------------
extern "C" void kernel_launch(void* const* d_in, const int* in_sizes, int n_in,
                              void* d_out, int out_size, void* d_ws,
                              size_t ws_size, hipStream_t stream) {
  const float* x    = (const float*)d_in[0];
  const float* w_in = (const float*)d_in[1];
  const float* b_in = (const float*)d_in[2];
  const float* cw   = (const float*)d_in[3];
  const float* cb   = (const float*)d_in[4];
  const float* wx   = (const float*)d_in[5];
  const float* wdt  = (const float*)d_in[6];
  const float* bdt  = (const float*)d_in[7];
  const float* alog = (const float*)d_in[8];
  const float* Dp   = (const float*)d_in[9];
  const float* wout = (const float*)d_in[10];
  const float* g1   = (const float*)d_in[11];
  const float* b1   = (const float*)d_in[12];
  const float* wf1  = (const float*)d_in[13];
  const float* bf1  = (const float*)d_in[14];
  const float* wf2  = (const float*)d_in[15];
  const float* bf2  = (const float*)d_in[16];
  const float* g2   = (const float*)d_in[17];
  const float* b2   = (const float*)d_in[18];
  const float* g3   = (const float*)d_in[19];
  const float* b3   = (const float*)d_in[20];
  float* out = (float*)d_out;

  const size_t MB1 = 1048576;
  char* g = (char*)d_ws;
  __hip_bfloat16* wbf_in  = (__hip_bfloat16*)(g);              // 512 KB
  __hip_bfloat16* wbf_out = (__hip_bfloat16*)(g + 524288);     // 256 KB
  __hip_bfloat16* wbf_f1  = (__hip_bfloat16*)(g + 786432);     // 256 KB
  __hip_bfloat16* wbf_f2  = (__hip_bfloat16*)(g + 1048576);    // 256 KB
  __hip_bfloat16* wbf_xp  = (__hip_bfloat16*)(g + 1310720);    // 128 KB
  const size_t SHARED = 1572864;

  // Regions per batch: R0 1MB | R1 2MB | R2 2MB | R3 2MB | R4 0.375MB | R5 2MB
  const size_t PB = 9 * MB1 + 393216;   // 9,830,400 B/batch
  int nb = (int)((ws_size - SHARED) / PB);
  if (ws_size <= SHARED || nb < 1) return;
  if (nb > NBTOT) nb = NBTOT;

  dim3 blk(256);
  cast_bf16_k<<<dim3(256), blk, 0, stream>>>(w_in, wbf_in, 65536);
  cast_bf16_k<<<dim3(128), blk, 0, stream>>>(wout, wbf_out, 32768);
  cast_bf16_k<<<dim3(128), blk, 0, stream>>>(wf1, wbf_f1, 32768);
  cast_bf16_k<<<dim3(128), blk, 0, stream>>>(wf2, wbf_f2, 32768);
  pad_wx_k<<<dim3(64), blk, 0, stream>>>(wx, wbf_xp);

  for (int b0 = 0; b0 < NBTOT; b0 += nb) {
    int bn = (NBTOT - b0 < nb) ? (NBTOT - b0) : nb;
    char* base = g + SHARED;
    char* R0 = base;                          // bn*1MB: xbf -> ap -> h1bf
    char* R1 = base + (size_t)bn * 1 * MB1;   // bn*2MB: xiprebf -> hp|Hc -> h1
    char* R2 = base + (size_t)bn * 3 * MB1;   // bn*2MB: zbf -> ffnybf
    char* R3 = base + (size_t)bn * 5 * MB1;   // bn*2MB: xibf/ybf -> t2
    char* R4 = base + (size_t)bn * 7 * MB1;   // bn*384KB: xdbl
    char* R5 = R4 + (size_t)bn * 393216;      // bn*2MB: deltab -> res

    __hip_bfloat16* xbf     = (__hip_bfloat16*)R0;
    float*          ap      = (float*)R0;
    __hip_bfloat16* h1bf    = (__hip_bfloat16*)R0;
    __hip_bfloat16* xiprebf = (__hip_bfloat16*)R1;
    float*          hp      = (float*)R1;
    float*          Hc      = (float*)(R1 + (size_t)bn * MB1);
    float*          h1      = (float*)R1;
    __hip_bfloat16* zbf     = (__hip_bfloat16*)R2;
    __hip_bfloat16* ffnybf  = (__hip_bfloat16*)R2;
    __hip_bfloat16* xibf    = (__hip_bfloat16*)R3;
    float*          t2      = (float*)R3;
    float*          xdbl    = (float*)R4;
    __hip_bfloat16* deltab  = (__hip_bfloat16*)R5;
    float*          res     = (float*)R5;

    const float* xg = x + (size_t)b0 * SEQ * 256;
    float* outg = out + (size_t)b0 * SEQ * 256;
    int M = bn * SEQ;
    int MT = M / 128;

    cast_bf16_k<<<dim3(M * 64 / 256), blk, 0, stream>>>(xg, xbf, M * 64);
    gemm_bf16<true, false, false, false, true><<<dim3(4, MT), blk, 0, stream>>>(
        xbf, wbf_in, b_in, nullptr, nullptr, xiprebf, 512, 256);
    gemm_bf16<true, false, false, false, true><<<dim3(4, MT), blk, 0, stream>>>(
        xbf, wbf_in + (size_t)512 * 256, b_in + 512, nullptr, nullptr, zbf,
        512, 256);
    conv_silu_k<<<dim3(M / 4), blk, 0, stream>>>(xiprebf, cw, cb, xibf);
    gemm_bf16<false, false, false, true, false><<<dim3(1, MT), blk, 0, stream>>>(
        xibf, wbf_xp, nullptr, nullptr, xdbl, nullptr, 48, 512);
    scan_p1<<<dim3(NCH, bn), dim3(512), 0, stream>>>(xibf, xdbl, alog, wdt,
                                                     bdt, ap, hp, deltab);
    scan_p2<<<dim3(bn * 32), blk, 0, stream>>>(ap, hp, Hc);
    scan_p3<<<dim3(NCH, bn), dim3(512), 0, stream>>>(xibf, xdbl, alog, deltab,
                                                     Hc, Dp, zbf, xibf);
    gemm_bf16<false, false, true, true, false><<<dim3(2, MT), blk, 0, stream>>>(
        xibf, wbf_out, nullptr, xg, res, nullptr, 256, 512);
    ln_k<<<dim3(M / 4), blk, 0, stream>>>(res, g1, b1, h1, h1bf);
    gemm_bf16<true, true, false, false, true><<<dim3(4, MT), blk, 0, stream>>>(
        h1bf, wbf_f1, bf1, nullptr, nullptr, ffnybf, 512, 256);
    gemm_bf16<true, false, true, true, false><<<dim3(2, MT), blk, 0, stream>>>(
        ffnybf, wbf_f2, bf2, h1, t2, nullptr, 256, 512);
    final_k<<<dim3(bn * 64), blk, 0, stream>>>(t2, g2, b2, g3, b3, xg, outg);
  }
}

// Round 6
// 351.344 us; speedup vs baseline: 2.8523x; 1.0454x over previous
//
#include <hip/hip_runtime.h>
#include <hip/hip_bf16.h>
#include <math.h>

#define SEQ    2048
#define NBTOT  16
#define NCH    64
#define CHL    32            // NCH*CHL == SEQ

#define L2E 1.4426950408889634f

typedef __attribute__((ext_vector_type(8))) __bf16 bf16x8;
typedef __attribute__((ext_vector_type(4))) float f32x4;

#define GLOAD16(gp, lp)                                                   \
  __builtin_amdgcn_global_load_lds(                                       \
      (const __attribute__((address_space(1))) unsigned int*)(gp),        \
      (__attribute__((address_space(3))) unsigned int*)(lp), 16, 0, 0)

// a[n] = a0^(n+1), depth-4 multiply tree
#define POWCHAIN(a, A0)                                                   \
  a[0] = (A0);            a[1] = a[0] * a[0];  a[2] = a[1] * a[0];        \
  a[3] = a[1] * a[1];     a[4] = a[3] * a[0];  a[5] = a[3] * a[1];        \
  a[6] = a[3] * a[2];     a[7] = a[3] * a[3];  a[8] = a[7] * a[0];        \
  a[9] = a[7] * a[1];     a[10] = a[7] * a[2]; a[11] = a[7] * a[3];       \
  a[12] = a[7] * a[4];    a[13] = a[7] * a[5]; a[14] = a[7] * a[6];       \
  a[15] = a[7] * a[7];

__device__ __forceinline__ float exp2_(float x) {
  return __builtin_amdgcn_exp2f(x);
}
__device__ __forceinline__ float silu_(float x) {
  return x * __builtin_amdgcn_rcpf(1.f + exp2_(-x * L2E));
}
__device__ __forceinline__ float softplus_(float x) {
  return fmaxf(x, 0.f) + __logf(1.f + exp2_(-fabsf(x) * L2E));
}
__device__ __forceinline__ float wsum_(float v) {
#pragma unroll
  for (int off = 32; off > 0; off >>= 1) v += __shfl_xor(v, off, 64);
  return v;
}

// ---------------------------------------------------------------------------
// bf16 MFMA GEMM (m97 structure): C[M,N] = A[M,K] @ W[N,K]^T (+bias)(+res)(relu)
// ---------------------------------------------------------------------------
template <bool BIAS, bool RELU, bool RES, bool F32OUT, bool BF16OUT>
__global__ __launch_bounds__(256) void gemm_bf16(
    const __hip_bfloat16* __restrict__ A, const __hip_bfloat16* __restrict__ W,
    const float* __restrict__ bias, const float* __restrict__ res,
    float* __restrict__ C, __hip_bfloat16* __restrict__ Cb, int N, int K) {
  __shared__ __align__(16) short Als[128 * 64];
  __shared__ __align__(16) short Bls[128 * 64];
  const int tid = threadIdx.x;
  const int lane = tid & 63;
  const int wid = tid >> 6;
  const int m0 = blockIdx.y * 128;
  const int n0 = blockIdx.x * 128;
  const int wm = (wid >> 1) * 64;
  const int wn = (wid & 1) * 64;
  const int lr = lane & 15;
  const int lk = lane >> 4;  // 0..3

  f32x4 acc[4][4];
#pragma unroll
  for (int m = 0; m < 4; ++m)
#pragma unroll
    for (int n = 0; n < 4; ++n) acc[m][n] = (f32x4){0.f, 0.f, 0.f, 0.f};

  const int srow = wid * 32 + (lane >> 3);
  const int scol = (lane & 7) * 8;
  const __hip_bfloat16* Ag = A + (size_t)(m0 + srow) * K + scol;
  const __hip_bfloat16* Wg = W + (size_t)(n0 + srow) * K + scol;
  short* Alb = Als + wid * 2048;
  short* Blb = Bls + wid * 2048;

  for (int kt = 0; kt < K; kt += 64) {
#pragma unroll
    for (int i = 0; i < 4; ++i) {
      GLOAD16(Ag + (size_t)(i * 8) * K + kt, Alb + i * 512);
      GLOAD16(Wg + (size_t)(i * 8) * K + kt, Blb + i * 512);
    }
    __syncthreads();
    const bf16x8* Af = reinterpret_cast<const bf16x8*>(Als);
    const bf16x8* Bf = reinterpret_cast<const bf16x8*>(Bls);
#pragma unroll
    for (int ks = 0; ks < 2; ++ks) {
      bf16x8 av[4], bv[4];
#pragma unroll
      for (int m = 0; m < 4; ++m)
        av[m] = Af[(wm + m * 16 + lr) * 8 + ks * 4 + lk];
#pragma unroll
      for (int n = 0; n < 4; ++n)
        bv[n] = Bf[(wn + n * 16 + lr) * 8 + ks * 4 + lk];
#pragma unroll
      for (int m = 0; m < 4; ++m)
#pragma unroll
        for (int n = 0; n < 4; ++n)
          acc[m][n] = __builtin_amdgcn_mfma_f32_16x16x32_bf16(
              av[m], bv[n], acc[m][n], 0, 0, 0);
    }
    __syncthreads();
  }

#pragma unroll
  for (int n = 0; n < 4; ++n) {
    int col = n0 + wn + n * 16 + lr;
    if (col >= N) continue;
    float bval = BIAS ? bias[col] : 0.f;
#pragma unroll
    for (int m = 0; m < 4; ++m) {
      int row0 = m0 + wm + m * 16 + lk * 4;
#pragma unroll
      for (int r = 0; r < 4; ++r) {
        size_t off = (size_t)(row0 + r) * N + col;
        float v = acc[m][n][r];
        if (BIAS) v += bval;
        if (RES) v += res[off];
        if (RELU) v = fmaxf(v, 0.f);
        if (F32OUT) C[off] = v;
        if (BF16OUT) Cb[off] = __float2bfloat16(v);
      }
    }
  }
}

// ---------------------------------------------------------------------------
__global__ __launch_bounds__(256) void cast_bf16_k(
    const float* __restrict__ src, __hip_bfloat16* __restrict__ dst, int n4) {
  int i = blockIdx.x * 256 + threadIdx.x;
  if (i >= n4) return;
  float4 v = reinterpret_cast<const float4*>(src)[i];
  union { __hip_bfloat16 h[4]; short4 s4; } u;
  u.h[0] = __float2bfloat16(v.x); u.h[1] = __float2bfloat16(v.y);
  u.h[2] = __float2bfloat16(v.z); u.h[3] = __float2bfloat16(v.w);
  reinterpret_cast<short4*>(dst)[i] = u.s4;
}

__global__ __launch_bounds__(256) void pad_wx_k(
    const float* __restrict__ src, __hip_bfloat16* __restrict__ dst) {
  int i = blockIdx.x * 256 + threadIdx.x;
  int row = i >> 7;
  union { __hip_bfloat16 h[4]; short4 s4; } u;
  if (row < 48) {
    float4 v = reinterpret_cast<const float4*>(src)[i];
    u.h[0] = __float2bfloat16(v.x); u.h[1] = __float2bfloat16(v.y);
    u.h[2] = __float2bfloat16(v.z); u.h[3] = __float2bfloat16(v.w);
  } else {
    u.h[0] = u.h[1] = u.h[2] = u.h[3] = __float2bfloat16(0.f);
  }
  reinterpret_cast<short4*>(dst)[i] = u.s4;
}

// ---------------------------------------------------------------------------
// Vectorized depthwise causal conv (D_CONV=4) + SiLU, bf16 in/out.
// ---------------------------------------------------------------------------
__global__ __launch_bounds__(256) void conv_silu_k(
    const __hip_bfloat16* __restrict__ xipre, const float* __restrict__ cw,
    const float* __restrict__ cb, __hip_bfloat16* __restrict__ xi) {
  int idx = blockIdx.x * 256 + threadIdx.x;  // r*64 + t
  int t = idx & 63;
  int r = idx >> 6;
  int l = r & (SEQ - 1);
  int c8 = t << 3;
  const __hip_bfloat16* p = xipre + (size_t)r * 512 + c8;
  union U8 { int4 v; __hip_bfloat16 h[8]; } x0, x1, x2, x3, o;
  const int4 z4 = make_int4(0, 0, 0, 0);
  x3.v = *reinterpret_cast<const int4*>(p);
  x2.v = (l >= 1) ? *reinterpret_cast<const int4*>(p - 512) : z4;
  x1.v = (l >= 2) ? *reinterpret_cast<const int4*>(p - 1024) : z4;
  x0.v = (l >= 3) ? *reinterpret_cast<const int4*>(p - 1536) : z4;
  const float4* cw4 = reinterpret_cast<const float4*>(cw);
#pragma unroll
  for (int j = 0; j < 8; ++j) {
    float4 w = cw4[c8 + j];
    float acc = cb[c8 + j];
    acc = fmaf(w.x, __bfloat162float(x0.h[j]), acc);
    acc = fmaf(w.y, __bfloat162float(x1.h[j]), acc);
    acc = fmaf(w.z, __bfloat162float(x2.h[j]), acc);
    acc = fmaf(w.w, __bfloat162float(x3.h[j]), acc);
    o.h[j] = __float2bfloat16(silu_(acc));
  }
  reinterpret_cast<int4*>(xi)[idx] = o.v;
}

// ---------------------------------------------------------------------------
// Chunked selective scan. A_log for this problem is log(1..16) broadcast, so
// exp(dl*A[n]) == e1^(n+1) with e1=exp(-dl): one exp2 + mul-tree instead of
// 16 exp2/step. Structure is VERIFIED at runtime from A_log; exact fallback
// loop otherwise (uniform branch).
// ---------------------------------------------------------------------------
__global__ __launch_bounds__(512) void scan_p1(
    const __hip_bfloat16* __restrict__ u, const float* __restrict__ xdbl,
    const float* __restrict__ A_log, const float* __restrict__ wdt,
    const float* __restrict__ bdt, float* __restrict__ ap,
    float* __restrict__ hp, __hip_bfloat16* __restrict__ deltab) {
  int d = threadIdx.x, c = blockIdx.x, b = blockIdx.y;
  __shared__ float Bsh[CHL][16];
  __shared__ float dtsh[CHL][16];
  int l0 = c * CHL;
  {
    int t = threadIdx.x;  // CHL*16 == 512
    int i = t >> 4, n = t & 15;
    size_t ro = (size_t)(b * SEQ + l0 + i) * 48;
    dtsh[i][n] = xdbl[ro + n];
    Bsh[i][n] = xdbl[ro + 16 + n];
  }
  float A2[16], wdtr[16];
  {
    const float4* aq = reinterpret_cast<const float4*>(&A_log[d * 16]);
    const float4* wq = reinterpret_cast<const float4*>(&wdt[d * 16]);
#pragma unroll
    for (int q = 0; q < 4; ++q) {
      float4 v = aq[q];
      A2[q * 4 + 0] = -exp2_(v.x * L2E) * L2E;
      A2[q * 4 + 1] = -exp2_(v.y * L2E) * L2E;
      A2[q * 4 + 2] = -exp2_(v.z * L2E) * L2E;
      A2[q * 4 + 3] = -exp2_(v.w * L2E) * L2E;
      float4 w = wq[q];
      wdtr[q * 4 + 0] = w.x; wdtr[q * 4 + 1] = w.y;
      wdtr[q * 4 + 2] = w.z; wdtr[q * 4 + 3] = w.w;
    }
  }
  bool chainok = true;
#pragma unroll
  for (int n = 1; n < 16; ++n)
    chainok = chainok &&
              (fabsf(A2[n] - (float)(n + 1) * A2[0]) <=
               1e-4f * (float)(n + 1) * fabsf(A2[0]));
  float bdtd = bdt[d];
  __syncthreads();
  float h[16];
#pragma unroll
  for (int n = 0; n < 16; ++n) h[n] = 0.f;
  float dlsum = 0.f;
  size_t base = (size_t)(b * SEQ + l0) * 512 + d;
  if (chainok) {
    for (int i = 0; i < CHL; ++i) {
      float dl = bdtd;
      const float4* dt4 = reinterpret_cast<const float4*>(&dtsh[i][0]);
#pragma unroll
      for (int q = 0; q < 4; ++q) {
        float4 t = dt4[q];
        dl = fmaf(t.x, wdtr[q * 4 + 0], dl);
        dl = fmaf(t.y, wdtr[q * 4 + 1], dl);
        dl = fmaf(t.z, wdtr[q * 4 + 2], dl);
        dl = fmaf(t.w, wdtr[q * 4 + 3], dl);
      }
      dl = softplus_(dl);
      deltab[base + (size_t)i * 512] = __float2bfloat16(dl);
      dlsum += dl;
      float ul = __bfloat162float(u[base + (size_t)i * 512]);
      float du = dl * ul;
      float a[16];
      POWCHAIN(a, exp2_(dl * A2[0]));
      const float4* B4 = reinterpret_cast<const float4*>(&Bsh[i][0]);
#pragma unroll
      for (int q = 0; q < 4; ++q) {
        float4 Bv = B4[q];
        h[q*4+0] = fmaf(a[q*4+0], h[q*4+0], du * Bv.x);
        h[q*4+1] = fmaf(a[q*4+1], h[q*4+1], du * Bv.y);
        h[q*4+2] = fmaf(a[q*4+2], h[q*4+2], du * Bv.z);
        h[q*4+3] = fmaf(a[q*4+3], h[q*4+3], du * Bv.w);
      }
    }
  } else {
    for (int i = 0; i < CHL; ++i) {
      float dl = bdtd;
      const float4* dt4 = reinterpret_cast<const float4*>(&dtsh[i][0]);
#pragma unroll
      for (int q = 0; q < 4; ++q) {
        float4 t = dt4[q];
        dl = fmaf(t.x, wdtr[q * 4 + 0], dl);
        dl = fmaf(t.y, wdtr[q * 4 + 1], dl);
        dl = fmaf(t.z, wdtr[q * 4 + 2], dl);
        dl = fmaf(t.w, wdtr[q * 4 + 3], dl);
      }
      dl = softplus_(dl);
      deltab[base + (size_t)i * 512] = __float2bfloat16(dl);
      dlsum += dl;
      float ul = __bfloat162float(u[base + (size_t)i * 512]);
      float du = dl * ul;
      const float4* B4 = reinterpret_cast<const float4*>(&Bsh[i][0]);
#pragma unroll
      for (int q = 0; q < 4; ++q) {
        float4 Bv = B4[q];
        h[q*4+0] = fmaf(exp2_(dl * A2[q*4+0]), h[q*4+0], du * Bv.x);
        h[q*4+1] = fmaf(exp2_(dl * A2[q*4+1]), h[q*4+1], du * Bv.y);
        h[q*4+2] = fmaf(exp2_(dl * A2[q*4+2]), h[q*4+2], du * Bv.z);
        h[q*4+3] = fmaf(exp2_(dl * A2[q*4+3]), h[q*4+3], du * Bv.w);
      }
    }
  }
  size_t o = ((size_t)((b * NCH + c) * 512) + d) * 16;
  float4* apq = reinterpret_cast<float4*>(ap + o);
  float4* hpq = reinterpret_cast<float4*>(hp + o);
  float a[16];
  if (chainok) {
    POWCHAIN(a, exp2_(A2[0] * dlsum));
  } else {
#pragma unroll
    for (int n = 0; n < 16; ++n) a[n] = exp2_(A2[n] * dlsum);
  }
#pragma unroll
  for (int q = 0; q < 4; ++q) {
    apq[q] = make_float4(a[q*4], a[q*4+1], a[q*4+2], a[q*4+3]);
    hpq[q] = make_float4(h[q*4], h[q*4+1], h[q*4+2], h[q*4+3]);
  }
}

// NOTE: Hc may alias ap (in-thread read-before-write per idx).
__global__ __launch_bounds__(256) void scan_p2(
    const float* ap, const float* __restrict__ hp, float* Hc) {
  int g = blockIdx.x * 256 + threadIdx.x;
  int b = g >> 13;
  int dn = g & 8191;
  float H = 0.f;
  for (int c = 0; c < NCH; ++c) {
    size_t idx = (size_t)(b * NCH + c) * 8192 + dn;
    float a = ap[idx], p = hp[idx];
    Hc[idx] = H;
    H = fmaf(a, H, p);
  }
}

__global__ __launch_bounds__(512) void scan_p3(
    const __hip_bfloat16* u,  // aliases y (same-thread read-before-write)
    const float* __restrict__ xdbl, const float* __restrict__ A_log,
    const __hip_bfloat16* __restrict__ deltab, const float* __restrict__ Hc,
    const float* __restrict__ Dp, const __hip_bfloat16* __restrict__ z,
    __hip_bfloat16* y) {
  int d = threadIdx.x, c = blockIdx.x, b = blockIdx.y;
  __shared__ float Bsh[CHL][16];
  __shared__ float Csh[CHL][16];
  int l0 = c * CHL;
  {
    int t = threadIdx.x;
    int i = t >> 4, n = t & 15;
    size_t ro = (size_t)(b * SEQ + l0 + i) * 48;
    Bsh[i][n] = xdbl[ro + 16 + n];
    Csh[i][n] = xdbl[ro + 32 + n];
  }
  float A2[16], h[16];
  {
    const float4* aq = reinterpret_cast<const float4*>(&A_log[d * 16]);
#pragma unroll
    for (int q = 0; q < 4; ++q) {
      float4 v = aq[q];
      A2[q * 4 + 0] = -exp2_(v.x * L2E) * L2E;
      A2[q * 4 + 1] = -exp2_(v.y * L2E) * L2E;
      A2[q * 4 + 2] = -exp2_(v.z * L2E) * L2E;
      A2[q * 4 + 3] = -exp2_(v.w * L2E) * L2E;
    }
    size_t o = ((size_t)((b * NCH + c) * 512) + d) * 16;
    const float4* hq = reinterpret_cast<const float4*>(Hc + o);
#pragma unroll
    for (int q = 0; q < 4; ++q) {
      float4 v = hq[q];
      h[q * 4 + 0] = v.x; h[q * 4 + 1] = v.y;
      h[q * 4 + 2] = v.z; h[q * 4 + 3] = v.w;
    }
  }
  bool chainok = true;
#pragma unroll
  for (int n = 1; n < 16; ++n)
    chainok = chainok &&
              (fabsf(A2[n] - (float)(n + 1) * A2[0]) <=
               1e-4f * (float)(n + 1) * fabsf(A2[0]));
  float Dpd = Dp[d];
  __syncthreads();
  size_t base = (size_t)(b * SEQ + l0) * 512 + d;
  if (chainok) {
    for (int i = 0; i < CHL; ++i) {
      float dl = __bfloat162float(deltab[base + (size_t)i * 512]);
      float ul = __bfloat162float(u[base + (size_t)i * 512]);
      float du = dl * ul;
      float yv = 0.f;
      float a[16];
      POWCHAIN(a, exp2_(dl * A2[0]));
      const float4* B4 = reinterpret_cast<const float4*>(&Bsh[i][0]);
      const float4* C4 = reinterpret_cast<const float4*>(&Csh[i][0]);
#pragma unroll
      for (int q = 0; q < 4; ++q) {
        float4 Bv = B4[q];
        float4 Cv = C4[q];
        h[q*4+0] = fmaf(a[q*4+0], h[q*4+0], du * Bv.x);
        h[q*4+1] = fmaf(a[q*4+1], h[q*4+1], du * Bv.y);
        h[q*4+2] = fmaf(a[q*4+2], h[q*4+2], du * Bv.z);
        h[q*4+3] = fmaf(a[q*4+3], h[q*4+3], du * Bv.w);
        yv = fmaf(h[q*4+0], Cv.x, yv);
        yv = fmaf(h[q*4+1], Cv.y, yv);
        yv = fmaf(h[q*4+2], Cv.z, yv);
        yv = fmaf(h[q*4+3], Cv.w, yv);
      }
      float zv = __bfloat162float(z[base + (size_t)i * 512]);
      y[base + (size_t)i * 512] =
          __float2bfloat16((yv + ul * Dpd) * silu_(zv));
    }
  } else {
    for (int i = 0; i < CHL; ++i) {
      float dl = __bfloat162float(deltab[base + (size_t)i * 512]);
      float ul = __bfloat162float(u[base + (size_t)i * 512]);
      float du = dl * ul;
      float yv = 0.f;
      const float4* B4 = reinterpret_cast<const float4*>(&Bsh[i][0]);
      const float4* C4 = reinterpret_cast<const float4*>(&Csh[i][0]);
#pragma unroll
      for (int q = 0; q < 4; ++q) {
        float4 Bv = B4[q];
        float4 Cv = C4[q];
        h[q*4+0] = fmaf(exp2_(dl * A2[q*4+0]), h[q*4+0], du * Bv.x);
        h[q*4+1] = fmaf(exp2_(dl * A2[q*4+1]), h[q*4+1], du * Bv.y);
        h[q*4+2] = fmaf(exp2_(dl * A2[q*4+2]), h[q*4+2], du * Bv.z);
        h[q*4+3] = fmaf(exp2_(dl * A2[q*4+3]), h[q*4+3], du * Bv.w);
        yv = fmaf(h[q*4+0], Cv.x, yv);
        yv = fmaf(h[q*4+1], Cv.y, yv);
        yv = fmaf(h[q*4+2], Cv.z, yv);
        yv = fmaf(h[q*4+3], Cv.w, yv);
      }
      float zv = __bfloat162float(z[base + (size_t)i * 512]);
      y[base + (size_t)i * 512] =
          __float2bfloat16((yv + ul * Dpd) * silu_(zv));
    }
  }
}

// ---------------------------------------------------------------------------
__global__ __launch_bounds__(256) void ln_k(
    const float* __restrict__ in, const float* __restrict__ g,
    const float* __restrict__ bb, float* __restrict__ out,
    __hip_bfloat16* __restrict__ outb) {
  int row = (blockIdx.x * 256 + threadIdx.x) >> 6;
  int lane = threadIdx.x & 63;
  float4 v = *reinterpret_cast<const float4*>(&in[(size_t)row * 256 + lane * 4]);
  float mu = wsum_(v.x + v.y + v.z + v.w) * (1.f / 256.f);
  float a0 = v.x - mu, a1 = v.y - mu, a2 = v.z - mu, a3 = v.w - mu;
  float var = wsum_(a0 * a0 + a1 * a1 + a2 * a2 + a3 * a3) * (1.f / 256.f);
  float rs = __builtin_amdgcn_rsqf(var + 1e-5f);
  float4 gg = *reinterpret_cast<const float4*>(&g[lane * 4]);
  float4 bq = *reinterpret_cast<const float4*>(&bb[lane * 4]);
  float4 o;
  o.x = a0 * rs * gg.x + bq.x; o.y = a1 * rs * gg.y + bq.y;
  o.z = a2 * rs * gg.z + bq.z; o.w = a3 * rs * gg.w + bq.w;
  *reinterpret_cast<float4*>(&out[(size_t)row * 256 + lane * 4]) = o;
  union { __hip_bfloat16 h[4]; short4 s4; } u;
  u.h[0] = __float2bfloat16(o.x); u.h[1] = __float2bfloat16(o.y);
  u.h[2] = __float2bfloat16(o.z); u.h[3] = __float2bfloat16(o.w);
  reinterpret_cast<short4*>(outb)[row * 64 + lane] = u.s4;
}

// ---------------------------------------------------------------------------
__global__ __launch_bounds__(256) void final_k(
    const float* __restrict__ t2, const float* __restrict__ g2v,
    const float* __restrict__ b2v, const float* __restrict__ g3v,
    const float* __restrict__ b3v, const float* __restrict__ x,
    float* __restrict__ out) {
  int bx = blockIdx.x;
  int half = bx & 1, nv = (bx >> 1) & 31, b = bx >> 6;
  int wave = threadIdx.x >> 6, lane = threadIdx.x & 63;
  __shared__ float sh[32][257];
  float4 gg2 = *reinterpret_cast<const float4*>(&g2v[lane * 4]);
  float4 bb2 = *reinterpret_cast<const float4*>(&b2v[lane * 4]);
  float4 gg3 = *reinterpret_cast<const float4*>(&g3v[lane * 4]);
  float4 bb3 = *reinterpret_cast<const float4*>(&b3v[lane * 4]);
#pragma unroll
  for (int i = 0; i < 8; ++i) {
    int pn = wave * 8 + i;
    int r = ((b * 32 + nv) << 6) + (half << 5) + pn;
    float4 v = *reinterpret_cast<const float4*>(&t2[(size_t)r * 256 + lane * 4]);
    float mu = wsum_(v.x + v.y + v.z + v.w) * (1.f / 256.f);
    float a0 = v.x - mu, a1 = v.y - mu, a2 = v.z - mu, a3 = v.w - mu;
    float var = wsum_(a0 * a0 + a1 * a1 + a2 * a2 + a3 * a3) * (1.f / 256.f);
    float rs = __builtin_amdgcn_rsqf(var + 1e-5f);
    a0 = a0 * rs * gg2.x + bb2.x; a1 = a1 * rs * gg2.y + bb2.y;
    a2 = a2 * rs * gg2.z + bb2.z; a3 = a3 * rs * gg2.w + bb2.w;
    mu = wsum_(a0 + a1 + a2 + a3) * (1.f / 256.f);
    float c0 = a0 - mu, c1 = a1 - mu, c2 = a2 - mu, c3 = a3 - mu;
    var = wsum_(c0 * c0 + c1 * c1 + c2 * c2 + c3 * c3) * (1.f / 256.f);
    rs = __builtin_amdgcn_rsqf(var + 1e-5f);
    sh[pn][lane * 4 + 0] = c0 * rs * gg3.x + bb3.x;
    sh[pn][lane * 4 + 1] = c1 * rs * gg3.y + bb3.y;
    sh[pn][lane * 4 + 2] = c2 * rs * gg3.z + bb3.z;
    sh[pn][lane * 4 + 3] = c3 * rs * gg3.w + bb3.w;
  }
  __syncthreads();
  int pnl = threadIdx.x & 31;
  int dbase = threadIdx.x >> 5;
  size_t obase = (size_t)((b * 32 + nv) * 256) * 64 + (half << 5) + pnl;
#pragma unroll
  for (int k = 0; k < 32; ++k) {
    int dd = dbase + (k << 3);
    size_t oi = obase + (size_t)dd * 64;
    out[oi] = sh[pnl][dd] + x[oi];
  }
}

// ---------------------------------------------------------------------------
extern "C" void kernel_launch(void* const* d_in, const int* in_sizes, int n_in,
                              void* d_out, int out_size, void* d_ws,
                              size_t ws_size, hipStream_t stream) {
  const float* x    = (const float*)d_in[0];
  const float* w_in = (const float*)d_in[1];
  const float* b_in = (const float*)d_in[2];
  const float* cw   = (const float*)d_in[3];
  const float* cb   = (const float*)d_in[4];
  const float* wx   = (const float*)d_in[5];
  const float* wdt  = (const float*)d_in[6];
  const float* bdt  = (const float*)d_in[7];
  const float* alog = (const float*)d_in[8];
  const float* Dp   = (const float*)d_in[9];
  const float* wout = (const float*)d_in[10];
  const float* g1   = (const float*)d_in[11];
  const float* b1   = (const float*)d_in[12];
  const float* wf1  = (const float*)d_in[13];
  const float* bf1  = (const float*)d_in[14];
  const float* wf2  = (const float*)d_in[15];
  const float* bf2  = (const float*)d_in[16];
  const float* g2   = (const float*)d_in[17];
  const float* b2   = (const float*)d_in[18];
  const float* g3   = (const float*)d_in[19];
  const float* b3   = (const float*)d_in[20];
  float* out = (float*)d_out;

  const size_t MB1 = 1048576;
  char* g = (char*)d_ws;
  __hip_bfloat16* wbf_in  = (__hip_bfloat16*)(g);              // 512 KB
  __hip_bfloat16* wbf_out = (__hip_bfloat16*)(g + 524288);     // 256 KB
  __hip_bfloat16* wbf_f1  = (__hip_bfloat16*)(g + 786432);     // 256 KB
  __hip_bfloat16* wbf_f2  = (__hip_bfloat16*)(g + 1048576);    // 256 KB
  __hip_bfloat16* wbf_xp  = (__hip_bfloat16*)(g + 1310720);    // 128 KB
  const size_t SHARED = 1572864;

  // Regions/batch: R0 1MB | R1 2MB | R2 2MB | R3 2MB | R4 384KB | R5 2MB | R6 2MB
  const size_t PB = 11 * MB1 + 393216;  // 11,927,552 B/batch
  int nb = (int)((ws_size - SHARED) / PB);
  if (ws_size <= SHARED || nb < 1) return;
  if (nb > NBTOT) nb = NBTOT;

  dim3 blk(256);
  cast_bf16_k<<<dim3(256), blk, 0, stream>>>(w_in, wbf_in, 65536);
  cast_bf16_k<<<dim3(128), blk, 0, stream>>>(wout, wbf_out, 32768);
  cast_bf16_k<<<dim3(128), blk, 0, stream>>>(wf1, wbf_f1, 32768);
  cast_bf16_k<<<dim3(128), blk, 0, stream>>>(wf2, wbf_f2, 32768);
  pad_wx_k<<<dim3(64), blk, 0, stream>>>(wx, wbf_xp);

  for (int b0 = 0; b0 < NBTOT; b0 += nb) {
    int bn = (NBTOT - b0 < nb) ? (NBTOT - b0) : nb;
    char* base = g + SHARED;
    char* R0 = base;                          // bn*1MB: xbf -> h1bf
    char* R1 = base + (size_t)bn * 1 * MB1;   // bn*2MB: xiprebf -> ap/Hc -> h1
    char* R2 = base + (size_t)bn * 3 * MB1;   // bn*2MB: zbf -> ffnybf
    char* R3 = base + (size_t)bn * 5 * MB1;   // bn*2MB: xibf/ybf -> t2
    char* R4 = base + (size_t)bn * 7 * MB1;   // bn*384KB: xdbl
    char* R5 = R4 + (size_t)bn * 393216;      // bn*2MB: deltab -> res
    char* R6 = R5 + (size_t)bn * 2 * MB1;     // bn*2MB: hp

    __hip_bfloat16* xbf     = (__hip_bfloat16*)R0;
    __hip_bfloat16* h1bf    = (__hip_bfloat16*)R0;
    __hip_bfloat16* xiprebf = (__hip_bfloat16*)R1;
    float*          ap      = (float*)R1;     // Hc aliases ap (see scan_p2)
    float*          h1      = (float*)R1;
    __hip_bfloat16* zbf     = (__hip_bfloat16*)R2;
    __hip_bfloat16* ffnybf  = (__hip_bfloat16*)R2;
    __hip_bfloat16* xibf    = (__hip_bfloat16*)R3;
    float*          t2      = (float*)R3;
    float*          xdbl    = (float*)R4;
    __hip_bfloat16* deltab  = (__hip_bfloat16*)R5;
    float*          res     = (float*)R5;
    float*          hp      = (float*)R6;

    const float* xg = x + (size_t)b0 * SEQ * 256;
    float* outg = out + (size_t)b0 * SEQ * 256;
    int M = bn * SEQ;
    int MT = M / 128;

    cast_bf16_k<<<dim3(M * 64 / 256), blk, 0, stream>>>(xg, xbf, M * 64);
    gemm_bf16<true, false, false, false, true><<<dim3(4, MT), blk, 0, stream>>>(
        xbf, wbf_in, b_in, nullptr, nullptr, xiprebf, 512, 256);
    gemm_bf16<true, false, false, false, true><<<dim3(4, MT), blk, 0, stream>>>(
        xbf, wbf_in + (size_t)512 * 256, b_in + 512, nullptr, nullptr, zbf,
        512, 256);
    conv_silu_k<<<dim3(M / 4), blk, 0, stream>>>(xiprebf, cw, cb, xibf);
    gemm_bf16<false, false, false, true, false><<<dim3(1, MT), blk, 0, stream>>>(
        xibf, wbf_xp, nullptr, nullptr, xdbl, nullptr, 48, 512);
    scan_p1<<<dim3(NCH, bn), dim3(512), 0, stream>>>(xibf, xdbl, alog, wdt,
                                                     bdt, ap, hp, deltab);
    scan_p2<<<dim3(bn * 32), blk, 0, stream>>>(ap, hp, ap);
    scan_p3<<<dim3(NCH, bn), dim3(512), 0, stream>>>(xibf, xdbl, alog, deltab,
                                                     ap, Dp, zbf, xibf);
    gemm_bf16<false, false, true, true, false><<<dim3(2, MT), blk, 0, stream>>>(
        xibf, wbf_out, nullptr, xg, res, nullptr, 256, 512);
    ln_k<<<dim3(M / 4), blk, 0, stream>>>(res, g1, b1, h1, h1bf);
    gemm_bf16<true, true, false, false, true><<<dim3(4, MT), blk, 0, stream>>>(
        h1bf, wbf_f1, bf1, nullptr, nullptr, ffnybf, 512, 256);
    gemm_bf16<true, false, true, true, false><<<dim3(2, MT), blk, 0, stream>>>(
        ffnybf, wbf_f2, bf2, h1, t2, nullptr, 256, 512);
    final_k<<<dim3(bn * 64), blk, 0, stream>>>(t2, g2, b2, g3, b3, xg, outg);
  }
}

// Round 7
// 341.079 us; speedup vs baseline: 2.9382x; 1.0301x over previous
//
#include <hip/hip_runtime.h>
#include <hip/hip_bf16.h>
#include <math.h>

#define SEQ    2048
#define NBTOT  16
#define NCH    64
#define CHL    32            // NCH*CHL == SEQ

#define L2E 1.4426950408889634f

typedef __attribute__((ext_vector_type(8))) __bf16 bf16x8;
typedef __attribute__((ext_vector_type(4))) float f32x4;
typedef __attribute__((ext_vector_type(2))) float f32x2;

#define GLOAD16(gp, lp)                                                   \
  __builtin_amdgcn_global_load_lds(                                       \
      (const __attribute__((address_space(1))) unsigned int*)(gp),        \
      (__attribute__((address_space(3))) unsigned int*)(lp), 16, 0, 0)

__device__ __forceinline__ float exp2_(float x) {
  return __builtin_amdgcn_exp2f(x);
}
__device__ __forceinline__ float silu_(float x) {
  return x * __builtin_amdgcn_rcpf(1.f + exp2_(-x * L2E));
}
__device__ __forceinline__ float softplus_(float x) {
  return fmaxf(x, 0.f) + __logf(1.f + exp2_(-fabsf(x) * L2E));
}
__device__ __forceinline__ float wsum_(float v) {
#pragma unroll
  for (int off = 32; off > 0; off >>= 1) v += __shfl_xor(v, off, 64);
  return v;
}
// p[k] = {e1^(2k+1), e1^(2k+2)}: 2 squares + 7 pk_mul, depth 4
__device__ __forceinline__ void powpairs_(float e1, f32x2 p[8]) {
  float e2 = e1 * e1;
  f32x2 p0; p0.x = e1; p0.y = e2;
  f32x2 s2; s2.x = e2; s2.y = e2;
  f32x2 s4 = s2 * s2;
  f32x2 s8 = s4 * s4;
  p[0] = p0;      p[1] = p0 * s2; p[2] = p0 * s4; p[3] = p[1] * s4;
  p[4] = p0 * s8; p[5] = p[1] * s8; p[6] = p[2] * s8; p[7] = p[3] * s8;
}

// ---------------------------------------------------------------------------
// bf16 MFMA GEMM (m97 structure): C[M,N] = A[M,K] @ W[N,K]^T (+bias)(+res)(relu)
// ---------------------------------------------------------------------------
template <bool BIAS, bool RELU, bool RES, bool F32OUT, bool BF16OUT>
__global__ __launch_bounds__(256) void gemm_bf16(
    const __hip_bfloat16* __restrict__ A, const __hip_bfloat16* __restrict__ W,
    const float* __restrict__ bias, const float* __restrict__ res,
    float* __restrict__ C, __hip_bfloat16* __restrict__ Cb, int N, int K) {
  __shared__ __align__(16) short Als[128 * 64];
  __shared__ __align__(16) short Bls[128 * 64];
  const int tid = threadIdx.x;
  const int lane = tid & 63;
  const int wid = tid >> 6;
  const int m0 = blockIdx.y * 128;
  const int n0 = blockIdx.x * 128;
  const int wm = (wid >> 1) * 64;
  const int wn = (wid & 1) * 64;
  const int lr = lane & 15;
  const int lk = lane >> 4;  // 0..3

  f32x4 acc[4][4];
#pragma unroll
  for (int m = 0; m < 4; ++m)
#pragma unroll
    for (int n = 0; n < 4; ++n) acc[m][n] = (f32x4){0.f, 0.f, 0.f, 0.f};

  const int srow = wid * 32 + (lane >> 3);
  const int scol = (lane & 7) * 8;
  const __hip_bfloat16* Ag = A + (size_t)(m0 + srow) * K + scol;
  const __hip_bfloat16* Wg = W + (size_t)(n0 + srow) * K + scol;
  short* Alb = Als + wid * 2048;
  short* Blb = Bls + wid * 2048;

  for (int kt = 0; kt < K; kt += 64) {
#pragma unroll
    for (int i = 0; i < 4; ++i) {
      GLOAD16(Ag + (size_t)(i * 8) * K + kt, Alb + i * 512);
      GLOAD16(Wg + (size_t)(i * 8) * K + kt, Blb + i * 512);
    }
    __syncthreads();
    const bf16x8* Af = reinterpret_cast<const bf16x8*>(Als);
    const bf16x8* Bf = reinterpret_cast<const bf16x8*>(Bls);
#pragma unroll
    for (int ks = 0; ks < 2; ++ks) {
      bf16x8 av[4], bv[4];
#pragma unroll
      for (int m = 0; m < 4; ++m)
        av[m] = Af[(wm + m * 16 + lr) * 8 + ks * 4 + lk];
#pragma unroll
      for (int n = 0; n < 4; ++n)
        bv[n] = Bf[(wn + n * 16 + lr) * 8 + ks * 4 + lk];
#pragma unroll
      for (int m = 0; m < 4; ++m)
#pragma unroll
        for (int n = 0; n < 4; ++n)
          acc[m][n] = __builtin_amdgcn_mfma_f32_16x16x32_bf16(
              av[m], bv[n], acc[m][n], 0, 0, 0);
    }
    __syncthreads();
  }

#pragma unroll
  for (int n = 0; n < 4; ++n) {
    int col = n0 + wn + n * 16 + lr;
    if (col >= N) continue;
    float bval = BIAS ? bias[col] : 0.f;
#pragma unroll
    for (int m = 0; m < 4; ++m) {
      int row0 = m0 + wm + m * 16 + lk * 4;
#pragma unroll
      for (int r = 0; r < 4; ++r) {
        size_t off = (size_t)(row0 + r) * N + col;
        float v = acc[m][n][r];
        if (BIAS) v += bval;
        if (RES) v += res[off];
        if (RELU) v = fmaxf(v, 0.f);
        if (F32OUT) C[off] = v;
        if (BF16OUT) Cb[off] = __float2bfloat16(v);
      }
    }
  }
}

// ---------------------------------------------------------------------------
__global__ __launch_bounds__(256) void cast_bf16_k(
    const float* __restrict__ src, __hip_bfloat16* __restrict__ dst, int n4) {
  int i = blockIdx.x * 256 + threadIdx.x;
  if (i >= n4) return;
  float4 v = reinterpret_cast<const float4*>(src)[i];
  union { __hip_bfloat16 h[4]; short4 s4; } u;
  u.h[0] = __float2bfloat16(v.x); u.h[1] = __float2bfloat16(v.y);
  u.h[2] = __float2bfloat16(v.z); u.h[3] = __float2bfloat16(v.w);
  reinterpret_cast<short4*>(dst)[i] = u.s4;
}

__global__ __launch_bounds__(256) void pad_wx_k(
    const float* __restrict__ src, __hip_bfloat16* __restrict__ dst) {
  int i = blockIdx.x * 256 + threadIdx.x;
  int row = i >> 7;
  union { __hip_bfloat16 h[4]; short4 s4; } u;
  if (row < 48) {
    float4 v = reinterpret_cast<const float4*>(src)[i];
    u.h[0] = __float2bfloat16(v.x); u.h[1] = __float2bfloat16(v.y);
    u.h[2] = __float2bfloat16(v.z); u.h[3] = __float2bfloat16(v.w);
  } else {
    u.h[0] = u.h[1] = u.h[2] = u.h[3] = __float2bfloat16(0.f);
  }
  reinterpret_cast<short4*>(dst)[i] = u.s4;
}

// ---------------------------------------------------------------------------
// Vectorized depthwise causal conv (D_CONV=4) + SiLU, bf16 in/out.
// ---------------------------------------------------------------------------
__global__ __launch_bounds__(256) void conv_silu_k(
    const __hip_bfloat16* __restrict__ xipre, const float* __restrict__ cw,
    const float* __restrict__ cb, __hip_bfloat16* __restrict__ xi) {
  int idx = blockIdx.x * 256 + threadIdx.x;  // r*64 + t
  int t = idx & 63;
  int r = idx >> 6;
  int l = r & (SEQ - 1);
  int c8 = t << 3;
  const __hip_bfloat16* p = xipre + (size_t)r * 512 + c8;
  union U8 { int4 v; __hip_bfloat16 h[8]; } x0, x1, x2, x3, o;
  const int4 z4 = make_int4(0, 0, 0, 0);
  x3.v = *reinterpret_cast<const int4*>(p);
  x2.v = (l >= 1) ? *reinterpret_cast<const int4*>(p - 512) : z4;
  x1.v = (l >= 2) ? *reinterpret_cast<const int4*>(p - 1024) : z4;
  x0.v = (l >= 3) ? *reinterpret_cast<const int4*>(p - 1536) : z4;
  const float4* cw4 = reinterpret_cast<const float4*>(cw);
#pragma unroll
  for (int j = 0; j < 8; ++j) {
    float4 w = cw4[c8 + j];
    float acc = cb[c8 + j];
    acc = fmaf(w.x, __bfloat162float(x0.h[j]), acc);
    acc = fmaf(w.y, __bfloat162float(x1.h[j]), acc);
    acc = fmaf(w.z, __bfloat162float(x2.h[j]), acc);
    acc = fmaf(w.w, __bfloat162float(x3.h[j]), acc);
    o.h[j] = __float2bfloat16(silu_(acc));
  }
  reinterpret_cast<int4*>(xi)[idx] = o.v;
}

// ---------------------------------------------------------------------------
// Chunked selective scan, 256-thd blocks, NO LDS: dt/B/C rows are wave-uniform
// -> scalar (SMEM) loads; state math packed f32x2 (v_pk_fma_f32).
// A_log structure (A[n] = (n+1)*A[0]) verified at runtime; exact fallback.
// grid: (2*NCH, bn); d = (blockIdx.x&1)*256 + tid, c = blockIdx.x>>1.
// ---------------------------------------------------------------------------
__global__ __launch_bounds__(256) void scan_p1(
    const __hip_bfloat16* __restrict__ u, const float* __restrict__ xdbl,
    const float* __restrict__ A_log, const float* __restrict__ wdt,
    const float* __restrict__ bdt, float* __restrict__ ap,
    float* __restrict__ hp, __hip_bfloat16* __restrict__ deltab) {
  const int d = ((blockIdx.x & 1) << 8) + threadIdx.x;
  const int c = blockIdx.x >> 1;
  const int b = blockIdx.y;
  const int l0 = c * CHL;
  float A2[16];
  f32x2 w2[8];
  {
    const float4* aq = reinterpret_cast<const float4*>(&A_log[d * 16]);
    const f32x2* wq = reinterpret_cast<const f32x2*>(&wdt[d * 16]);
#pragma unroll
    for (int q = 0; q < 4; ++q) {
      float4 v = aq[q];
      A2[q * 4 + 0] = -exp2_(v.x * L2E) * L2E;
      A2[q * 4 + 1] = -exp2_(v.y * L2E) * L2E;
      A2[q * 4 + 2] = -exp2_(v.z * L2E) * L2E;
      A2[q * 4 + 3] = -exp2_(v.w * L2E) * L2E;
    }
#pragma unroll
    for (int k = 0; k < 8; ++k) w2[k] = wq[k];
  }
  bool chainok = true;
#pragma unroll
  for (int n = 1; n < 16; ++n)
    chainok = chainok &&
              (fabsf(A2[n] - (float)(n + 1) * A2[0]) <=
               1e-4f * (float)(n + 1) * fabsf(A2[0]));
  const float bdtd = bdt[d];
  const float nL = A2[0];
  f32x2 h2[8];
#pragma unroll
  for (int k = 0; k < 8; ++k) h2[k] = (f32x2){0.f, 0.f};
  float dlsum = 0.f;
  size_t base = (size_t)(b * SEQ + l0) * 512 + d;
  const float* rowp = xdbl + (size_t)(b * SEQ + l0) * 48;
  if (chainok) {
#pragma unroll 4
    for (int i = 0; i < CHL; ++i) {
      const f32x2* r2 = reinterpret_cast<const f32x2*>(rowp + i * 48);
      f32x2 acc2; acc2.x = bdtd; acc2.y = 0.f;
#pragma unroll
      for (int k = 0; k < 8; ++k)
        acc2 = __builtin_elementwise_fma(r2[k], w2[k], acc2);
      float dl = softplus_(acc2.x + acc2.y);
      deltab[base + (size_t)i * 512] = __float2bfloat16(dl);
      dlsum += dl;
      float du = dl * __bfloat162float(u[base + (size_t)i * 512]);
      f32x2 p[8];
      powpairs_(exp2_(dl * nL), p);
      f32x2 du2; du2.x = du; du2.y = du;
#pragma unroll
      for (int k = 0; k < 8; ++k)
        h2[k] = __builtin_elementwise_fma(p[k], h2[k], du2 * r2[8 + k]);
    }
  } else {
#pragma unroll 2
    for (int i = 0; i < CHL; ++i) {
      const f32x2* r2 = reinterpret_cast<const f32x2*>(rowp + i * 48);
      f32x2 acc2; acc2.x = bdtd; acc2.y = 0.f;
#pragma unroll
      for (int k = 0; k < 8; ++k)
        acc2 = __builtin_elementwise_fma(r2[k], w2[k], acc2);
      float dl = softplus_(acc2.x + acc2.y);
      deltab[base + (size_t)i * 512] = __float2bfloat16(dl);
      dlsum += dl;
      float du = dl * __bfloat162float(u[base + (size_t)i * 512]);
      f32x2 du2; du2.x = du; du2.y = du;
#pragma unroll
      for (int k = 0; k < 8; ++k) {
        f32x2 a; a.x = exp2_(dl * A2[2 * k]); a.y = exp2_(dl * A2[2 * k + 1]);
        h2[k] = __builtin_elementwise_fma(a, h2[k], du2 * r2[8 + k]);
      }
    }
  }
  f32x2 pa[8];
  if (chainok) {
    powpairs_(exp2_(nL * dlsum), pa);
  } else {
#pragma unroll
    for (int k = 0; k < 8; ++k) {
      pa[k].x = exp2_(A2[2 * k] * dlsum);
      pa[k].y = exp2_(A2[2 * k + 1] * dlsum);
    }
  }
  size_t o = ((size_t)((b * NCH + c) * 512) + d) * 16;
  float4* apq = reinterpret_cast<float4*>(ap + o);
  float4* hpq = reinterpret_cast<float4*>(hp + o);
#pragma unroll
  for (int q = 0; q < 4; ++q) {
    apq[q] = make_float4(pa[2*q].x, pa[2*q].y, pa[2*q+1].x, pa[2*q+1].y);
    hpq[q] = make_float4(h2[2*q].x, h2[2*q].y, h2[2*q+1].x, h2[2*q+1].y);
  }
}

// NOTE: Hc may alias ap (in-thread read-before-write per idx).
__global__ __launch_bounds__(256) void scan_p2(
    const float* ap, const float* __restrict__ hp, float* Hc) {
  int g = blockIdx.x * 256 + threadIdx.x;
  int b = g >> 13;
  int dn = g & 8191;
  float H = 0.f;
  for (int c = 0; c < NCH; ++c) {
    size_t idx = (size_t)(b * NCH + c) * 8192 + dn;
    float a = ap[idx], p = hp[idx];
    Hc[idx] = H;
    H = fmaf(a, H, p);
  }
}

__global__ __launch_bounds__(256) void scan_p3(
    const __hip_bfloat16* u,  // aliases y (same-thread read-before-write)
    const float* __restrict__ xdbl, const float* __restrict__ A_log,
    const __hip_bfloat16* __restrict__ deltab, const float* __restrict__ Hc,
    const float* __restrict__ Dp, const __hip_bfloat16* __restrict__ z,
    __hip_bfloat16* y) {
  const int d = ((blockIdx.x & 1) << 8) + threadIdx.x;
  const int c = blockIdx.x >> 1;
  const int b = blockIdx.y;
  const int l0 = c * CHL;
  float A2[16];
  {
    const float4* aq = reinterpret_cast<const float4*>(&A_log[d * 16]);
#pragma unroll
    for (int q = 0; q < 4; ++q) {
      float4 v = aq[q];
      A2[q * 4 + 0] = -exp2_(v.x * L2E) * L2E;
      A2[q * 4 + 1] = -exp2_(v.y * L2E) * L2E;
      A2[q * 4 + 2] = -exp2_(v.z * L2E) * L2E;
      A2[q * 4 + 3] = -exp2_(v.w * L2E) * L2E;
    }
  }
  bool chainok = true;
#pragma unroll
  for (int n = 1; n < 16; ++n)
    chainok = chainok &&
              (fabsf(A2[n] - (float)(n + 1) * A2[0]) <=
               1e-4f * (float)(n + 1) * fabsf(A2[0]));
  const float nL = A2[0];
  f32x2 h2[8];
  {
    size_t o = ((size_t)((b * NCH + c) * 512) + d) * 16;
    const f32x2* hq = reinterpret_cast<const f32x2*>(Hc + o);
#pragma unroll
    for (int k = 0; k < 8; ++k) h2[k] = hq[k];
  }
  const float Dpd = Dp[d];
  size_t base = (size_t)(b * SEQ + l0) * 512 + d;
  const float* rowp = xdbl + (size_t)(b * SEQ + l0) * 48;
  if (chainok) {
#pragma unroll 4
    for (int i = 0; i < CHL; ++i) {
      const f32x2* r2 = reinterpret_cast<const f32x2*>(rowp + i * 48);
      float dl = __bfloat162float(deltab[base + (size_t)i * 512]);
      float ul = __bfloat162float(u[base + (size_t)i * 512]);
      float du = dl * ul;
      f32x2 p[8];
      powpairs_(exp2_(dl * nL), p);
      f32x2 du2; du2.x = du; du2.y = du;
      f32x2 yv2; yv2.x = 0.f; yv2.y = 0.f;
#pragma unroll
      for (int k = 0; k < 8; ++k) {
        h2[k] = __builtin_elementwise_fma(p[k], h2[k], du2 * r2[8 + k]);
        yv2 = __builtin_elementwise_fma(h2[k], r2[16 + k], yv2);
      }
      float yv = yv2.x + yv2.y;
      float zv = __bfloat162float(z[base + (size_t)i * 512]);
      y[base + (size_t)i * 512] =
          __float2bfloat16((yv + ul * Dpd) * silu_(zv));
    }
  } else {
#pragma unroll 2
    for (int i = 0; i < CHL; ++i) {
      const f32x2* r2 = reinterpret_cast<const f32x2*>(rowp + i * 48);
      float dl = __bfloat162float(deltab[base + (size_t)i * 512]);
      float ul = __bfloat162float(u[base + (size_t)i * 512]);
      float du = dl * ul;
      f32x2 du2; du2.x = du; du2.y = du;
      f32x2 yv2; yv2.x = 0.f; yv2.y = 0.f;
#pragma unroll
      for (int k = 0; k < 8; ++k) {
        f32x2 a; a.x = exp2_(dl * A2[2 * k]); a.y = exp2_(dl * A2[2 * k + 1]);
        h2[k] = __builtin_elementwise_fma(a, h2[k], du2 * r2[8 + k]);
        yv2 = __builtin_elementwise_fma(h2[k], r2[16 + k], yv2);
      }
      float yv = yv2.x + yv2.y;
      float zv = __bfloat162float(z[base + (size_t)i * 512]);
      y[base + (size_t)i * 512] =
          __float2bfloat16((yv + ul * Dpd) * silu_(zv));
    }
  }
}

// ---------------------------------------------------------------------------
__global__ __launch_bounds__(256) void ln_k(
    const float* __restrict__ in, const float* __restrict__ g,
    const float* __restrict__ bb, float* __restrict__ out,
    __hip_bfloat16* __restrict__ outb) {
  int row = (blockIdx.x * 256 + threadIdx.x) >> 6;
  int lane = threadIdx.x & 63;
  float4 v = *reinterpret_cast<const float4*>(&in[(size_t)row * 256 + lane * 4]);
  float mu = wsum_(v.x + v.y + v.z + v.w) * (1.f / 256.f);
  float a0 = v.x - mu, a1 = v.y - mu, a2 = v.z - mu, a3 = v.w - mu;
  float var = wsum_(a0 * a0 + a1 * a1 + a2 * a2 + a3 * a3) * (1.f / 256.f);
  float rs = __builtin_amdgcn_rsqf(var + 1e-5f);
  float4 gg = *reinterpret_cast<const float4*>(&g[lane * 4]);
  float4 bq = *reinterpret_cast<const float4*>(&bb[lane * 4]);
  float4 o;
  o.x = a0 * rs * gg.x + bq.x; o.y = a1 * rs * gg.y + bq.y;
  o.z = a2 * rs * gg.z + bq.z; o.w = a3 * rs * gg.w + bq.w;
  *reinterpret_cast<float4*>(&out[(size_t)row * 256 + lane * 4]) = o;
  union { __hip_bfloat16 h[4]; short4 s4; } u;
  u.h[0] = __float2bfloat16(o.x); u.h[1] = __float2bfloat16(o.y);
  u.h[2] = __float2bfloat16(o.z); u.h[3] = __float2bfloat16(o.w);
  reinterpret_cast<short4*>(outb)[row * 64 + lane] = u.s4;
}

// ---------------------------------------------------------------------------
__global__ __launch_bounds__(256) void final_k(
    const float* __restrict__ t2, const float* __restrict__ g2v,
    const float* __restrict__ b2v, const float* __restrict__ g3v,
    const float* __restrict__ b3v, const float* __restrict__ x,
    float* __restrict__ out) {
  int bx = blockIdx.x;
  int half = bx & 1, nv = (bx >> 1) & 31, b = bx >> 6;
  int wave = threadIdx.x >> 6, lane = threadIdx.x & 63;
  __shared__ float sh[32][257];
  float4 gg2 = *reinterpret_cast<const float4*>(&g2v[lane * 4]);
  float4 bb2 = *reinterpret_cast<const float4*>(&b2v[lane * 4]);
  float4 gg3 = *reinterpret_cast<const float4*>(&g3v[lane * 4]);
  float4 bb3 = *reinterpret_cast<const float4*>(&b3v[lane * 4]);
#pragma unroll
  for (int i = 0; i < 8; ++i) {
    int pn = wave * 8 + i;
    int r = ((b * 32 + nv) << 6) + (half << 5) + pn;
    float4 v = *reinterpret_cast<const float4*>(&t2[(size_t)r * 256 + lane * 4]);
    float mu = wsum_(v.x + v.y + v.z + v.w) * (1.f / 256.f);
    float a0 = v.x - mu, a1 = v.y - mu, a2 = v.z - mu, a3 = v.w - mu;
    float var = wsum_(a0 * a0 + a1 * a1 + a2 * a2 + a3 * a3) * (1.f / 256.f);
    float rs = __builtin_amdgcn_rsqf(var + 1e-5f);
    a0 = a0 * rs * gg2.x + bb2.x; a1 = a1 * rs * gg2.y + bb2.y;
    a2 = a2 * rs * gg2.z + bb2.z; a3 = a3 * rs * gg2.w + bb2.w;
    mu = wsum_(a0 + a1 + a2 + a3) * (1.f / 256.f);
    float c0 = a0 - mu, c1 = a1 - mu, c2 = a2 - mu, c3 = a3 - mu;
    var = wsum_(c0 * c0 + c1 * c1 + c2 * c2 + c3 * c3) * (1.f / 256.f);
    rs = __builtin_amdgcn_rsqf(var + 1e-5f);
    sh[pn][lane * 4 + 0] = c0 * rs * gg3.x + bb3.x;
    sh[pn][lane * 4 + 1] = c1 * rs * gg3.y + bb3.y;
    sh[pn][lane * 4 + 2] = c2 * rs * gg3.z + bb3.z;
    sh[pn][lane * 4 + 3] = c3 * rs * gg3.w + bb3.w;
  }
  __syncthreads();
  int pnl = threadIdx.x & 31;
  int dbase = threadIdx.x >> 5;
  size_t obase = (size_t)((b * 32 + nv) * 256) * 64 + (half << 5) + pnl;
#pragma unroll
  for (int k = 0; k < 32; ++k) {
    int dd = dbase + (k << 3);
    size_t oi = obase + (size_t)dd * 64;
    out[oi] = sh[pnl][dd] + x[oi];
  }
}

// ---------------------------------------------------------------------------
extern "C" void kernel_launch(void* const* d_in, const int* in_sizes, int n_in,
                              void* d_out, int out_size, void* d_ws,
                              size_t ws_size, hipStream_t stream) {
  const float* x    = (const float*)d_in[0];
  const float* w_in = (const float*)d_in[1];
  const float* b_in = (const float*)d_in[2];
  const float* cw   = (const float*)d_in[3];
  const float* cb   = (const float*)d_in[4];
  const float* wx   = (const float*)d_in[5];
  const float* wdt  = (const float*)d_in[6];
  const float* bdt  = (const float*)d_in[7];
  const float* alog = (const float*)d_in[8];
  const float* Dp   = (const float*)d_in[9];
  const float* wout = (const float*)d_in[10];
  const float* g1   = (const float*)d_in[11];
  const float* b1   = (const float*)d_in[12];
  const float* wf1  = (const float*)d_in[13];
  const float* bf1  = (const float*)d_in[14];
  const float* wf2  = (const float*)d_in[15];
  const float* bf2  = (const float*)d_in[16];
  const float* g2   = (const float*)d_in[17];
  const float* b2   = (const float*)d_in[18];
  const float* g3   = (const float*)d_in[19];
  const float* b3   = (const float*)d_in[20];
  float* out = (float*)d_out;

  const size_t MB1 = 1048576;
  char* g = (char*)d_ws;
  __hip_bfloat16* wbf_in  = (__hip_bfloat16*)(g);              // 512 KB
  __hip_bfloat16* wbf_out = (__hip_bfloat16*)(g + 524288);     // 256 KB
  __hip_bfloat16* wbf_f1  = (__hip_bfloat16*)(g + 786432);     // 256 KB
  __hip_bfloat16* wbf_f2  = (__hip_bfloat16*)(g + 1048576);    // 256 KB
  __hip_bfloat16* wbf_xp  = (__hip_bfloat16*)(g + 1310720);    // 128 KB
  const size_t SHARED = 1572864;

  // Regions/batch: R0 1MB | R1 2MB | R2 2MB | R3 2MB | R4 384KB | R5 2MB | R6 2MB
  const size_t PB = 11 * MB1 + 393216;  // 11,927,552 B/batch
  int nb = (int)((ws_size - SHARED) / PB);
  if (ws_size <= SHARED || nb < 1) return;
  if (nb > NBTOT) nb = NBTOT;

  dim3 blk(256);
  cast_bf16_k<<<dim3(256), blk, 0, stream>>>(w_in, wbf_in, 65536);
  cast_bf16_k<<<dim3(128), blk, 0, stream>>>(wout, wbf_out, 32768);
  cast_bf16_k<<<dim3(128), blk, 0, stream>>>(wf1, wbf_f1, 32768);
  cast_bf16_k<<<dim3(128), blk, 0, stream>>>(wf2, wbf_f2, 32768);
  pad_wx_k<<<dim3(64), blk, 0, stream>>>(wx, wbf_xp);

  for (int b0 = 0; b0 < NBTOT; b0 += nb) {
    int bn = (NBTOT - b0 < nb) ? (NBTOT - b0) : nb;
    char* base = g + SHARED;
    char* R0 = base;                          // bn*1MB: xbf -> h1bf
    char* R1 = base + (size_t)bn * 1 * MB1;   // bn*2MB: xiprebf -> ap/Hc -> h1
    char* R2 = base + (size_t)bn * 3 * MB1;   // bn*2MB: zbf -> ffnybf
    char* R3 = base + (size_t)bn * 5 * MB1;   // bn*2MB: xibf/ybf -> t2
    char* R4 = base + (size_t)bn * 7 * MB1;   // bn*384KB: xdbl
    char* R5 = R4 + (size_t)bn * 393216;      // bn*2MB: deltab -> res
    char* R6 = R5 + (size_t)bn * 2 * MB1;     // bn*2MB: hp

    __hip_bfloat16* xbf     = (__hip_bfloat16*)R0;
    __hip_bfloat16* h1bf    = (__hip_bfloat16*)R0;
    __hip_bfloat16* xiprebf = (__hip_bfloat16*)R1;
    float*          ap      = (float*)R1;     // Hc aliases ap (see scan_p2)
    float*          h1      = (float*)R1;
    __hip_bfloat16* zbf     = (__hip_bfloat16*)R2;
    __hip_bfloat16* ffnybf  = (__hip_bfloat16*)R2;
    __hip_bfloat16* xibf    = (__hip_bfloat16*)R3;
    float*          t2      = (float*)R3;
    float*          xdbl    = (float*)R4;
    __hip_bfloat16* deltab  = (__hip_bfloat16*)R5;
    float*          res     = (float*)R5;
    float*          hp      = (float*)R6;

    const float* xg = x + (size_t)b0 * SEQ * 256;
    float* outg = out + (size_t)b0 * SEQ * 256;
    int M = bn * SEQ;
    int MT = M / 128;

    cast_bf16_k<<<dim3(M * 64 / 256), blk, 0, stream>>>(xg, xbf, M * 64);
    gemm_bf16<true, false, false, false, true><<<dim3(4, MT), blk, 0, stream>>>(
        xbf, wbf_in, b_in, nullptr, nullptr, xiprebf, 512, 256);
    gemm_bf16<true, false, false, false, true><<<dim3(4, MT), blk, 0, stream>>>(
        xbf, wbf_in + (size_t)512 * 256, b_in + 512, nullptr, nullptr, zbf,
        512, 256);
    conv_silu_k<<<dim3(M / 4), blk, 0, stream>>>(xiprebf, cw, cb, xibf);
    gemm_bf16<false, false, false, true, false><<<dim3(1, MT), blk, 0, stream>>>(
        xibf, wbf_xp, nullptr, nullptr, xdbl, nullptr, 48, 512);
    scan_p1<<<dim3(NCH * 2, bn), blk, 0, stream>>>(xibf, xdbl, alog, wdt,
                                                   bdt, ap, hp, deltab);
    scan_p2<<<dim3(bn * 32), blk, 0, stream>>>(ap, hp, ap);
    scan_p3<<<dim3(NCH * 2, bn), blk, 0, stream>>>(xibf, xdbl, alog, deltab,
                                                   ap, Dp, zbf, xibf);
    gemm_bf16<false, false, true, true, false><<<dim3(2, MT), blk, 0, stream>>>(
        xibf, wbf_out, nullptr, xg, res, nullptr, 256, 512);
    ln_k<<<dim3(M / 4), blk, 0, stream>>>(res, g1, b1, h1, h1bf);
    gemm_bf16<true, true, false, false, true><<<dim3(4, MT), blk, 0, stream>>>(
        h1bf, wbf_f1, bf1, nullptr, nullptr, ffnybf, 512, 256);
    gemm_bf16<true, false, true, true, false><<<dim3(2, MT), blk, 0, stream>>>(
        ffnybf, wbf_f2, bf2, h1, t2, nullptr, 256, 512);
    final_k<<<dim3(bn * 64), blk, 0, stream>>>(t2, g2, b2, g3, b3, xg, outg);
  }
}

// Round 8
// 319.395 us; speedup vs baseline: 3.1376x; 1.0679x over previous
//
#include <hip/hip_runtime.h>
#include <hip/hip_bf16.h>
#include <math.h>

#define SEQ    2048
#define NBTOT  16
#define NCH    64
#define CHL    32            // NCH*CHL == SEQ

#define L2E 1.4426950408889634f

typedef __attribute__((ext_vector_type(8))) __bf16 bf16x8;
typedef __attribute__((ext_vector_type(4))) float f32x4;
typedef __attribute__((ext_vector_type(2))) float f32x2;

#define GLOAD16(gp, lp)                                                   \
  __builtin_amdgcn_global_load_lds(                                       \
      (const __attribute__((address_space(1))) unsigned int*)(gp),        \
      (__attribute__((address_space(3))) unsigned int*)(lp), 16, 0, 0)

__device__ __forceinline__ float exp2_(float x) {
  return __builtin_amdgcn_exp2f(x);
}
__device__ __forceinline__ float silu_(float x) {
  return x * __builtin_amdgcn_rcpf(1.f + exp2_(-x * L2E));
}
__device__ __forceinline__ float softplus_(float x) {
  return fmaxf(x, 0.f) + __logf(1.f + exp2_(-fabsf(x) * L2E));
}
__device__ __forceinline__ float wsum_(float v) {
#pragma unroll
  for (int off = 32; off > 0; off >>= 1) v += __shfl_xor(v, off, 64);
  return v;
}
// p[k] = {e1^(2k+1), e1^(2k+2)}: 2 squares + 7 pk_mul, depth 4
__device__ __forceinline__ void powpairs_(float e1, f32x2 p[8]) {
  float e2 = e1 * e1;
  f32x2 p0; p0.x = e1; p0.y = e2;
  f32x2 s2; s2.x = e2; s2.y = e2;
  f32x2 s4 = s2 * s2;
  f32x2 s8 = s4 * s4;
  p[0] = p0;      p[1] = p0 * s2; p[2] = p0 * s4; p[3] = p[1] * s4;
  p[4] = p0 * s8; p[5] = p[1] * s8; p[6] = p[2] * s8; p[7] = p[3] * s8;
}

// ---------------------------------------------------------------------------
// bf16 MFMA GEMM (m97 structure): C[M,N] = A[M,K] @ W[N,K]^T
// (+bias)(+f32 res)(+bf16 res)(relu); f32 and/or bf16 out.
// ---------------------------------------------------------------------------
template <bool BIAS, bool RELU, bool RES, bool RESB, bool F32OUT, bool BF16OUT>
__global__ __launch_bounds__(256) void gemm_bf16(
    const __hip_bfloat16* __restrict__ A, const __hip_bfloat16* __restrict__ W,
    const float* __restrict__ bias, const float* __restrict__ res,
    const __hip_bfloat16* __restrict__ resb, float* __restrict__ C,
    __hip_bfloat16* __restrict__ Cb, int N, int K) {
  __shared__ __align__(16) short Als[128 * 64];
  __shared__ __align__(16) short Bls[128 * 64];
  const int tid = threadIdx.x;
  const int lane = tid & 63;
  const int wid = tid >> 6;
  const int m0 = blockIdx.y * 128;
  const int n0 = blockIdx.x * 128;
  const int wm = (wid >> 1) * 64;
  const int wn = (wid & 1) * 64;
  const int lr = lane & 15;
  const int lk = lane >> 4;  // 0..3

  f32x4 acc[4][4];
#pragma unroll
  for (int m = 0; m < 4; ++m)
#pragma unroll
    for (int n = 0; n < 4; ++n) acc[m][n] = (f32x4){0.f, 0.f, 0.f, 0.f};

  const int srow = wid * 32 + (lane >> 3);
  const int scol = (lane & 7) * 8;
  const __hip_bfloat16* Ag = A + (size_t)(m0 + srow) * K + scol;
  const __hip_bfloat16* Wg = W + (size_t)(n0 + srow) * K + scol;
  short* Alb = Als + wid * 2048;
  short* Blb = Bls + wid * 2048;

  for (int kt = 0; kt < K; kt += 64) {
#pragma unroll
    for (int i = 0; i < 4; ++i) {
      GLOAD16(Ag + (size_t)(i * 8) * K + kt, Alb + i * 512);
      GLOAD16(Wg + (size_t)(i * 8) * K + kt, Blb + i * 512);
    }
    __syncthreads();
    const bf16x8* Af = reinterpret_cast<const bf16x8*>(Als);
    const bf16x8* Bf = reinterpret_cast<const bf16x8*>(Bls);
#pragma unroll
    for (int ks = 0; ks < 2; ++ks) {
      bf16x8 av[4], bv[4];
#pragma unroll
      for (int m = 0; m < 4; ++m)
        av[m] = Af[(wm + m * 16 + lr) * 8 + ks * 4 + lk];
#pragma unroll
      for (int n = 0; n < 4; ++n)
        bv[n] = Bf[(wn + n * 16 + lr) * 8 + ks * 4 + lk];
#pragma unroll
      for (int m = 0; m < 4; ++m)
#pragma unroll
        for (int n = 0; n < 4; ++n)
          acc[m][n] = __builtin_amdgcn_mfma_f32_16x16x32_bf16(
              av[m], bv[n], acc[m][n], 0, 0, 0);
    }
    __syncthreads();
  }

#pragma unroll
  for (int n = 0; n < 4; ++n) {
    int col = n0 + wn + n * 16 + lr;
    if (col >= N) continue;
    float bval = BIAS ? bias[col] : 0.f;
#pragma unroll
    for (int m = 0; m < 4; ++m) {
      int row0 = m0 + wm + m * 16 + lk * 4;
#pragma unroll
      for (int r = 0; r < 4; ++r) {
        size_t off = (size_t)(row0 + r) * N + col;
        float v = acc[m][n][r];
        if (BIAS) v += bval;
        if (RES) v += res[off];
        if (RESB) v += __bfloat162float(resb[off]);
        if (RELU) v = fmaxf(v, 0.f);
        if (F32OUT) C[off] = v;
        if (BF16OUT) Cb[off] = __float2bfloat16(v);
      }
    }
  }
}

// ---------------------------------------------------------------------------
__global__ __launch_bounds__(256) void cast_bf16_k(
    const float* __restrict__ src, __hip_bfloat16* __restrict__ dst, int n4) {
  int i = blockIdx.x * 256 + threadIdx.x;
  if (i >= n4) return;
  float4 v = reinterpret_cast<const float4*>(src)[i];
  union { __hip_bfloat16 h[4]; short4 s4; } u;
  u.h[0] = __float2bfloat16(v.x); u.h[1] = __float2bfloat16(v.y);
  u.h[2] = __float2bfloat16(v.z); u.h[3] = __float2bfloat16(v.w);
  reinterpret_cast<short4*>(dst)[i] = u.s4;
}

__global__ __launch_bounds__(256) void pad_wx_k(
    const float* __restrict__ src, __hip_bfloat16* __restrict__ dst) {
  int i = blockIdx.x * 256 + threadIdx.x;
  int row = i >> 7;
  union { __hip_bfloat16 h[4]; short4 s4; } u;
  if (row < 48) {
    float4 v = reinterpret_cast<const float4*>(src)[i];
    u.h[0] = __float2bfloat16(v.x); u.h[1] = __float2bfloat16(v.y);
    u.h[2] = __float2bfloat16(v.z); u.h[3] = __float2bfloat16(v.w);
  } else {
    u.h[0] = u.h[1] = u.h[2] = u.h[3] = __float2bfloat16(0.f);
  }
  reinterpret_cast<short4*>(dst)[i] = u.s4;
}

// ---------------------------------------------------------------------------
// Depthwise causal conv (D_CONV=4) + SiLU. In: xz (rows, 1024) cols 0..511.
// Out: xi (rows, 512).
// ---------------------------------------------------------------------------
__global__ __launch_bounds__(256) void conv_silu_k(
    const __hip_bfloat16* __restrict__ xz, const float* __restrict__ cw,
    const float* __restrict__ cb, __hip_bfloat16* __restrict__ xi) {
  int idx = blockIdx.x * 256 + threadIdx.x;  // r*64 + t
  int t = idx & 63;
  int r = idx >> 6;
  int l = r & (SEQ - 1);
  int c8 = t << 3;
  const __hip_bfloat16* p = xz + (size_t)r * 1024 + c8;
  union U8 { int4 v; __hip_bfloat16 h[8]; } x0, x1, x2, x3, o;
  const int4 z4 = make_int4(0, 0, 0, 0);
  x3.v = *reinterpret_cast<const int4*>(p);
  x2.v = (l >= 1) ? *reinterpret_cast<const int4*>(p - 1024) : z4;
  x1.v = (l >= 2) ? *reinterpret_cast<const int4*>(p - 2048) : z4;
  x0.v = (l >= 3) ? *reinterpret_cast<const int4*>(p - 3072) : z4;
  const float4* cw4 = reinterpret_cast<const float4*>(cw);
#pragma unroll
  for (int j = 0; j < 8; ++j) {
    float4 w = cw4[c8 + j];
    float acc = cb[c8 + j];
    acc = fmaf(w.x, __bfloat162float(x0.h[j]), acc);
    acc = fmaf(w.y, __bfloat162float(x1.h[j]), acc);
    acc = fmaf(w.z, __bfloat162float(x2.h[j]), acc);
    acc = fmaf(w.w, __bfloat162float(x3.h[j]), acc);
    o.h[j] = __float2bfloat16(silu_(acc));
  }
  reinterpret_cast<int4*>(xi)[idx] = o.v;
}

// ---------------------------------------------------------------------------
// Chunked selective scan. No LDS (xdbl rows wave-uniform -> SMEM loads),
// packed f32x2 math. p1 stores only hp + dlsum (ap compressed 16x via
// exp2(A2[n]*dlsum)); p3 recomputes delta from xdbl. A_log power-chain
// structure verified at runtime; exact fallback kept.
// grid: (2*NCH, bn); d = (blockIdx.x&1)*256 + tid, c = blockIdx.x>>1.
// ---------------------------------------------------------------------------
__global__ __launch_bounds__(256) void scan_p1(
    const __hip_bfloat16* __restrict__ u, const float* __restrict__ xdbl,
    const float* __restrict__ A_log, const float* __restrict__ wdt,
    const float* __restrict__ bdt, float* __restrict__ dlsum,
    float* __restrict__ hp) {
  const int d = ((blockIdx.x & 1) << 8) + threadIdx.x;
  const int c = blockIdx.x >> 1;
  const int b = blockIdx.y;
  const int l0 = c * CHL;
  float A2[16];
  f32x2 w2[8];
  {
    const float4* aq = reinterpret_cast<const float4*>(&A_log[d * 16]);
    const f32x2* wq = reinterpret_cast<const f32x2*>(&wdt[d * 16]);
#pragma unroll
    for (int q = 0; q < 4; ++q) {
      float4 v = aq[q];
      A2[q * 4 + 0] = -exp2_(v.x * L2E) * L2E;
      A2[q * 4 + 1] = -exp2_(v.y * L2E) * L2E;
      A2[q * 4 + 2] = -exp2_(v.z * L2E) * L2E;
      A2[q * 4 + 3] = -exp2_(v.w * L2E) * L2E;
    }
#pragma unroll
    for (int k = 0; k < 8; ++k) w2[k] = wq[k];
  }
  bool chainok = true;
#pragma unroll
  for (int n = 1; n < 16; ++n)
    chainok = chainok &&
              (fabsf(A2[n] - (float)(n + 1) * A2[0]) <=
               1e-4f * (float)(n + 1) * fabsf(A2[0]));
  const float bdtd = bdt[d];
  const float nL = A2[0];
  f32x2 h2[8];
#pragma unroll
  for (int k = 0; k < 8; ++k) h2[k] = (f32x2){0.f, 0.f};
  float dls = 0.f;
  size_t base = (size_t)(b * SEQ + l0) * 512 + d;
  const float* rowp = xdbl + (size_t)(b * SEQ + l0) * 48;
  if (chainok) {
#pragma unroll 4
    for (int i = 0; i < CHL; ++i) {
      const f32x2* r2 = reinterpret_cast<const f32x2*>(rowp + i * 48);
      f32x2 acc2; acc2.x = bdtd; acc2.y = 0.f;
#pragma unroll
      for (int k = 0; k < 8; ++k)
        acc2 = __builtin_elementwise_fma(r2[k], w2[k], acc2);
      float dl = softplus_(acc2.x + acc2.y);
      dls += dl;
      float du = dl * __bfloat162float(u[base + (size_t)i * 512]);
      f32x2 p[8];
      powpairs_(exp2_(dl * nL), p);
      f32x2 du2; du2.x = du; du2.y = du;
#pragma unroll
      for (int k = 0; k < 8; ++k)
        h2[k] = __builtin_elementwise_fma(p[k], h2[k], du2 * r2[8 + k]);
    }
  } else {
#pragma unroll 2
    for (int i = 0; i < CHL; ++i) {
      const f32x2* r2 = reinterpret_cast<const f32x2*>(rowp + i * 48);
      f32x2 acc2; acc2.x = bdtd; acc2.y = 0.f;
#pragma unroll
      for (int k = 0; k < 8; ++k)
        acc2 = __builtin_elementwise_fma(r2[k], w2[k], acc2);
      float dl = softplus_(acc2.x + acc2.y);
      dls += dl;
      float du = dl * __bfloat162float(u[base + (size_t)i * 512]);
      f32x2 du2; du2.x = du; du2.y = du;
#pragma unroll
      for (int k = 0; k < 8; ++k) {
        f32x2 a; a.x = exp2_(dl * A2[2 * k]); a.y = exp2_(dl * A2[2 * k + 1]);
        h2[k] = __builtin_elementwise_fma(a, h2[k], du2 * r2[8 + k]);
      }
    }
  }
  size_t sc = (size_t)(b * NCH + c) * 512 + d;
  dlsum[sc] = dls;
  float4* hpq = reinterpret_cast<float4*>(hp + sc * 16);
#pragma unroll
  for (int q = 0; q < 4; ++q)
    hpq[q] = make_float4(h2[2*q].x, h2[2*q].y, h2[2*q+1].x, h2[2*q+1].y);
}

// In-place: Hc overwrites hp (in-thread read-before-write per idx).
// Decay recomputed from dlsum: a = exp2(A2[n] * dlsum[b,c,d]).
__global__ __launch_bounds__(256) void scan_p2(
    float* hp, const float* __restrict__ dlsum,
    const float* __restrict__ A_log) {
  int g = blockIdx.x * 256 + threadIdx.x;
  int b = g >> 13;
  int dn = g & 8191;
  int d = dn >> 4;
  float A2n = -exp2_(A_log[dn] * L2E) * L2E;
  float H = 0.f;
  for (int c = 0; c < NCH; ++c) {
    float ds = dlsum[(size_t)(b * NCH + c) * 512 + d];
    size_t idx = (size_t)(b * NCH + c) * 8192 + dn;
    float p = hp[idx];
    float a = exp2_(A2n * ds);
    hp[idx] = H;
    H = fmaf(a, H, p);
  }
}

__global__ __launch_bounds__(256) void scan_p3(
    const __hip_bfloat16* u,  // aliases y (same-thread read-before-write)
    const float* __restrict__ xdbl, const float* __restrict__ A_log,
    const float* __restrict__ wdt, const float* __restrict__ bdt,
    const float* __restrict__ Hc, const float* __restrict__ Dp,
    const __hip_bfloat16* __restrict__ xz, __hip_bfloat16* y) {
  const int d = ((blockIdx.x & 1) << 8) + threadIdx.x;
  const int c = blockIdx.x >> 1;
  const int b = blockIdx.y;
  const int l0 = c * CHL;
  float A2[16];
  f32x2 w2[8];
  {
    const float4* aq = reinterpret_cast<const float4*>(&A_log[d * 16]);
    const f32x2* wq = reinterpret_cast<const f32x2*>(&wdt[d * 16]);
#pragma unroll
    for (int q = 0; q < 4; ++q) {
      float4 v = aq[q];
      A2[q * 4 + 0] = -exp2_(v.x * L2E) * L2E;
      A2[q * 4 + 1] = -exp2_(v.y * L2E) * L2E;
      A2[q * 4 + 2] = -exp2_(v.z * L2E) * L2E;
      A2[q * 4 + 3] = -exp2_(v.w * L2E) * L2E;
    }
#pragma unroll
    for (int k = 0; k < 8; ++k) w2[k] = wq[k];
  }
  bool chainok = true;
#pragma unroll
  for (int n = 1; n < 16; ++n)
    chainok = chainok &&
              (fabsf(A2[n] - (float)(n + 1) * A2[0]) <=
               1e-4f * (float)(n + 1) * fabsf(A2[0]));
  const float nL = A2[0];
  const float bdtd = bdt[d];
  f32x2 h2[8];
  {
    const f32x2* hq =
        reinterpret_cast<const f32x2*>(Hc + ((size_t)(b * NCH + c) * 512 + d) * 16);
#pragma unroll
    for (int k = 0; k < 8; ++k) h2[k] = hq[k];
  }
  const float Dpd = Dp[d];
  size_t base = (size_t)(b * SEQ + l0) * 512 + d;
  const float* rowp = xdbl + (size_t)(b * SEQ + l0) * 48;
  const __hip_bfloat16* zp = xz + (size_t)(b * SEQ + l0) * 1024 + 512 + d;
  if (chainok) {
#pragma unroll 4
    for (int i = 0; i < CHL; ++i) {
      const f32x2* r2 = reinterpret_cast<const f32x2*>(rowp + i * 48);
      f32x2 acc2; acc2.x = bdtd; acc2.y = 0.f;
#pragma unroll
      for (int k = 0; k < 8; ++k)
        acc2 = __builtin_elementwise_fma(r2[k], w2[k], acc2);
      float dl = softplus_(acc2.x + acc2.y);
      float ul = __bfloat162float(u[base + (size_t)i * 512]);
      float du = dl * ul;
      f32x2 p[8];
      powpairs_(exp2_(dl * nL), p);
      f32x2 du2; du2.x = du; du2.y = du;
      f32x2 yv2; yv2.x = 0.f; yv2.y = 0.f;
#pragma unroll
      for (int k = 0; k < 8; ++k) {
        h2[k] = __builtin_elementwise_fma(p[k], h2[k], du2 * r2[8 + k]);
        yv2 = __builtin_elementwise_fma(h2[k], r2[16 + k], yv2);
      }
      float yv = yv2.x + yv2.y;
      float zv = __bfloat162float(zp[(size_t)i * 1024]);
      y[base + (size_t)i * 512] =
          __float2bfloat16((yv + ul * Dpd) * silu_(zv));
    }
  } else {
#pragma unroll 2
    for (int i = 0; i < CHL; ++i) {
      const f32x2* r2 = reinterpret_cast<const f32x2*>(rowp + i * 48);
      f32x2 acc2; acc2.x = bdtd; acc2.y = 0.f;
#pragma unroll
      for (int k = 0; k < 8; ++k)
        acc2 = __builtin_elementwise_fma(r2[k], w2[k], acc2);
      float dl = softplus_(acc2.x + acc2.y);
      float ul = __bfloat162float(u[base + (size_t)i * 512]);
      float du = dl * ul;
      f32x2 du2; du2.x = du; du2.y = du;
      f32x2 yv2; yv2.x = 0.f; yv2.y = 0.f;
#pragma unroll
      for (int k = 0; k < 8; ++k) {
        f32x2 a; a.x = exp2_(dl * A2[2 * k]); a.y = exp2_(dl * A2[2 * k + 1]);
        h2[k] = __builtin_elementwise_fma(a, h2[k], du2 * r2[8 + k]);
        yv2 = __builtin_elementwise_fma(h2[k], r2[16 + k], yv2);
      }
      float yv = yv2.x + yv2.y;
      float zv = __bfloat162float(zp[(size_t)i * 1024]);
      y[base + (size_t)i * 512] =
          __float2bfloat16((yv + ul * Dpd) * silu_(zv));
    }
  }
}

// ---------------------------------------------------------------------------
// LayerNorm rows of 256, bf16 in -> bf16 out (1 wave/row).
// ---------------------------------------------------------------------------
__global__ __launch_bounds__(256) void ln_k(
    const __hip_bfloat16* __restrict__ in, const float* __restrict__ g,
    const float* __restrict__ bb, __hip_bfloat16* __restrict__ outb) {
  int row = (blockIdx.x * 256 + threadIdx.x) >> 6;
  int lane = threadIdx.x & 63;
  union { short4 s4; __hip_bfloat16 h[4]; } iv;
  iv.s4 = reinterpret_cast<const short4*>(in)[row * 64 + lane];
  float v0 = __bfloat162float(iv.h[0]), v1 = __bfloat162float(iv.h[1]);
  float v2 = __bfloat162float(iv.h[2]), v3 = __bfloat162float(iv.h[3]);
  float mu = wsum_(v0 + v1 + v2 + v3) * (1.f / 256.f);
  float a0 = v0 - mu, a1 = v1 - mu, a2 = v2 - mu, a3 = v3 - mu;
  float var = wsum_(a0 * a0 + a1 * a1 + a2 * a2 + a3 * a3) * (1.f / 256.f);
  float rs = __builtin_amdgcn_rsqf(var + 1e-5f);
  float4 gg = *reinterpret_cast<const float4*>(&g[lane * 4]);
  float4 bq = *reinterpret_cast<const float4*>(&bb[lane * 4]);
  union { __hip_bfloat16 h[4]; short4 s4; } u;
  u.h[0] = __float2bfloat16(a0 * rs * gg.x + bq.x);
  u.h[1] = __float2bfloat16(a1 * rs * gg.y + bq.y);
  u.h[2] = __float2bfloat16(a2 * rs * gg.z + bq.z);
  u.h[3] = __float2bfloat16(a3 * rs * gg.w + bq.w);
  reinterpret_cast<short4*>(outb)[row * 64 + lane] = u.s4;
}

// ---------------------------------------------------------------------------
// Final: LN2(t2 bf16) -> LN3 -> transpose (d,pn) -> + x_residual -> out.
// ---------------------------------------------------------------------------
__global__ __launch_bounds__(256) void final_k(
    const __hip_bfloat16* __restrict__ t2, const float* __restrict__ g2v,
    const float* __restrict__ b2v, const float* __restrict__ g3v,
    const float* __restrict__ b3v, const float* __restrict__ x,
    float* __restrict__ out) {
  int bx = blockIdx.x;
  int half = bx & 1, nv = (bx >> 1) & 31, b = bx >> 6;
  int wave = threadIdx.x >> 6, lane = threadIdx.x & 63;
  __shared__ float sh[32][257];
  float4 gg2 = *reinterpret_cast<const float4*>(&g2v[lane * 4]);
  float4 bb2 = *reinterpret_cast<const float4*>(&b2v[lane * 4]);
  float4 gg3 = *reinterpret_cast<const float4*>(&g3v[lane * 4]);
  float4 bb3 = *reinterpret_cast<const float4*>(&b3v[lane * 4]);
#pragma unroll
  for (int i = 0; i < 8; ++i) {
    int pn = wave * 8 + i;
    int r = ((b * 32 + nv) << 6) + (half << 5) + pn;
    union { short4 s4; __hip_bfloat16 h[4]; } iv;
    iv.s4 = reinterpret_cast<const short4*>(t2)[r * 64 + lane];
    float v0 = __bfloat162float(iv.h[0]), v1 = __bfloat162float(iv.h[1]);
    float v2 = __bfloat162float(iv.h[2]), v3 = __bfloat162float(iv.h[3]);
    float mu = wsum_(v0 + v1 + v2 + v3) * (1.f / 256.f);
    float a0 = v0 - mu, a1 = v1 - mu, a2 = v2 - mu, a3 = v3 - mu;
    float var = wsum_(a0 * a0 + a1 * a1 + a2 * a2 + a3 * a3) * (1.f / 256.f);
    float rs = __builtin_amdgcn_rsqf(var + 1e-5f);
    a0 = a0 * rs * gg2.x + bb2.x; a1 = a1 * rs * gg2.y + bb2.y;
    a2 = a2 * rs * gg2.z + bb2.z; a3 = a3 * rs * gg2.w + bb2.w;
    mu = wsum_(a0 + a1 + a2 + a3) * (1.f / 256.f);
    float c0 = a0 - mu, c1 = a1 - mu, c2 = a2 - mu, c3 = a3 - mu;
    var = wsum_(c0 * c0 + c1 * c1 + c2 * c2 + c3 * c3) * (1.f / 256.f);
    rs = __builtin_amdgcn_rsqf(var + 1e-5f);
    sh[pn][lane * 4 + 0] = c0 * rs * gg3.x + bb3.x;
    sh[pn][lane * 4 + 1] = c1 * rs * gg3.y + bb3.y;
    sh[pn][lane * 4 + 2] = c2 * rs * gg3.z + bb3.z;
    sh[pn][lane * 4 + 3] = c3 * rs * gg3.w + bb3.w;
  }
  __syncthreads();
  int pnl = threadIdx.x & 31;
  int dbase = threadIdx.x >> 5;
  size_t obase = (size_t)((b * 32 + nv) * 256) * 64 + (half << 5) + pnl;
#pragma unroll
  for (int k = 0; k < 32; ++k) {
    int dd = dbase + (k << 3);
    size_t oi = obase + (size_t)dd * 64;
    out[oi] = sh[pnl][dd] + x[oi];
  }
}

// ---------------------------------------------------------------------------
extern "C" void kernel_launch(void* const* d_in, const int* in_sizes, int n_in,
                              void* d_out, int out_size, void* d_ws,
                              size_t ws_size, hipStream_t stream) {
  const float* x    = (const float*)d_in[0];
  const float* w_in = (const float*)d_in[1];
  const float* b_in = (const float*)d_in[2];
  const float* cw   = (const float*)d_in[3];
  const float* cb   = (const float*)d_in[4];
  const float* wx   = (const float*)d_in[5];
  const float* wdt  = (const float*)d_in[6];
  const float* bdt  = (const float*)d_in[7];
  const float* alog = (const float*)d_in[8];
  const float* Dp   = (const float*)d_in[9];
  const float* wout = (const float*)d_in[10];
  const float* g1   = (const float*)d_in[11];
  const float* b1   = (const float*)d_in[12];
  const float* wf1  = (const float*)d_in[13];
  const float* bf1  = (const float*)d_in[14];
  const float* wf2  = (const float*)d_in[15];
  const float* bf2  = (const float*)d_in[16];
  const float* g2   = (const float*)d_in[17];
  const float* b2   = (const float*)d_in[18];
  const float* g3   = (const float*)d_in[19];
  const float* b3   = (const float*)d_in[20];
  float* out = (float*)d_out;

  const size_t MB1 = 1048576;
  char* g = (char*)d_ws;
  __hip_bfloat16* wbf_in  = (__hip_bfloat16*)(g);              // 512 KB
  __hip_bfloat16* wbf_out = (__hip_bfloat16*)(g + 524288);     // 256 KB
  __hip_bfloat16* wbf_f1  = (__hip_bfloat16*)(g + 786432);     // 256 KB
  __hip_bfloat16* wbf_f2  = (__hip_bfloat16*)(g + 1048576);    // 256 KB
  __hip_bfloat16* wbf_xp  = (__hip_bfloat16*)(g + 1310720);    // 128 KB
  const size_t SHARED = 1572864;

  // Regions/batch: RA 4MB (xz|t2b) | RB 1MB (xbf|dlsum) | RC 2MB (xi|ffny)
  //                RD 384KB (xdbl) | RE 2MB (hp/Hc | resb+h1bf)
  const size_t PB = 9 * MB1 + 393216;  // 9,830,400 B/batch
  int nb = (int)((ws_size - SHARED) / PB);
  if (ws_size <= SHARED || nb < 1) return;
  if (nb > NBTOT) nb = NBTOT;

  dim3 blk(256);
  cast_bf16_k<<<dim3(256), blk, 0, stream>>>(w_in, wbf_in, 65536);
  cast_bf16_k<<<dim3(128), blk, 0, stream>>>(wout, wbf_out, 32768);
  cast_bf16_k<<<dim3(128), blk, 0, stream>>>(wf1, wbf_f1, 32768);
  cast_bf16_k<<<dim3(128), blk, 0, stream>>>(wf2, wbf_f2, 32768);
  pad_wx_k<<<dim3(64), blk, 0, stream>>>(wx, wbf_xp);

  for (int b0 = 0; b0 < NBTOT; b0 += nb) {
    int bn = (NBTOT - b0 < nb) ? (NBTOT - b0) : nb;
    char* base = g + SHARED;
    char* RA = base;                          // bn*4MB
    char* RB = base + (size_t)bn * 4 * MB1;   // bn*1MB
    char* RC = base + (size_t)bn * 5 * MB1;   // bn*2MB
    char* RD = base + (size_t)bn * 7 * MB1;   // bn*384KB
    char* RE = RD + (size_t)bn * 393216;      // bn*2MB

    __hip_bfloat16* xz     = (__hip_bfloat16*)RA;
    __hip_bfloat16* t2b    = (__hip_bfloat16*)RA;
    __hip_bfloat16* xbf    = (__hip_bfloat16*)RB;
    float*          dlsum  = (float*)RB;
    __hip_bfloat16* xibf   = (__hip_bfloat16*)RC;
    __hip_bfloat16* ffnybf = (__hip_bfloat16*)RC;
    float*          xdbl   = (float*)RD;
    float*          hp     = (float*)RE;      // Hc in-place
    __hip_bfloat16* resb   = (__hip_bfloat16*)RE;
    __hip_bfloat16* h1bf   = (__hip_bfloat16*)(RE + (size_t)bn * MB1);

    const float* xg = x + (size_t)b0 * SEQ * 256;
    float* outg = out + (size_t)b0 * SEQ * 256;
    int M = bn * SEQ;
    int MT = M / 128;

    cast_bf16_k<<<dim3(M * 64 / 256), blk, 0, stream>>>(xg, xbf, M * 64);
    // in_proj merged (N=1024, K=256) -> xz bf16
    gemm_bf16<true, false, false, false, false, true>
        <<<dim3(8, MT), blk, 0, stream>>>(xbf, wbf_in, b_in, nullptr, nullptr,
                                          nullptr, xz, 1024, 256);
    conv_silu_k<<<dim3(M / 4), blk, 0, stream>>>(xz, cw, cb, xibf);
    gemm_bf16<false, false, false, false, true, false>
        <<<dim3(1, MT), blk, 0, stream>>>(xibf, wbf_xp, nullptr, nullptr,
                                          nullptr, xdbl, nullptr, 48, 512);
    scan_p1<<<dim3(NCH * 2, bn), blk, 0, stream>>>(xibf, xdbl, alog, wdt, bdt,
                                                   dlsum, hp);
    scan_p2<<<dim3(bn * 32), blk, 0, stream>>>(hp, dlsum, alog);
    scan_p3<<<dim3(NCH * 2, bn), blk, 0, stream>>>(xibf, xdbl, alog, wdt, bdt,
                                                   hp, Dp, xz, xibf);
    // out_proj + residual(x f32) -> resb bf16 (N=256, K=512)
    gemm_bf16<false, false, true, false, false, true>
        <<<dim3(2, MT), blk, 0, stream>>>(xibf, wbf_out, nullptr, xg, nullptr,
                                          nullptr, resb, 256, 512);
    ln_k<<<dim3(M / 4), blk, 0, stream>>>(resb, g1, b1, h1bf);
    // ffn1 + relu (N=512, K=256) -> ffnybf
    gemm_bf16<true, true, false, false, false, true>
        <<<dim3(4, MT), blk, 0, stream>>>(h1bf, wbf_f1, bf1, nullptr, nullptr,
                                          nullptr, ffnybf, 512, 256);
    // ffn2 + bias + residual(h1 bf16) -> t2b bf16 (N=256, K=512)
    gemm_bf16<true, false, false, true, false, true>
        <<<dim3(2, MT), blk, 0, stream>>>(ffnybf, wbf_f2, bf2, nullptr, h1bf,
                                          nullptr, t2b, 256, 512);
    final_k<<<dim3(bn * 64), blk, 0, stream>>>(t2b, g2, b2, g3, b3, xg, outg);
  }
}

// Round 9
// 303.086 us; speedup vs baseline: 3.3065x; 1.0538x over previous
//
#include <hip/hip_runtime.h>
#include <hip/hip_bf16.h>
#include <math.h>

#define SEQ    2048
#define NBTOT  16
#define NCH    64
#define CHL    32            // NCH*CHL == SEQ

#define L2E 1.4426950408889634f

typedef __attribute__((ext_vector_type(8))) __bf16 bf16x8;
typedef __attribute__((ext_vector_type(4))) float f32x4;
typedef __attribute__((ext_vector_type(2))) float f32x2;

#define GLOAD16(gp, lp)                                                   \
  __builtin_amdgcn_global_load_lds(                                       \
      (const __attribute__((address_space(1))) unsigned int*)(gp),        \
      (__attribute__((address_space(3))) unsigned int*)(lp), 16, 0, 0)

__device__ __forceinline__ float exp2_(float x) {
  return __builtin_amdgcn_exp2f(x);
}
__device__ __forceinline__ float silu_(float x) {
  return x * __builtin_amdgcn_rcpf(1.f + exp2_(-x * L2E));
}
__device__ __forceinline__ float softplus_(float x) {
  return fmaxf(x, 0.f) + __logf(1.f + exp2_(-fabsf(x) * L2E));
}
__device__ __forceinline__ float wsum_(float v) {
#pragma unroll
  for (int off = 32; off > 0; off >>= 1) v += __shfl_xor(v, off, 64);
  return v;
}
// p[k] = {e1^(2k+1), e1^(2k+2)}: 2 squares + 7 pk_mul, depth 4
__device__ __forceinline__ void powpairs_(float e1, f32x2 p[8]) {
  float e2 = e1 * e1;
  f32x2 p0; p0.x = e1; p0.y = e2;
  f32x2 s2; s2.x = e2; s2.y = e2;
  f32x2 s4 = s2 * s2;
  f32x2 s8 = s4 * s4;
  p[0] = p0;      p[1] = p0 * s2; p[2] = p0 * s4; p[3] = p[1] * s4;
  p[4] = p0 * s8; p[5] = p[1] * s8; p[6] = p[2] * s8; p[7] = p[3] * s8;
}

// ---------------------------------------------------------------------------
// bf16 MFMA GEMM (m97 structure): C[M,N] = A[M,K] @ W[N,K]^T
// (+bias)(+f32 res)(+bf16 res)(relu); f32 and/or bf16 out.
// ---------------------------------------------------------------------------
template <bool BIAS, bool RELU, bool RES, bool RESB, bool F32OUT, bool BF16OUT>
__global__ __launch_bounds__(256) void gemm_bf16(
    const __hip_bfloat16* __restrict__ A, const __hip_bfloat16* __restrict__ W,
    const float* __restrict__ bias, const float* __restrict__ res,
    const __hip_bfloat16* __restrict__ resb, float* __restrict__ C,
    __hip_bfloat16* __restrict__ Cb, int N, int K) {
  __shared__ __align__(16) short Als[128 * 64];
  __shared__ __align__(16) short Bls[128 * 64];
  const int tid = threadIdx.x;
  const int lane = tid & 63;
  const int wid = tid >> 6;
  const int m0 = blockIdx.y * 128;
  const int n0 = blockIdx.x * 128;
  const int wm = (wid >> 1) * 64;
  const int wn = (wid & 1) * 64;
  const int lr = lane & 15;
  const int lk = lane >> 4;  // 0..3

  f32x4 acc[4][4];
#pragma unroll
  for (int m = 0; m < 4; ++m)
#pragma unroll
    for (int n = 0; n < 4; ++n) acc[m][n] = (f32x4){0.f, 0.f, 0.f, 0.f};

  const int srow = wid * 32 + (lane >> 3);
  const int scol = (lane & 7) * 8;
  const __hip_bfloat16* Ag = A + (size_t)(m0 + srow) * K + scol;
  const __hip_bfloat16* Wg = W + (size_t)(n0 + srow) * K + scol;
  short* Alb = Als + wid * 2048;
  short* Blb = Bls + wid * 2048;

  for (int kt = 0; kt < K; kt += 64) {
#pragma unroll
    for (int i = 0; i < 4; ++i) {
      GLOAD16(Ag + (size_t)(i * 8) * K + kt, Alb + i * 512);
      GLOAD16(Wg + (size_t)(i * 8) * K + kt, Blb + i * 512);
    }
    __syncthreads();
    const bf16x8* Af = reinterpret_cast<const bf16x8*>(Als);
    const bf16x8* Bf = reinterpret_cast<const bf16x8*>(Bls);
#pragma unroll
    for (int ks = 0; ks < 2; ++ks) {
      bf16x8 av[4], bv[4];
#pragma unroll
      for (int m = 0; m < 4; ++m)
        av[m] = Af[(wm + m * 16 + lr) * 8 + ks * 4 + lk];
#pragma unroll
      for (int n = 0; n < 4; ++n)
        bv[n] = Bf[(wn + n * 16 + lr) * 8 + ks * 4 + lk];
#pragma unroll
      for (int m = 0; m < 4; ++m)
#pragma unroll
        for (int n = 0; n < 4; ++n)
          acc[m][n] = __builtin_amdgcn_mfma_f32_16x16x32_bf16(
              av[m], bv[n], acc[m][n], 0, 0, 0);
    }
    __syncthreads();
  }

#pragma unroll
  for (int n = 0; n < 4; ++n) {
    int col = n0 + wn + n * 16 + lr;
    if (col >= N) continue;
    float bval = BIAS ? bias[col] : 0.f;
#pragma unroll
    for (int m = 0; m < 4; ++m) {
      int row0 = m0 + wm + m * 16 + lk * 4;
#pragma unroll
      for (int r = 0; r < 4; ++r) {
        size_t off = (size_t)(row0 + r) * N + col;
        float v = acc[m][n][r];
        if (BIAS) v += bval;
        if (RES) v += res[off];
        if (RESB) v += __bfloat162float(resb[off]);
        if (RELU) v = fmaxf(v, 0.f);
        if (F32OUT) C[off] = v;
        if (BF16OUT) Cb[off] = __float2bfloat16(v);
      }
    }
  }
}

// ---------------------------------------------------------------------------
__global__ __launch_bounds__(256) void cast_bf16_k(
    const float* __restrict__ src, __hip_bfloat16* __restrict__ dst, int n4) {
  int i = blockIdx.x * 256 + threadIdx.x;
  if (i >= n4) return;
  float4 v = reinterpret_cast<const float4*>(src)[i];
  union { __hip_bfloat16 h[4]; short4 s4; } u;
  u.h[0] = __float2bfloat16(v.x); u.h[1] = __float2bfloat16(v.y);
  u.h[2] = __float2bfloat16(v.z); u.h[3] = __float2bfloat16(v.w);
  reinterpret_cast<short4*>(dst)[i] = u.s4;
}

__global__ __launch_bounds__(256) void pad_wx_k(
    const float* __restrict__ src, __hip_bfloat16* __restrict__ dst) {
  int i = blockIdx.x * 256 + threadIdx.x;
  int row = i >> 7;
  union { __hip_bfloat16 h[4]; short4 s4; } u;
  if (row < 48) {
    float4 v = reinterpret_cast<const float4*>(src)[i];
    u.h[0] = __float2bfloat16(v.x); u.h[1] = __float2bfloat16(v.y);
    u.h[2] = __float2bfloat16(v.z); u.h[3] = __float2bfloat16(v.w);
  } else {
    u.h[0] = u.h[1] = u.h[2] = u.h[3] = __float2bfloat16(0.f);
  }
  reinterpret_cast<short4*>(dst)[i] = u.s4;
}

// ---------------------------------------------------------------------------
// Depthwise causal conv (D_CONV=4) + SiLU. In: xz (rows, 1024) cols 0..511.
// ---------------------------------------------------------------------------
__global__ __launch_bounds__(256) void conv_silu_k(
    const __hip_bfloat16* __restrict__ xz, const float* __restrict__ cw,
    const float* __restrict__ cb, __hip_bfloat16* __restrict__ xi) {
  int idx = blockIdx.x * 256 + threadIdx.x;  // r*64 + t
  int t = idx & 63;
  int r = idx >> 6;
  int l = r & (SEQ - 1);
  int c8 = t << 3;
  const __hip_bfloat16* p = xz + (size_t)r * 1024 + c8;
  union U8 { int4 v; __hip_bfloat16 h[8]; } x0, x1, x2, x3, o;
  const int4 z4 = make_int4(0, 0, 0, 0);
  x3.v = *reinterpret_cast<const int4*>(p);
  x2.v = (l >= 1) ? *reinterpret_cast<const int4*>(p - 1024) : z4;
  x1.v = (l >= 2) ? *reinterpret_cast<const int4*>(p - 2048) : z4;
  x0.v = (l >= 3) ? *reinterpret_cast<const int4*>(p - 3072) : z4;
  const float4* cw4 = reinterpret_cast<const float4*>(cw);
#pragma unroll
  for (int j = 0; j < 8; ++j) {
    float4 w = cw4[c8 + j];
    float acc = cb[c8 + j];
    acc = fmaf(w.x, __bfloat162float(x0.h[j]), acc);
    acc = fmaf(w.y, __bfloat162float(x1.h[j]), acc);
    acc = fmaf(w.z, __bfloat162float(x2.h[j]), acc);
    acc = fmaf(w.w, __bfloat162float(x3.h[j]), acc);
    o.h[j] = __float2bfloat16(silu_(acc));
  }
  reinterpret_cast<int4*>(xi)[idx] = o.v;
}

// ---------------------------------------------------------------------------
// Chunked selective scan. No LDS; xdbl rows wave-uniform -> SMEM loads in p1;
// packed f32x2 math. p1 stores hp (bf16) + dlsum + delta (bf16).
// p3 reads delta, no dot/softplus. A_log power-chain verified at runtime.
// grid: (2*NCH, bn); d = (blockIdx.x&1)*256 + tid, c = blockIdx.x>>1.
// ---------------------------------------------------------------------------
__global__ __launch_bounds__(256) void scan_p1(
    const __hip_bfloat16* __restrict__ u, const float* __restrict__ xdbl,
    const float* __restrict__ A_log, const float* __restrict__ wdt,
    const float* __restrict__ bdt, float* __restrict__ dlsum,
    __hip_bfloat16* __restrict__ hp, __hip_bfloat16* __restrict__ deltab) {
  const int d = ((blockIdx.x & 1) << 8) + threadIdx.x;
  const int c = blockIdx.x >> 1;
  const int b = blockIdx.y;
  const int l0 = c * CHL;
  float A2[16];
  f32x2 w2[8];
  {
    const float4* aq = reinterpret_cast<const float4*>(&A_log[d * 16]);
    const f32x2* wq = reinterpret_cast<const f32x2*>(&wdt[d * 16]);
#pragma unroll
    for (int q = 0; q < 4; ++q) {
      float4 v = aq[q];
      A2[q * 4 + 0] = -exp2_(v.x * L2E) * L2E;
      A2[q * 4 + 1] = -exp2_(v.y * L2E) * L2E;
      A2[q * 4 + 2] = -exp2_(v.z * L2E) * L2E;
      A2[q * 4 + 3] = -exp2_(v.w * L2E) * L2E;
    }
#pragma unroll
    for (int k = 0; k < 8; ++k) w2[k] = wq[k];
  }
  bool chainok = true;
#pragma unroll
  for (int n = 1; n < 16; ++n)
    chainok = chainok &&
              (fabsf(A2[n] - (float)(n + 1) * A2[0]) <=
               1e-4f * (float)(n + 1) * fabsf(A2[0]));
  const float bdtd = bdt[d];
  const float nL = A2[0];
  f32x2 h2[8];
#pragma unroll
  for (int k = 0; k < 8; ++k) h2[k] = (f32x2){0.f, 0.f};
  float dls = 0.f;
  size_t base = (size_t)(b * SEQ + l0) * 512 + d;
  const float* rowp = xdbl + (size_t)(b * SEQ + l0) * 48;
  if (chainok) {
#pragma unroll 4
    for (int i = 0; i < CHL; ++i) {
      const f32x2* r2 = reinterpret_cast<const f32x2*>(rowp + i * 48);
      f32x2 acc2; acc2.x = bdtd; acc2.y = 0.f;
#pragma unroll
      for (int k = 0; k < 8; ++k)
        acc2 = __builtin_elementwise_fma(r2[k], w2[k], acc2);
      float dl = softplus_(acc2.x + acc2.y);
      deltab[base + (size_t)i * 512] = __float2bfloat16(dl);
      dls += dl;
      float du = dl * __bfloat162float(u[base + (size_t)i * 512]);
      f32x2 p[8];
      powpairs_(exp2_(dl * nL), p);
      f32x2 du2; du2.x = du; du2.y = du;
#pragma unroll
      for (int k = 0; k < 8; ++k)
        h2[k] = __builtin_elementwise_fma(p[k], h2[k], du2 * r2[8 + k]);
    }
  } else {
#pragma unroll 2
    for (int i = 0; i < CHL; ++i) {
      const f32x2* r2 = reinterpret_cast<const f32x2*>(rowp + i * 48);
      f32x2 acc2; acc2.x = bdtd; acc2.y = 0.f;
#pragma unroll
      for (int k = 0; k < 8; ++k)
        acc2 = __builtin_elementwise_fma(r2[k], w2[k], acc2);
      float dl = softplus_(acc2.x + acc2.y);
      deltab[base + (size_t)i * 512] = __float2bfloat16(dl);
      dls += dl;
      float du = dl * __bfloat162float(u[base + (size_t)i * 512]);
      f32x2 du2; du2.x = du; du2.y = du;
#pragma unroll
      for (int k = 0; k < 8; ++k) {
        f32x2 a; a.x = exp2_(dl * A2[2 * k]); a.y = exp2_(dl * A2[2 * k + 1]);
        h2[k] = __builtin_elementwise_fma(a, h2[k], du2 * r2[8 + k]);
      }
    }
  }
  size_t sc = (size_t)(b * NCH + c) * 512 + d;
  dlsum[sc] = dls;
  union { __hip_bfloat16 h[4]; short4 s4; } o0, o1, o2, o3;
#pragma unroll
  for (int j = 0; j < 2; ++j) {
    o0.h[2*j] = __float2bfloat16(h2[j].x);   o0.h[2*j+1] = __float2bfloat16(h2[j].y);
    o1.h[2*j] = __float2bfloat16(h2[2+j].x); o1.h[2*j+1] = __float2bfloat16(h2[2+j].y);
    o2.h[2*j] = __float2bfloat16(h2[4+j].x); o2.h[2*j+1] = __float2bfloat16(h2[4+j].y);
    o3.h[2*j] = __float2bfloat16(h2[6+j].x); o3.h[2*j+1] = __float2bfloat16(h2[6+j].y);
  }
  short4* hq = reinterpret_cast<short4*>(hp + sc * 16);
  hq[0] = o0.s4; hq[1] = o1.s4; hq[2] = o2.s4; hq[3] = o3.s4;
}

// In-place: Hc overwrites hp (in-thread read-before-write per idx).
__global__ __launch_bounds__(256) void scan_p2(
    __hip_bfloat16* hp, const float* __restrict__ dlsum,
    const float* __restrict__ A_log) {
  int g = blockIdx.x * 256 + threadIdx.x;
  int b = g >> 13;
  int dn = g & 8191;
  int d = dn >> 4;
  float A2n = -exp2_(A_log[dn] * L2E) * L2E;
  float H = 0.f;
  for (int c = 0; c < NCH; ++c) {
    float ds = dlsum[(size_t)(b * NCH + c) * 512 + d];
    size_t idx = (size_t)(b * NCH + c) * 8192 + dn;
    float p = __bfloat162float(hp[idx]);
    float a = exp2_(A2n * ds);
    hp[idx] = __float2bfloat16(H);
    H = fmaf(a, H, p);
  }
}

__global__ __launch_bounds__(256) void scan_p3(
    const __hip_bfloat16* u,  // aliases y (same-thread read-before-write)
    const float* __restrict__ A_log,
    const __hip_bfloat16* __restrict__ deltab, const float* __restrict__ xdbl,
    const __hip_bfloat16* __restrict__ Hc, const float* __restrict__ Dp,
    const __hip_bfloat16* __restrict__ xz, __hip_bfloat16* y) {
  const int d = ((blockIdx.x & 1) << 8) + threadIdx.x;
  const int c = blockIdx.x >> 1;
  const int b = blockIdx.y;
  const int l0 = c * CHL;
  float A2[16];
  {
    const float4* aq = reinterpret_cast<const float4*>(&A_log[d * 16]);
#pragma unroll
    for (int q = 0; q < 4; ++q) {
      float4 v = aq[q];
      A2[q * 4 + 0] = -exp2_(v.x * L2E) * L2E;
      A2[q * 4 + 1] = -exp2_(v.y * L2E) * L2E;
      A2[q * 4 + 2] = -exp2_(v.z * L2E) * L2E;
      A2[q * 4 + 3] = -exp2_(v.w * L2E) * L2E;
    }
  }
  bool chainok = true;
#pragma unroll
  for (int n = 1; n < 16; ++n)
    chainok = chainok &&
              (fabsf(A2[n] - (float)(n + 1) * A2[0]) <=
               1e-4f * (float)(n + 1) * fabsf(A2[0]));
  const float nL = A2[0];
  f32x2 h2[8];
  {
    const short4* hq =
        reinterpret_cast<const short4*>(Hc + ((size_t)(b * NCH + c) * 512 + d) * 16);
#pragma unroll
    for (int q = 0; q < 4; ++q) {
      union { short4 s4; __hip_bfloat16 h[4]; } iv;
      iv.s4 = hq[q];
      h2[2*q].x = __bfloat162float(iv.h[0]);
      h2[2*q].y = __bfloat162float(iv.h[1]);
      h2[2*q+1].x = __bfloat162float(iv.h[2]);
      h2[2*q+1].y = __bfloat162float(iv.h[3]);
    }
  }
  const float Dpd = Dp[d];
  size_t base = (size_t)(b * SEQ + l0) * 512 + d;
  const float* rowp = xdbl + (size_t)(b * SEQ + l0) * 48;
  const __hip_bfloat16* zp = xz + (size_t)(b * SEQ + l0) * 1024 + 512 + d;
  if (chainok) {
#pragma unroll 4
    for (int i = 0; i < CHL; ++i) {
      const f32x2* r2 = reinterpret_cast<const f32x2*>(rowp + i * 48);
      float dl = __bfloat162float(deltab[base + (size_t)i * 512]);
      float ul = __bfloat162float(u[base + (size_t)i * 512]);
      float du = dl * ul;
      f32x2 p[8];
      powpairs_(exp2_(dl * nL), p);
      f32x2 du2; du2.x = du; du2.y = du;
      f32x2 yv2; yv2.x = 0.f; yv2.y = 0.f;
#pragma unroll
      for (int k = 0; k < 8; ++k) {
        h2[k] = __builtin_elementwise_fma(p[k], h2[k], du2 * r2[8 + k]);
        yv2 = __builtin_elementwise_fma(h2[k], r2[16 + k], yv2);
      }
      float yv = yv2.x + yv2.y;
      float zv = __bfloat162float(zp[(size_t)i * 1024]);
      y[base + (size_t)i * 512] =
          __float2bfloat16((yv + ul * Dpd) * silu_(zv));
    }
  } else {
#pragma unroll 2
    for (int i = 0; i < CHL; ++i) {
      const f32x2* r2 = reinterpret_cast<const f32x2*>(rowp + i * 48);
      float dl = __bfloat162float(deltab[base + (size_t)i * 512]);
      float ul = __bfloat162float(u[base + (size_t)i * 512]);
      float du = dl * ul;
      f32x2 du2; du2.x = du; du2.y = du;
      f32x2 yv2; yv2.x = 0.f; yv2.y = 0.f;
#pragma unroll
      for (int k = 0; k < 8; ++k) {
        f32x2 a; a.x = exp2_(dl * A2[2 * k]); a.y = exp2_(dl * A2[2 * k + 1]);
        h2[k] = __builtin_elementwise_fma(a, h2[k], du2 * r2[8 + k]);
        yv2 = __builtin_elementwise_fma(h2[k], r2[16 + k], yv2);
      }
      float yv = yv2.x + yv2.y;
      float zv = __bfloat162float(zp[(size_t)i * 1024]);
      y[base + (size_t)i * 512] =
          __float2bfloat16((yv + ul * Dpd) * silu_(zv));
    }
  }
}

// ---------------------------------------------------------------------------
__global__ __launch_bounds__(256) void ln_k(
    const __hip_bfloat16* __restrict__ in, const float* __restrict__ g,
    const float* __restrict__ bb, __hip_bfloat16* __restrict__ outb) {
  int row = (blockIdx.x * 256 + threadIdx.x) >> 6;
  int lane = threadIdx.x & 63;
  union { short4 s4; __hip_bfloat16 h[4]; } iv;
  iv.s4 = reinterpret_cast<const short4*>(in)[row * 64 + lane];
  float v0 = __bfloat162float(iv.h[0]), v1 = __bfloat162float(iv.h[1]);
  float v2 = __bfloat162float(iv.h[2]), v3 = __bfloat162float(iv.h[3]);
  float mu = wsum_(v0 + v1 + v2 + v3) * (1.f / 256.f);
  float a0 = v0 - mu, a1 = v1 - mu, a2 = v2 - mu, a3 = v3 - mu;
  float var = wsum_(a0 * a0 + a1 * a1 + a2 * a2 + a3 * a3) * (1.f / 256.f);
  float rs = __builtin_amdgcn_rsqf(var + 1e-5f);
  float4 gg = *reinterpret_cast<const float4*>(&g[lane * 4]);
  float4 bq = *reinterpret_cast<const float4*>(&bb[lane * 4]);
  union { __hip_bfloat16 h[4]; short4 s4; } u;
  u.h[0] = __float2bfloat16(a0 * rs * gg.x + bq.x);
  u.h[1] = __float2bfloat16(a1 * rs * gg.y + bq.y);
  u.h[2] = __float2bfloat16(a2 * rs * gg.z + bq.z);
  u.h[3] = __float2bfloat16(a3 * rs * gg.w + bq.w);
  reinterpret_cast<short4*>(outb)[row * 64 + lane] = u.s4;
}

// ---------------------------------------------------------------------------
__global__ __launch_bounds__(256) void final_k(
    const __hip_bfloat16* __restrict__ t2, const float* __restrict__ g2v,
    const float* __restrict__ b2v, const float* __restrict__ g3v,
    const float* __restrict__ b3v, const float* __restrict__ x,
    float* __restrict__ out) {
  int bx = blockIdx.x;
  int half = bx & 1, nv = (bx >> 1) & 31, b = bx >> 6;
  int wave = threadIdx.x >> 6, lane = threadIdx.x & 63;
  __shared__ float sh[32][257];
  float4 gg2 = *reinterpret_cast<const float4*>(&g2v[lane * 4]);
  float4 bb2 = *reinterpret_cast<const float4*>(&b2v[lane * 4]);
  float4 gg3 = *reinterpret_cast<const float4*>(&g3v[lane * 4]);
  float4 bb3 = *reinterpret_cast<const float4*>(&b3v[lane * 4]);
#pragma unroll
  for (int i = 0; i < 8; ++i) {
    int pn = wave * 8 + i;
    int r = ((b * 32 + nv) << 6) + (half << 5) + pn;
    union { short4 s4; __hip_bfloat16 h[4]; } iv;
    iv.s4 = reinterpret_cast<const short4*>(t2)[r * 64 + lane];
    float v0 = __bfloat162float(iv.h[0]), v1 = __bfloat162float(iv.h[1]);
    float v2 = __bfloat162float(iv.h[2]), v3 = __bfloat162float(iv.h[3]);
    float mu = wsum_(v0 + v1 + v2 + v3) * (1.f / 256.f);
    float a0 = v0 - mu, a1 = v1 - mu, a2 = v2 - mu, a3 = v3 - mu;
    float var = wsum_(a0 * a0 + a1 * a1 + a2 * a2 + a3 * a3) * (1.f / 256.f);
    float rs = __builtin_amdgcn_rsqf(var + 1e-5f);
    a0 = a0 * rs * gg2.x + bb2.x; a1 = a1 * rs * gg2.y + bb2.y;
    a2 = a2 * rs * gg2.z + bb2.z; a3 = a3 * rs * gg2.w + bb2.w;
    mu = wsum_(a0 + a1 + a2 + a3) * (1.f / 256.f);
    float c0 = a0 - mu, c1 = a1 - mu, c2 = a2 - mu, c3 = a3 - mu;
    var = wsum_(c0 * c0 + c1 * c1 + c2 * c2 + c3 * c3) * (1.f / 256.f);
    rs = __builtin_amdgcn_rsqf(var + 1e-5f);
    sh[pn][lane * 4 + 0] = c0 * rs * gg3.x + bb3.x;
    sh[pn][lane * 4 + 1] = c1 * rs * gg3.y + bb3.y;
    sh[pn][lane * 4 + 2] = c2 * rs * gg3.z + bb3.z;
    sh[pn][lane * 4 + 3] = c3 * rs * gg3.w + bb3.w;
  }
  __syncthreads();
  int pnl = threadIdx.x & 31;
  int dbase = threadIdx.x >> 5;
  size_t obase = (size_t)((b * 32 + nv) * 256) * 64 + (half << 5) + pnl;
#pragma unroll
  for (int k = 0; k < 32; ++k) {
    int dd = dbase + (k << 3);
    size_t oi = obase + (size_t)dd * 64;
    out[oi] = sh[pnl][dd] + x[oi];
  }
}

// ---------------------------------------------------------------------------
extern "C" void kernel_launch(void* const* d_in, const int* in_sizes, int n_in,
                              void* d_out, int out_size, void* d_ws,
                              size_t ws_size, hipStream_t stream) {
  const float* x    = (const float*)d_in[0];
  const float* w_in = (const float*)d_in[1];
  const float* b_in = (const float*)d_in[2];
  const float* cw   = (const float*)d_in[3];
  const float* cb   = (const float*)d_in[4];
  const float* wx   = (const float*)d_in[5];
  const float* wdt  = (const float*)d_in[6];
  const float* bdt  = (const float*)d_in[7];
  const float* alog = (const float*)d_in[8];
  const float* Dp   = (const float*)d_in[9];
  const float* wout = (const float*)d_in[10];
  const float* g1   = (const float*)d_in[11];
  const float* b1   = (const float*)d_in[12];
  const float* wf1  = (const float*)d_in[13];
  const float* bf1  = (const float*)d_in[14];
  const float* wf2  = (const float*)d_in[15];
  const float* bf2  = (const float*)d_in[16];
  const float* g2   = (const float*)d_in[17];
  const float* b2   = (const float*)d_in[18];
  const float* g3   = (const float*)d_in[19];
  const float* b3   = (const float*)d_in[20];
  float* out = (float*)d_out;

  const size_t MB1 = 1048576;
  char* g = (char*)d_ws;
  __hip_bfloat16* wbf_in  = (__hip_bfloat16*)(g);              // 512 KB
  __hip_bfloat16* wbf_out = (__hip_bfloat16*)(g + 524288);     // 256 KB
  __hip_bfloat16* wbf_f1  = (__hip_bfloat16*)(g + 786432);     // 256 KB
  __hip_bfloat16* wbf_f2  = (__hip_bfloat16*)(g + 1048576);    // 256 KB
  __hip_bfloat16* wbf_xp  = (__hip_bfloat16*)(g + 1310720);    // 128 KB
  const size_t SHARED = 1572864;

  // Regions/batch: RA 4MB (xz|t2b) | RB 1MB (xbf|dlsum) | RC 2MB (xi|ffny)
  //   RD 384KB (xdbl) | RE 2MB (hp bf16 | resb+h1bf) | RF 2MB (deltab)
  const size_t PB = 11 * MB1 + 393216;  // 11,927,552 B/batch
  int nb = (int)((ws_size - SHARED) / PB);
  if (ws_size <= SHARED || nb < 1) return;
  if (nb > NBTOT) nb = NBTOT;

  dim3 blk(256);
  cast_bf16_k<<<dim3(256), blk, 0, stream>>>(w_in, wbf_in, 65536);
  cast_bf16_k<<<dim3(128), blk, 0, stream>>>(wout, wbf_out, 32768);
  cast_bf16_k<<<dim3(128), blk, 0, stream>>>(wf1, wbf_f1, 32768);
  cast_bf16_k<<<dim3(128), blk, 0, stream>>>(wf2, wbf_f2, 32768);
  pad_wx_k<<<dim3(64), blk, 0, stream>>>(wx, wbf_xp);

  for (int b0 = 0; b0 < NBTOT; b0 += nb) {
    int bn = (NBTOT - b0 < nb) ? (NBTOT - b0) : nb;
    char* base = g + SHARED;
    char* RA = base;                          // bn*4MB
    char* RB = base + (size_t)bn * 4 * MB1;   // bn*1MB
    char* RC = base + (size_t)bn * 5 * MB1;   // bn*2MB
    char* RD = base + (size_t)bn * 7 * MB1;   // bn*384KB
    char* RE = RD + (size_t)bn * 393216;      // bn*2MB
    char* RF = RE + (size_t)bn * 2 * MB1;     // bn*2MB

    __hip_bfloat16* xz     = (__hip_bfloat16*)RA;
    __hip_bfloat16* t2b    = (__hip_bfloat16*)RA;
    __hip_bfloat16* xbf    = (__hip_bfloat16*)RB;
    float*          dlsum  = (float*)RB;
    __hip_bfloat16* xibf   = (__hip_bfloat16*)RC;
    __hip_bfloat16* ffnybf = (__hip_bfloat16*)RC;
    float*          xdbl   = (float*)RD;
    __hip_bfloat16* hp     = (__hip_bfloat16*)RE;   // Hc in-place (bf16)
    __hip_bfloat16* resb   = (__hip_bfloat16*)RE;   // after scan
    __hip_bfloat16* h1bf   = (__hip_bfloat16*)(RE + (size_t)bn * MB1);
    __hip_bfloat16* deltab = (__hip_bfloat16*)RF;

    const float* xg = x + (size_t)b0 * SEQ * 256;
    float* outg = out + (size_t)b0 * SEQ * 256;
    int M = bn * SEQ;
    int MT = M / 128;

    cast_bf16_k<<<dim3(M * 64 / 256), blk, 0, stream>>>(xg, xbf, M * 64);
    gemm_bf16<true, false, false, false, false, true>
        <<<dim3(8, MT), blk, 0, stream>>>(xbf, wbf_in, b_in, nullptr, nullptr,
                                          nullptr, xz, 1024, 256);
    conv_silu_k<<<dim3(M / 4), blk, 0, stream>>>(xz, cw, cb, xibf);
    gemm_bf16<false, false, false, false, true, false>
        <<<dim3(1, MT), blk, 0, stream>>>(xibf, wbf_xp, nullptr, nullptr,
                                          nullptr, xdbl, nullptr, 48, 512);
    scan_p1<<<dim3(NCH * 2, bn), blk, 0, stream>>>(xibf, xdbl, alog, wdt, bdt,
                                                   dlsum, hp, deltab);
    scan_p2<<<dim3(bn * 32), blk, 0, stream>>>(hp, dlsum, alog);
    scan_p3<<<dim3(NCH * 2, bn), blk, 0, stream>>>(xibf, alog, deltab, xdbl,
                                                   hp, Dp, xz, xibf);
    gemm_bf16<false, false, true, false, false, true>
        <<<dim3(2, MT), blk, 0, stream>>>(xibf, wbf_out, nullptr, xg, nullptr,
                                          nullptr, resb, 256, 512);
    ln_k<<<dim3(M / 4), blk, 0, stream>>>(resb, g1, b1, h1bf);
    gemm_bf16<true, true, false, false, false, true>
        <<<dim3(4, MT), blk, 0, stream>>>(h1bf, wbf_f1, bf1, nullptr, nullptr,
                                          nullptr, ffnybf, 512, 256);
    gemm_bf16<true, false, false, true, false, true>
        <<<dim3(2, MT), blk, 0, stream>>>(ffnybf, wbf_f2, bf2, nullptr, h1bf,
                                          nullptr, t2b, 256, 512);
    final_k<<<dim3(bn * 64), blk, 0, stream>>>(t2b, g2, b2, g3, b3, xg, outg);
  }
}

// Round 10
// 280.056 us; speedup vs baseline: 3.5784x; 1.0822x over previous
//
#include <hip/hip_runtime.h>
#include <hip/hip_bf16.h>
#include <math.h>

#define SEQ    2048
#define NBTOT  16
#define NCH    64
#define CHL    32            // NCH*CHL == SEQ

#define L2E 1.4426950408889634f

typedef __attribute__((ext_vector_type(8))) __bf16 bf16x8;
typedef __attribute__((ext_vector_type(4))) float f32x4;
typedef __attribute__((ext_vector_type(2))) float f32x2;

#define GLOAD16(gp, lp)                                                   \
  __builtin_amdgcn_global_load_lds(                                       \
      (const __attribute__((address_space(1))) unsigned int*)(gp),        \
      (__attribute__((address_space(3))) unsigned int*)(lp), 16, 0, 0)

__device__ __forceinline__ float exp2_(float x) {
  return __builtin_amdgcn_exp2f(x);
}
__device__ __forceinline__ float silu_(float x) {
  return x * __builtin_amdgcn_rcpf(1.f + exp2_(-x * L2E));
}
__device__ __forceinline__ float softplus_(float x) {
  return fmaxf(x, 0.f) + __logf(1.f + exp2_(-fabsf(x) * L2E));
}
__device__ __forceinline__ float wsum_(float v) {
#pragma unroll
  for (int off = 32; off > 0; off >>= 1) v += __shfl_xor(v, off, 64);
  return v;
}
// p[k] = {e1^(2k+1), e1^(2k+2)}: 2 squares + 7 pk_mul, depth 4
__device__ __forceinline__ void powpairs_(float e1, f32x2 p[8]) {
  float e2 = e1 * e1;
  f32x2 p0; p0.x = e1; p0.y = e2;
  f32x2 s2; s2.x = e2; s2.y = e2;
  f32x2 s4 = s2 * s2;
  f32x2 s8 = s4 * s4;
  p[0] = p0;      p[1] = p0 * s2; p[2] = p0 * s4; p[3] = p[1] * s4;
  p[4] = p0 * s8; p[5] = p[1] * s8; p[6] = p[2] * s8; p[7] = p[3] * s8;
}

// ---------------------------------------------------------------------------
// bf16 MFMA GEMM (m97 structure) + XCD-chunk swizzle (T1) + LDS-bounce
// vectorized bf16 epilogue. C[M,N] = A[M,K] @ W[N,K]^T.
// 1-D grid, nwg = NT*MT (mult of 8); tile = (swz>>NTlog, swz & (NT-1)).
// BF16OUT requires N % 128 == 0 (all callers satisfy); F32OUT masks col.
// ---------------------------------------------------------------------------
template <bool BIAS, bool RELU, bool RES, bool RESB, bool F32OUT, bool BF16OUT,
          int NTLOG>
__global__ __launch_bounds__(256) void gemm_bf16(
    const __hip_bfloat16* __restrict__ A, const __hip_bfloat16* __restrict__ W,
    const float* __restrict__ bias, const float* __restrict__ res,
    const __hip_bfloat16* __restrict__ resb, float* __restrict__ C,
    __hip_bfloat16* __restrict__ Cb, int N, int K) {
  // 36864 B: staging (32768) and epilogue (4 waves x 64 rows x 72 shorts)
  __shared__ __align__(16) char ShRaw[36864];
  short* Als = reinterpret_cast<short*>(ShRaw);
  short* Bls = Als + 8192;
  const int tid = threadIdx.x;
  const int lane = tid & 63;
  const int wid = tid >> 6;
  // XCD-chunk swizzle: round-robin blockIdx -> contiguous swz per XCD
  const int nwg = gridDim.x;
  const int swz = (blockIdx.x & 7) * (nwg >> 3) + (blockIdx.x >> 3);
  const int m0 = (swz >> NTLOG) * 128;
  const int n0 = (swz & ((1 << NTLOG) - 1)) * 128;
  const int wm = (wid >> 1) * 64;
  const int wn = (wid & 1) * 64;
  const int lr = lane & 15;
  const int lk = lane >> 4;  // 0..3

  f32x4 acc[4][4];
#pragma unroll
  for (int m = 0; m < 4; ++m)
#pragma unroll
    for (int n = 0; n < 4; ++n) acc[m][n] = (f32x4){0.f, 0.f, 0.f, 0.f};

  const int srow = wid * 32 + (lane >> 3);
  const int scol = (lane & 7) * 8;
  const __hip_bfloat16* Ag = A + (size_t)(m0 + srow) * K + scol;
  const __hip_bfloat16* Wg = W + (size_t)(n0 + srow) * K + scol;
  short* Alb = Als + wid * 2048;
  short* Blb = Bls + wid * 2048;

  for (int kt = 0; kt < K; kt += 64) {
#pragma unroll
    for (int i = 0; i < 4; ++i) {
      GLOAD16(Ag + (size_t)(i * 8) * K + kt, Alb + i * 512);
      GLOAD16(Wg + (size_t)(i * 8) * K + kt, Blb + i * 512);
    }
    __syncthreads();
    const bf16x8* Af = reinterpret_cast<const bf16x8*>(Als);
    const bf16x8* Bf = reinterpret_cast<const bf16x8*>(Bls);
#pragma unroll
    for (int ks = 0; ks < 2; ++ks) {
      bf16x8 av[4], bv[4];
#pragma unroll
      for (int m = 0; m < 4; ++m)
        av[m] = Af[(wm + m * 16 + lr) * 8 + ks * 4 + lk];
#pragma unroll
      for (int n = 0; n < 4; ++n)
        bv[n] = Bf[(wn + n * 16 + lr) * 8 + ks * 4 + lk];
#pragma unroll
      for (int m = 0; m < 4; ++m)
#pragma unroll
        for (int n = 0; n < 4; ++n)
          acc[m][n] = __builtin_amdgcn_mfma_f32_16x16x32_bf16(
              av[m], bv[n], acc[m][n], 0, 0, 0);
    }
    __syncthreads();  // after this, staging LDS is dead -> epilogue reuse
  }

  if (BF16OUT) {
    // per-wave 64x64 bf16 bounce, row stride 72 shorts (144 B, 16B-aligned)
    __hip_bfloat16* epi =
        reinterpret_cast<__hip_bfloat16*>(ShRaw) + wid * 4608;
#pragma unroll
    for (int n = 0; n < 4; ++n) {
      int col = n0 + wn + n * 16 + lr;
      float bval = BIAS ? bias[col] : 0.f;
#pragma unroll
      for (int m = 0; m < 4; ++m) {
        int lrow = m * 16 + lk * 4;
#pragma unroll
        for (int r = 0; r < 4; ++r) {
          float v = acc[m][n][r];
          if (BIAS) v += bval;
          if (RES) v += res[(size_t)(m0 + wm + lrow + r) * N + col];
          if (RESB)
            v += __bfloat162float(resb[(size_t)(m0 + wm + lrow + r) * N + col]);
          if (RELU) v = fmaxf(v, 0.f);
          epi[(lrow + r) * 72 + n * 16 + lr] = __float2bfloat16(v);
        }
      }
    }
    const int lr8 = (lane & 7) * 8;
    const int lrw = lane >> 3;
    const size_t obase = (size_t)(m0 + wm) * N + n0 + wn + lr8;
#pragma unroll
    for (int j = 0; j < 8; ++j) {
      int row = j * 8 + lrw;
      int4 vv = *reinterpret_cast<const int4*>(epi + row * 72 + lr8);
      *reinterpret_cast<int4*>(&Cb[obase + (size_t)row * N]) = vv;
    }
  }
  if (F32OUT) {
#pragma unroll
    for (int n = 0; n < 4; ++n) {
      int col = n0 + wn + n * 16 + lr;
      if (col >= N) continue;
      float bval = BIAS ? bias[col] : 0.f;
#pragma unroll
      for (int m = 0; m < 4; ++m) {
        int row0 = m0 + wm + m * 16 + lk * 4;
#pragma unroll
        for (int r = 0; r < 4; ++r) {
          size_t off = (size_t)(row0 + r) * N + col;
          float v = acc[m][n][r];
          if (BIAS) v += bval;
          if (RES) v += res[off];
          if (RESB) v += __bfloat162float(resb[off]);
          if (RELU) v = fmaxf(v, 0.f);
          C[off] = v;
        }
      }
    }
  }
}

// ---------------------------------------------------------------------------
__global__ __launch_bounds__(256) void cast_bf16_k(
    const float* __restrict__ src, __hip_bfloat16* __restrict__ dst, int n4) {
  int i = blockIdx.x * 256 + threadIdx.x;
  if (i >= n4) return;
  float4 v = reinterpret_cast<const float4*>(src)[i];
  union { __hip_bfloat16 h[4]; short4 s4; } u;
  u.h[0] = __float2bfloat16(v.x); u.h[1] = __float2bfloat16(v.y);
  u.h[2] = __float2bfloat16(v.z); u.h[3] = __float2bfloat16(v.w);
  reinterpret_cast<short4*>(dst)[i] = u.s4;
}

__global__ __launch_bounds__(256) void pad_wx_k(
    const float* __restrict__ src, __hip_bfloat16* __restrict__ dst) {
  int i = blockIdx.x * 256 + threadIdx.x;
  int row = i >> 7;
  union { __hip_bfloat16 h[4]; short4 s4; } u;
  if (row < 48) {
    float4 v = reinterpret_cast<const float4*>(src)[i];
    u.h[0] = __float2bfloat16(v.x); u.h[1] = __float2bfloat16(v.y);
    u.h[2] = __float2bfloat16(v.z); u.h[3] = __float2bfloat16(v.w);
  } else {
    u.h[0] = u.h[1] = u.h[2] = u.h[3] = __float2bfloat16(0.f);
  }
  reinterpret_cast<short4*>(dst)[i] = u.s4;
}

// ---------------------------------------------------------------------------
// Depthwise causal conv (D_CONV=4) + SiLU. In: xz (rows, 1024) cols 0..511.
// ---------------------------------------------------------------------------
__global__ __launch_bounds__(256) void conv_silu_k(
    const __hip_bfloat16* __restrict__ xz, const float* __restrict__ cw,
    const float* __restrict__ cb, __hip_bfloat16* __restrict__ xi) {
  int idx = blockIdx.x * 256 + threadIdx.x;  // r*64 + t
  int t = idx & 63;
  int r = idx >> 6;
  int l = r & (SEQ - 1);
  int c8 = t << 3;
  const __hip_bfloat16* p = xz + (size_t)r * 1024 + c8;
  union U8 { int4 v; __hip_bfloat16 h[8]; } x0, x1, x2, x3, o;
  const int4 z4 = make_int4(0, 0, 0, 0);
  x3.v = *reinterpret_cast<const int4*>(p);
  x2.v = (l >= 1) ? *reinterpret_cast<const int4*>(p - 1024) : z4;
  x1.v = (l >= 2) ? *reinterpret_cast<const int4*>(p - 2048) : z4;
  x0.v = (l >= 3) ? *reinterpret_cast<const int4*>(p - 3072) : z4;
  const float4* cw4 = reinterpret_cast<const float4*>(cw);
#pragma unroll
  for (int j = 0; j < 8; ++j) {
    float4 w = cw4[c8 + j];
    float acc = cb[c8 + j];
    acc = fmaf(w.x, __bfloat162float(x0.h[j]), acc);
    acc = fmaf(w.y, __bfloat162float(x1.h[j]), acc);
    acc = fmaf(w.z, __bfloat162float(x2.h[j]), acc);
    acc = fmaf(w.w, __bfloat162float(x3.h[j]), acc);
    o.h[j] = __float2bfloat16(silu_(acc));
  }
  reinterpret_cast<int4*>(xi)[idx] = o.v;
}

// ---------------------------------------------------------------------------
// Chunked selective scan (unchanged from R9).
// ---------------------------------------------------------------------------
__global__ __launch_bounds__(256) void scan_p1(
    const __hip_bfloat16* __restrict__ u, const float* __restrict__ xdbl,
    const float* __restrict__ A_log, const float* __restrict__ wdt,
    const float* __restrict__ bdt, float* __restrict__ dlsum,
    __hip_bfloat16* __restrict__ hp, __hip_bfloat16* __restrict__ deltab) {
  const int d = ((blockIdx.x & 1) << 8) + threadIdx.x;
  const int c = blockIdx.x >> 1;
  const int b = blockIdx.y;
  const int l0 = c * CHL;
  float A2[16];
  f32x2 w2[8];
  {
    const float4* aq = reinterpret_cast<const float4*>(&A_log[d * 16]);
    const f32x2* wq = reinterpret_cast<const f32x2*>(&wdt[d * 16]);
#pragma unroll
    for (int q = 0; q < 4; ++q) {
      float4 v = aq[q];
      A2[q * 4 + 0] = -exp2_(v.x * L2E) * L2E;
      A2[q * 4 + 1] = -exp2_(v.y * L2E) * L2E;
      A2[q * 4 + 2] = -exp2_(v.z * L2E) * L2E;
      A2[q * 4 + 3] = -exp2_(v.w * L2E) * L2E;
    }
#pragma unroll
    for (int k = 0; k < 8; ++k) w2[k] = wq[k];
  }
  bool chainok = true;
#pragma unroll
  for (int n = 1; n < 16; ++n)
    chainok = chainok &&
              (fabsf(A2[n] - (float)(n + 1) * A2[0]) <=
               1e-4f * (float)(n + 1) * fabsf(A2[0]));
  const float bdtd = bdt[d];
  const float nL = A2[0];
  f32x2 h2[8];
#pragma unroll
  for (int k = 0; k < 8; ++k) h2[k] = (f32x2){0.f, 0.f};
  float dls = 0.f;
  size_t base = (size_t)(b * SEQ + l0) * 512 + d;
  const float* rowp = xdbl + (size_t)(b * SEQ + l0) * 48;
  if (chainok) {
#pragma unroll 4
    for (int i = 0; i < CHL; ++i) {
      const f32x2* r2 = reinterpret_cast<const f32x2*>(rowp + i * 48);
      f32x2 acc2; acc2.x = bdtd; acc2.y = 0.f;
#pragma unroll
      for (int k = 0; k < 8; ++k)
        acc2 = __builtin_elementwise_fma(r2[k], w2[k], acc2);
      float dl = softplus_(acc2.x + acc2.y);
      deltab[base + (size_t)i * 512] = __float2bfloat16(dl);
      dls += dl;
      float du = dl * __bfloat162float(u[base + (size_t)i * 512]);
      f32x2 p[8];
      powpairs_(exp2_(dl * nL), p);
      f32x2 du2; du2.x = du; du2.y = du;
#pragma unroll
      for (int k = 0; k < 8; ++k)
        h2[k] = __builtin_elementwise_fma(p[k], h2[k], du2 * r2[8 + k]);
    }
  } else {
#pragma unroll 2
    for (int i = 0; i < CHL; ++i) {
      const f32x2* r2 = reinterpret_cast<const f32x2*>(rowp + i * 48);
      f32x2 acc2; acc2.x = bdtd; acc2.y = 0.f;
#pragma unroll
      for (int k = 0; k < 8; ++k)
        acc2 = __builtin_elementwise_fma(r2[k], w2[k], acc2);
      float dl = softplus_(acc2.x + acc2.y);
      deltab[base + (size_t)i * 512] = __float2bfloat16(dl);
      dls += dl;
      float du = dl * __bfloat162float(u[base + (size_t)i * 512]);
      f32x2 du2; du2.x = du; du2.y = du;
#pragma unroll
      for (int k = 0; k < 8; ++k) {
        f32x2 a; a.x = exp2_(dl * A2[2 * k]); a.y = exp2_(dl * A2[2 * k + 1]);
        h2[k] = __builtin_elementwise_fma(a, h2[k], du2 * r2[8 + k]);
      }
    }
  }
  size_t sc = (size_t)(b * NCH + c) * 512 + d;
  dlsum[sc] = dls;
  union { __hip_bfloat16 h[4]; short4 s4; } o0, o1, o2, o3;
#pragma unroll
  for (int j = 0; j < 2; ++j) {
    o0.h[2*j] = __float2bfloat16(h2[j].x);   o0.h[2*j+1] = __float2bfloat16(h2[j].y);
    o1.h[2*j] = __float2bfloat16(h2[2+j].x); o1.h[2*j+1] = __float2bfloat16(h2[2+j].y);
    o2.h[2*j] = __float2bfloat16(h2[4+j].x); o2.h[2*j+1] = __float2bfloat16(h2[4+j].y);
    o3.h[2*j] = __float2bfloat16(h2[6+j].x); o3.h[2*j+1] = __float2bfloat16(h2[6+j].y);
  }
  short4* hq = reinterpret_cast<short4*>(hp + sc * 16);
  hq[0] = o0.s4; hq[1] = o1.s4; hq[2] = o2.s4; hq[3] = o3.s4;
}

// In-place: Hc overwrites hp (in-thread read-before-write per idx).
__global__ __launch_bounds__(256) void scan_p2(
    __hip_bfloat16* hp, const float* __restrict__ dlsum,
    const float* __restrict__ A_log) {
  int g = blockIdx.x * 256 + threadIdx.x;
  int b = g >> 13;
  int dn = g & 8191;
  int d = dn >> 4;
  float A2n = -exp2_(A_log[dn] * L2E) * L2E;
  float H = 0.f;
  for (int c = 0; c < NCH; ++c) {
    float ds = dlsum[(size_t)(b * NCH + c) * 512 + d];
    size_t idx = (size_t)(b * NCH + c) * 8192 + dn;
    float p = __bfloat162float(hp[idx]);
    float a = exp2_(A2n * ds);
    hp[idx] = __float2bfloat16(H);
    H = fmaf(a, H, p);
  }
}

__global__ __launch_bounds__(256) void scan_p3(
    const __hip_bfloat16* u,  // aliases y (same-thread read-before-write)
    const float* __restrict__ A_log,
    const __hip_bfloat16* __restrict__ deltab, const float* __restrict__ xdbl,
    const __hip_bfloat16* __restrict__ Hc, const float* __restrict__ Dp,
    const __hip_bfloat16* __restrict__ xz, __hip_bfloat16* y) {
  const int d = ((blockIdx.x & 1) << 8) + threadIdx.x;
  const int c = blockIdx.x >> 1;
  const int b = blockIdx.y;
  const int l0 = c * CHL;
  float A2[16];
  {
    const float4* aq = reinterpret_cast<const float4*>(&A_log[d * 16]);
#pragma unroll
    for (int q = 0; q < 4; ++q) {
      float4 v = aq[q];
      A2[q * 4 + 0] = -exp2_(v.x * L2E) * L2E;
      A2[q * 4 + 1] = -exp2_(v.y * L2E) * L2E;
      A2[q * 4 + 2] = -exp2_(v.z * L2E) * L2E;
      A2[q * 4 + 3] = -exp2_(v.w * L2E) * L2E;
    }
  }
  bool chainok = true;
#pragma unroll
  for (int n = 1; n < 16; ++n)
    chainok = chainok &&
              (fabsf(A2[n] - (float)(n + 1) * A2[0]) <=
               1e-4f * (float)(n + 1) * fabsf(A2[0]));
  const float nL = A2[0];
  f32x2 h2[8];
  {
    const short4* hq =
        reinterpret_cast<const short4*>(Hc + ((size_t)(b * NCH + c) * 512 + d) * 16);
#pragma unroll
    for (int q = 0; q < 4; ++q) {
      union { short4 s4; __hip_bfloat16 h[4]; } iv;
      iv.s4 = hq[q];
      h2[2*q].x = __bfloat162float(iv.h[0]);
      h2[2*q].y = __bfloat162float(iv.h[1]);
      h2[2*q+1].x = __bfloat162float(iv.h[2]);
      h2[2*q+1].y = __bfloat162float(iv.h[3]);
    }
  }
  const float Dpd = Dp[d];
  size_t base = (size_t)(b * SEQ + l0) * 512 + d;
  const float* rowp = xdbl + (size_t)(b * SEQ + l0) * 48;
  const __hip_bfloat16* zp = xz + (size_t)(b * SEQ + l0) * 1024 + 512 + d;
  if (chainok) {
#pragma unroll 4
    for (int i = 0; i < CHL; ++i) {
      const f32x2* r2 = reinterpret_cast<const f32x2*>(rowp + i * 48);
      float dl = __bfloat162float(deltab[base + (size_t)i * 512]);
      float ul = __bfloat162float(u[base + (size_t)i * 512]);
      float du = dl * ul;
      f32x2 p[8];
      powpairs_(exp2_(dl * nL), p);
      f32x2 du2; du2.x = du; du2.y = du;
      f32x2 yv2; yv2.x = 0.f; yv2.y = 0.f;
#pragma unroll
      for (int k = 0; k < 8; ++k) {
        h2[k] = __builtin_elementwise_fma(p[k], h2[k], du2 * r2[8 + k]);
        yv2 = __builtin_elementwise_fma(h2[k], r2[16 + k], yv2);
      }
      float yv = yv2.x + yv2.y;
      float zv = __bfloat162float(zp[(size_t)i * 1024]);
      y[base + (size_t)i * 512] =
          __float2bfloat16((yv + ul * Dpd) * silu_(zv));
    }
  } else {
#pragma unroll 2
    for (int i = 0; i < CHL; ++i) {
      const f32x2* r2 = reinterpret_cast<const f32x2*>(rowp + i * 48);
      float dl = __bfloat162float(deltab[base + (size_t)i * 512]);
      float ul = __bfloat162float(u[base + (size_t)i * 512]);
      float du = dl * ul;
      f32x2 du2; du2.x = du; du2.y = du;
      f32x2 yv2; yv2.x = 0.f; yv2.y = 0.f;
#pragma unroll
      for (int k = 0; k < 8; ++k) {
        f32x2 a; a.x = exp2_(dl * A2[2 * k]); a.y = exp2_(dl * A2[2 * k + 1]);
        h2[k] = __builtin_elementwise_fma(a, h2[k], du2 * r2[8 + k]);
        yv2 = __builtin_elementwise_fma(h2[k], r2[16 + k], yv2);
      }
      float yv = yv2.x + yv2.y;
      float zv = __bfloat162float(zp[(size_t)i * 1024]);
      y[base + (size_t)i * 512] =
          __float2bfloat16((yv + ul * Dpd) * silu_(zv));
    }
  }
}

// ---------------------------------------------------------------------------
__global__ __launch_bounds__(256) void ln_k(
    const __hip_bfloat16* __restrict__ in, const float* __restrict__ g,
    const float* __restrict__ bb, __hip_bfloat16* __restrict__ outb) {
  int row = (blockIdx.x * 256 + threadIdx.x) >> 6;
  int lane = threadIdx.x & 63;
  union { short4 s4; __hip_bfloat16 h[4]; } iv;
  iv.s4 = reinterpret_cast<const short4*>(in)[row * 64 + lane];
  float v0 = __bfloat162float(iv.h[0]), v1 = __bfloat162float(iv.h[1]);
  float v2 = __bfloat162float(iv.h[2]), v3 = __bfloat162float(iv.h[3]);
  float mu = wsum_(v0 + v1 + v2 + v3) * (1.f / 256.f);
  float a0 = v0 - mu, a1 = v1 - mu, a2 = v2 - mu, a3 = v3 - mu;
  float var = wsum_(a0 * a0 + a1 * a1 + a2 * a2 + a3 * a3) * (1.f / 256.f);
  float rs = __builtin_amdgcn_rsqf(var + 1e-5f);
  float4 gg = *reinterpret_cast<const float4*>(&g[lane * 4]);
  float4 bq = *reinterpret_cast<const float4*>(&bb[lane * 4]);
  union { __hip_bfloat16 h[4]; short4 s4; } u;
  u.h[0] = __float2bfloat16(a0 * rs * gg.x + bq.x);
  u.h[1] = __float2bfloat16(a1 * rs * gg.y + bq.y);
  u.h[2] = __float2bfloat16(a2 * rs * gg.z + bq.z);
  u.h[3] = __float2bfloat16(a3 * rs * gg.w + bq.w);
  reinterpret_cast<short4*>(outb)[row * 64 + lane] = u.s4;
}

// ---------------------------------------------------------------------------
__global__ __launch_bounds__(256) void final_k(
    const __hip_bfloat16* __restrict__ t2, const float* __restrict__ g2v,
    const float* __restrict__ b2v, const float* __restrict__ g3v,
    const float* __restrict__ b3v, const float* __restrict__ x,
    float* __restrict__ out) {
  int bx = blockIdx.x;
  int half = bx & 1, nv = (bx >> 1) & 31, b = bx >> 6;
  int wave = threadIdx.x >> 6, lane = threadIdx.x & 63;
  __shared__ float sh[32][257];
  float4 gg2 = *reinterpret_cast<const float4*>(&g2v[lane * 4]);
  float4 bb2 = *reinterpret_cast<const float4*>(&b2v[lane * 4]);
  float4 gg3 = *reinterpret_cast<const float4*>(&g3v[lane * 4]);
  float4 bb3 = *reinterpret_cast<const float4*>(&b3v[lane * 4]);
#pragma unroll
  for (int i = 0; i < 8; ++i) {
    int pn = wave * 8 + i;
    int r = ((b * 32 + nv) << 6) + (half << 5) + pn;
    union { short4 s4; __hip_bfloat16 h[4]; } iv;
    iv.s4 = reinterpret_cast<const short4*>(t2)[r * 64 + lane];
    float v0 = __bfloat162float(iv.h[0]), v1 = __bfloat162float(iv.h[1]);
    float v2 = __bfloat162float(iv.h[2]), v3 = __bfloat162float(iv.h[3]);
    float mu = wsum_(v0 + v1 + v2 + v3) * (1.f / 256.f);
    float a0 = v0 - mu, a1 = v1 - mu, a2 = v2 - mu, a3 = v3 - mu;
    float var = wsum_(a0 * a0 + a1 * a1 + a2 * a2 + a3 * a3) * (1.f / 256.f);
    float rs = __builtin_amdgcn_rsqf(var + 1e-5f);
    a0 = a0 * rs * gg2.x + bb2.x; a1 = a1 * rs * gg2.y + bb2.y;
    a2 = a2 * rs * gg2.z + bb2.z; a3 = a3 * rs * gg2.w + bb2.w;
    mu = wsum_(a0 + a1 + a2 + a3) * (1.f / 256.f);
    float c0 = a0 - mu, c1 = a1 - mu, c2 = a2 - mu, c3 = a3 - mu;
    var = wsum_(c0 * c0 + c1 * c1 + c2 * c2 + c3 * c3) * (1.f / 256.f);
    rs = __builtin_amdgcn_rsqf(var + 1e-5f);
    sh[pn][lane * 4 + 0] = c0 * rs * gg3.x + bb3.x;
    sh[pn][lane * 4 + 1] = c1 * rs * gg3.y + bb3.y;
    sh[pn][lane * 4 + 2] = c2 * rs * gg3.z + bb3.z;
    sh[pn][lane * 4 + 3] = c3 * rs * gg3.w + bb3.w;
  }
  __syncthreads();
  int pnl = threadIdx.x & 31;
  int dbase = threadIdx.x >> 5;
  size_t obase = (size_t)((b * 32 + nv) * 256) * 64 + (half << 5) + pnl;
#pragma unroll
  for (int k = 0; k < 32; ++k) {
    int dd = dbase + (k << 3);
    size_t oi = obase + (size_t)dd * 64;
    out[oi] = sh[pnl][dd] + x[oi];
  }
}

// ---------------------------------------------------------------------------
extern "C" void kernel_launch(void* const* d_in, const int* in_sizes, int n_in,
                              void* d_out, int out_size, void* d_ws,
                              size_t ws_size, hipStream_t stream) {
  const float* x    = (const float*)d_in[0];
  const float* w_in = (const float*)d_in[1];
  const float* b_in = (const float*)d_in[2];
  const float* cw   = (const float*)d_in[3];
  const float* cb   = (const float*)d_in[4];
  const float* wx   = (const float*)d_in[5];
  const float* wdt  = (const float*)d_in[6];
  const float* bdt  = (const float*)d_in[7];
  const float* alog = (const float*)d_in[8];
  const float* Dp   = (const float*)d_in[9];
  const float* wout = (const float*)d_in[10];
  const float* g1   = (const float*)d_in[11];
  const float* b1   = (const float*)d_in[12];
  const float* wf1  = (const float*)d_in[13];
  const float* bf1  = (const float*)d_in[14];
  const float* wf2  = (const float*)d_in[15];
  const float* bf2  = (const float*)d_in[16];
  const float* g2   = (const float*)d_in[17];
  const float* b2   = (const float*)d_in[18];
  const float* g3   = (const float*)d_in[19];
  const float* b3   = (const float*)d_in[20];
  float* out = (float*)d_out;

  const size_t MB1 = 1048576;
  char* g = (char*)d_ws;
  __hip_bfloat16* wbf_in  = (__hip_bfloat16*)(g);              // 512 KB
  __hip_bfloat16* wbf_out = (__hip_bfloat16*)(g + 524288);     // 256 KB
  __hip_bfloat16* wbf_f1  = (__hip_bfloat16*)(g + 786432);     // 256 KB
  __hip_bfloat16* wbf_f2  = (__hip_bfloat16*)(g + 1048576);    // 256 KB
  __hip_bfloat16* wbf_xp  = (__hip_bfloat16*)(g + 1310720);    // 128 KB
  const size_t SHARED = 1572864;

  // Regions/batch: RA 4MB (xz|t2b) | RB 1MB (xbf|dlsum) | RC 2MB (xi|ffny)
  //   RD 384KB (xdbl) | RE 2MB (hp bf16 | resb+h1bf) | RF 2MB (deltab)
  const size_t PB = 11 * MB1 + 393216;  // 11,927,552 B/batch
  int nb = (int)((ws_size - SHARED) / PB);
  if (ws_size <= SHARED || nb < 1) return;
  if (nb > NBTOT) nb = NBTOT;

  dim3 blk(256);
  cast_bf16_k<<<dim3(256), blk, 0, stream>>>(w_in, wbf_in, 65536);
  cast_bf16_k<<<dim3(128), blk, 0, stream>>>(wout, wbf_out, 32768);
  cast_bf16_k<<<dim3(128), blk, 0, stream>>>(wf1, wbf_f1, 32768);
  cast_bf16_k<<<dim3(128), blk, 0, stream>>>(wf2, wbf_f2, 32768);
  pad_wx_k<<<dim3(64), blk, 0, stream>>>(wx, wbf_xp);

  for (int b0 = 0; b0 < NBTOT; b0 += nb) {
    int bn = (NBTOT - b0 < nb) ? (NBTOT - b0) : nb;
    char* base = g + SHARED;
    char* RA = base;                          // bn*4MB
    char* RB = base + (size_t)bn * 4 * MB1;   // bn*1MB
    char* RC = base + (size_t)bn * 5 * MB1;   // bn*2MB
    char* RD = base + (size_t)bn * 7 * MB1;   // bn*384KB
    char* RE = RD + (size_t)bn * 393216;      // bn*2MB
    char* RF = RE + (size_t)bn * 2 * MB1;     // bn*2MB

    __hip_bfloat16* xz     = (__hip_bfloat16*)RA;
    __hip_bfloat16* t2b    = (__hip_bfloat16*)RA;
    __hip_bfloat16* xbf    = (__hip_bfloat16*)RB;
    float*          dlsum  = (float*)RB;
    __hip_bfloat16* xibf   = (__hip_bfloat16*)RC;
    __hip_bfloat16* ffnybf = (__hip_bfloat16*)RC;
    float*          xdbl   = (float*)RD;
    __hip_bfloat16* hp     = (__hip_bfloat16*)RE;   // Hc in-place (bf16)
    __hip_bfloat16* resb   = (__hip_bfloat16*)RE;   // after scan
    __hip_bfloat16* h1bf   = (__hip_bfloat16*)(RE + (size_t)bn * MB1);
    __hip_bfloat16* deltab = (__hip_bfloat16*)RF;

    const float* xg = x + (size_t)b0 * SEQ * 256;
    float* outg = out + (size_t)b0 * SEQ * 256;
    int M = bn * SEQ;
    int MT = M / 128;

    cast_bf16_k<<<dim3(M * 64 / 256), blk, 0, stream>>>(xg, xbf, M * 64);
    // in_proj (N=1024, NT=8) -> xz bf16
    gemm_bf16<true, false, false, false, false, true, 3>
        <<<dim3(8 * MT), blk, 0, stream>>>(xbf, wbf_in, b_in, nullptr, nullptr,
                                           nullptr, xz, 1024, 256);
    conv_silu_k<<<dim3(M / 4), blk, 0, stream>>>(xz, cw, cb, xibf);
    // x_proj (N=48 padded, NT=1) -> xdbl f32
    gemm_bf16<false, false, false, false, true, false, 0>
        <<<dim3(MT), blk, 0, stream>>>(xibf, wbf_xp, nullptr, nullptr,
                                       nullptr, xdbl, nullptr, 48, 512);
    scan_p1<<<dim3(NCH * 2, bn), blk, 0, stream>>>(xibf, xdbl, alog, wdt, bdt,
                                                   dlsum, hp, deltab);
    scan_p2<<<dim3(bn * 32), blk, 0, stream>>>(hp, dlsum, alog);
    scan_p3<<<dim3(NCH * 2, bn), blk, 0, stream>>>(xibf, alog, deltab, xdbl,
                                                   hp, Dp, xz, xibf);
    // out_proj + residual(x f32) -> resb bf16 (N=256, NT=2)
    gemm_bf16<false, false, true, false, false, true, 1>
        <<<dim3(2 * MT), blk, 0, stream>>>(xibf, wbf_out, nullptr, xg, nullptr,
                                           nullptr, resb, 256, 512);
    ln_k<<<dim3(M / 4), blk, 0, stream>>>(resb, g1, b1, h1bf);
    // ffn1 + relu (N=512, NT=4) -> ffnybf
    gemm_bf16<true, true, false, false, false, true, 2>
        <<<dim3(4 * MT), blk, 0, stream>>>(h1bf, wbf_f1, bf1, nullptr, nullptr,
                                           nullptr, ffnybf, 512, 256);
    // ffn2 + bias + residual(h1 bf16) -> t2b bf16 (N=256, NT=2)
    gemm_bf16<true, false, false, true, false, true, 1>
        <<<dim3(2 * MT), blk, 0, stream>>>(ffnybf, wbf_f2, bf2, nullptr, h1bf,
                                           nullptr, t2b, 256, 512);
    final_k<<<dim3(bn * 64), blk, 0, stream>>>(t2b, g2, b2, g3, b3, xg, outg);
  }
}

// Round 11
// 277.554 us; speedup vs baseline: 3.6106x; 1.0090x over previous
//
#include <hip/hip_runtime.h>
#include <hip/hip_bf16.h>
#include <math.h>

#define SEQ    2048
#define NBTOT  16
#define NCH    64
#define CHL    32            // NCH*CHL == SEQ

#define L2E 1.4426950408889634f

typedef __attribute__((ext_vector_type(8))) __bf16 bf16x8;
typedef __attribute__((ext_vector_type(4))) float f32x4;
typedef __attribute__((ext_vector_type(2))) float f32x2;

#define GLOAD16(gp, lp)                                                   \
  __builtin_amdgcn_global_load_lds(                                       \
      (const __attribute__((address_space(1))) unsigned int*)(gp),        \
      (__attribute__((address_space(3))) unsigned int*)(lp), 16, 0, 0)

__device__ __forceinline__ float exp2_(float x) {
  return __builtin_amdgcn_exp2f(x);
}
__device__ __forceinline__ float silu_(float x) {
  return x * __builtin_amdgcn_rcpf(1.f + exp2_(-x * L2E));
}
__device__ __forceinline__ float softplus_(float x) {
  return fmaxf(x, 0.f) + __logf(1.f + exp2_(-fabsf(x) * L2E));
}
__device__ __forceinline__ float wsum_(float v) {
#pragma unroll
  for (int off = 32; off > 0; off >>= 1) v += __shfl_xor(v, off, 64);
  return v;
}
// Bijective XCD-chunk swizzle: XCD k (dispatch round-robin) owns the
// contiguous work range [k*nwg/8, (k+1)*nwg/8). nwg must be mult of 8.
// Used by EVERY row-streaming kernel so row->XCD is pipeline-consistent.
__device__ __forceinline__ int xcdswz_(int bid, int nwg) {
  return (bid & 7) * (nwg >> 3) + (bid >> 3);
}
// p[k] = {e1^(2k+1), e1^(2k+2)}: 2 squares + 7 pk_mul, depth 4
__device__ __forceinline__ void powpairs_(float e1, f32x2 p[8]) {
  float e2 = e1 * e1;
  f32x2 p0; p0.x = e1; p0.y = e2;
  f32x2 s2; s2.x = e2; s2.y = e2;
  f32x2 s4 = s2 * s2;
  f32x2 s8 = s4 * s4;
  p[0] = p0;      p[1] = p0 * s2; p[2] = p0 * s4; p[3] = p[1] * s4;
  p[4] = p0 * s8; p[5] = p[1] * s8; p[6] = p[2] * s8; p[7] = p[3] * s8;
}

// ---------------------------------------------------------------------------
// bf16 MFMA GEMM (m97 structure) + XCD-chunk swizzle + LDS-bounce epilogue.
// ---------------------------------------------------------------------------
template <bool BIAS, bool RELU, bool RES, bool RESB, bool F32OUT, bool BF16OUT,
          int NTLOG>
__global__ __launch_bounds__(256) void gemm_bf16(
    const __hip_bfloat16* __restrict__ A, const __hip_bfloat16* __restrict__ W,
    const float* __restrict__ bias, const float* __restrict__ res,
    const __hip_bfloat16* __restrict__ resb, float* __restrict__ C,
    __hip_bfloat16* __restrict__ Cb, int N, int K) {
  __shared__ __align__(16) char ShRaw[36864];
  short* Als = reinterpret_cast<short*>(ShRaw);
  short* Bls = Als + 8192;
  const int tid = threadIdx.x;
  const int lane = tid & 63;
  const int wid = tid >> 6;
  const int swz = xcdswz_(blockIdx.x, gridDim.x);
  const int m0 = (swz >> NTLOG) * 128;
  const int n0 = (swz & ((1 << NTLOG) - 1)) * 128;
  const int wm = (wid >> 1) * 64;
  const int wn = (wid & 1) * 64;
  const int lr = lane & 15;
  const int lk = lane >> 4;  // 0..3

  f32x4 acc[4][4];
#pragma unroll
  for (int m = 0; m < 4; ++m)
#pragma unroll
    for (int n = 0; n < 4; ++n) acc[m][n] = (f32x4){0.f, 0.f, 0.f, 0.f};

  const int srow = wid * 32 + (lane >> 3);
  const int scol = (lane & 7) * 8;
  const __hip_bfloat16* Ag = A + (size_t)(m0 + srow) * K + scol;
  const __hip_bfloat16* Wg = W + (size_t)(n0 + srow) * K + scol;
  short* Alb = Als + wid * 2048;
  short* Blb = Bls + wid * 2048;

  for (int kt = 0; kt < K; kt += 64) {
#pragma unroll
    for (int i = 0; i < 4; ++i) {
      GLOAD16(Ag + (size_t)(i * 8) * K + kt, Alb + i * 512);
      GLOAD16(Wg + (size_t)(i * 8) * K + kt, Blb + i * 512);
    }
    __syncthreads();
    const bf16x8* Af = reinterpret_cast<const bf16x8*>(Als);
    const bf16x8* Bf = reinterpret_cast<const bf16x8*>(Bls);
#pragma unroll
    for (int ks = 0; ks < 2; ++ks) {
      bf16x8 av[4], bv[4];
#pragma unroll
      for (int m = 0; m < 4; ++m)
        av[m] = Af[(wm + m * 16 + lr) * 8 + ks * 4 + lk];
#pragma unroll
      for (int n = 0; n < 4; ++n)
        bv[n] = Bf[(wn + n * 16 + lr) * 8 + ks * 4 + lk];
#pragma unroll
      for (int m = 0; m < 4; ++m)
#pragma unroll
        for (int n = 0; n < 4; ++n)
          acc[m][n] = __builtin_amdgcn_mfma_f32_16x16x32_bf16(
              av[m], bv[n], acc[m][n], 0, 0, 0);
    }
    __syncthreads();  // after this, staging LDS is dead -> epilogue reuse
  }

  if (BF16OUT) {
    __hip_bfloat16* epi =
        reinterpret_cast<__hip_bfloat16*>(ShRaw) + wid * 4608;
#pragma unroll
    for (int n = 0; n < 4; ++n) {
      int col = n0 + wn + n * 16 + lr;
      float bval = BIAS ? bias[col] : 0.f;
#pragma unroll
      for (int m = 0; m < 4; ++m) {
        int lrow = m * 16 + lk * 4;
#pragma unroll
        for (int r = 0; r < 4; ++r) {
          float v = acc[m][n][r];
          if (BIAS) v += bval;
          if (RES) v += res[(size_t)(m0 + wm + lrow + r) * N + col];
          if (RESB)
            v += __bfloat162float(resb[(size_t)(m0 + wm + lrow + r) * N + col]);
          if (RELU) v = fmaxf(v, 0.f);
          epi[(lrow + r) * 72 + n * 16 + lr] = __float2bfloat16(v);
        }
      }
    }
    const int lr8 = (lane & 7) * 8;
    const int lrw = lane >> 3;
    const size_t obase = (size_t)(m0 + wm) * N + n0 + wn + lr8;
#pragma unroll
    for (int j = 0; j < 8; ++j) {
      int row = j * 8 + lrw;
      int4 vv = *reinterpret_cast<const int4*>(epi + row * 72 + lr8);
      *reinterpret_cast<int4*>(&Cb[obase + (size_t)row * N]) = vv;
    }
  }
  if (F32OUT) {
#pragma unroll
    for (int n = 0; n < 4; ++n) {
      int col = n0 + wn + n * 16 + lr;
      if (col >= N) continue;
      float bval = BIAS ? bias[col] : 0.f;
#pragma unroll
      for (int m = 0; m < 4; ++m) {
        int row0 = m0 + wm + m * 16 + lk * 4;
#pragma unroll
        for (int r = 0; r < 4; ++r) {
          size_t off = (size_t)(row0 + r) * N + col;
          float v = acc[m][n][r];
          if (BIAS) v += bval;
          if (RES) v += res[off];
          if (RESB) v += __bfloat162float(resb[off]);
          if (RELU) v = fmaxf(v, 0.f);
          C[off] = v;
        }
      }
    }
  }
}

// ---------------------------------------------------------------------------
__global__ __launch_bounds__(256) void cast_bf16_k(
    const float* __restrict__ src, __hip_bfloat16* __restrict__ dst, int n4) {
  int i = xcdswz_(blockIdx.x, gridDim.x) * 256 + threadIdx.x;
  if (i >= n4) return;
  float4 v = reinterpret_cast<const float4*>(src)[i];
  union { __hip_bfloat16 h[4]; short4 s4; } u;
  u.h[0] = __float2bfloat16(v.x); u.h[1] = __float2bfloat16(v.y);
  u.h[2] = __float2bfloat16(v.z); u.h[3] = __float2bfloat16(v.w);
  reinterpret_cast<short4*>(dst)[i] = u.s4;
}

__global__ __launch_bounds__(256) void pad_wx_k(
    const float* __restrict__ src, __hip_bfloat16* __restrict__ dst) {
  int i = blockIdx.x * 256 + threadIdx.x;
  int row = i >> 7;
  union { __hip_bfloat16 h[4]; short4 s4; } u;
  if (row < 48) {
    float4 v = reinterpret_cast<const float4*>(src)[i];
    u.h[0] = __float2bfloat16(v.x); u.h[1] = __float2bfloat16(v.y);
    u.h[2] = __float2bfloat16(v.z); u.h[3] = __float2bfloat16(v.w);
  } else {
    u.h[0] = u.h[1] = u.h[2] = u.h[3] = __float2bfloat16(0.f);
  }
  reinterpret_cast<short4*>(dst)[i] = u.s4;
}

// ---------------------------------------------------------------------------
// Depthwise causal conv (D_CONV=4) + SiLU. In: xz (rows, 1024) cols 0..511.
// ---------------------------------------------------------------------------
__global__ __launch_bounds__(256) void conv_silu_k(
    const __hip_bfloat16* __restrict__ xz, const float* __restrict__ cw,
    const float* __restrict__ cb, __hip_bfloat16* __restrict__ xi) {
  int idx = xcdswz_(blockIdx.x, gridDim.x) * 256 + threadIdx.x;  // r*64 + t
  int t = idx & 63;
  int r = idx >> 6;
  int l = r & (SEQ - 1);
  int c8 = t << 3;
  const __hip_bfloat16* p = xz + (size_t)r * 1024 + c8;
  union U8 { int4 v; __hip_bfloat16 h[8]; } x0, x1, x2, x3, o;
  const int4 z4 = make_int4(0, 0, 0, 0);
  x3.v = *reinterpret_cast<const int4*>(p);
  x2.v = (l >= 1) ? *reinterpret_cast<const int4*>(p - 1024) : z4;
  x1.v = (l >= 2) ? *reinterpret_cast<const int4*>(p - 2048) : z4;
  x0.v = (l >= 3) ? *reinterpret_cast<const int4*>(p - 3072) : z4;
  const float4* cw4 = reinterpret_cast<const float4*>(cw);
#pragma unroll
  for (int j = 0; j < 8; ++j) {
    float4 w = cw4[c8 + j];
    float acc = cb[c8 + j];
    acc = fmaf(w.x, __bfloat162float(x0.h[j]), acc);
    acc = fmaf(w.y, __bfloat162float(x1.h[j]), acc);
    acc = fmaf(w.z, __bfloat162float(x2.h[j]), acc);
    acc = fmaf(w.w, __bfloat162float(x3.h[j]), acc);
    o.h[j] = __float2bfloat16(silu_(acc));
  }
  reinterpret_cast<int4*>(xi)[idx] = o.v;
}

// ---------------------------------------------------------------------------
// Chunked selective scan (math unchanged from R10; 1-D grid + XCD swizzle,
// decode w -> (b, c, dhalf), w row-ordered so row->XCD matches the GEMMs).
// ---------------------------------------------------------------------------
__global__ __launch_bounds__(256) void scan_p1(
    const __hip_bfloat16* __restrict__ u, const float* __restrict__ xdbl,
    const float* __restrict__ A_log, const float* __restrict__ wdt,
    const float* __restrict__ bdt, float* __restrict__ dlsum,
    __hip_bfloat16* __restrict__ hp, __hip_bfloat16* __restrict__ deltab) {
  const int w = xcdswz_(blockIdx.x, gridDim.x);  // b*128 + c*2 + h
  const int b = w >> 7;
  const int c = (w >> 1) & 63;
  const int d = ((w & 1) << 8) + threadIdx.x;
  const int l0 = c * CHL;
  float A2[16];
  f32x2 w2[8];
  {
    const float4* aq = reinterpret_cast<const float4*>(&A_log[d * 16]);
    const f32x2* wq = reinterpret_cast<const f32x2*>(&wdt[d * 16]);
#pragma unroll
    for (int q = 0; q < 4; ++q) {
      float4 v = aq[q];
      A2[q * 4 + 0] = -exp2_(v.x * L2E) * L2E;
      A2[q * 4 + 1] = -exp2_(v.y * L2E) * L2E;
      A2[q * 4 + 2] = -exp2_(v.z * L2E) * L2E;
      A2[q * 4 + 3] = -exp2_(v.w * L2E) * L2E;
    }
#pragma unroll
    for (int k = 0; k < 8; ++k) w2[k] = wq[k];
  }
  bool chainok = true;
#pragma unroll
  for (int n = 1; n < 16; ++n)
    chainok = chainok &&
              (fabsf(A2[n] - (float)(n + 1) * A2[0]) <=
               1e-4f * (float)(n + 1) * fabsf(A2[0]));
  const float bdtd = bdt[d];
  const float nL = A2[0];
  f32x2 h2[8];
#pragma unroll
  for (int k = 0; k < 8; ++k) h2[k] = (f32x2){0.f, 0.f};
  float dls = 0.f;
  size_t base = (size_t)(b * SEQ + l0) * 512 + d;
  const float* rowp = xdbl + (size_t)(b * SEQ + l0) * 48;
  if (chainok) {
#pragma unroll 4
    for (int i = 0; i < CHL; ++i) {
      const f32x2* r2 = reinterpret_cast<const f32x2*>(rowp + i * 48);
      f32x2 acc2; acc2.x = bdtd; acc2.y = 0.f;
#pragma unroll
      for (int k = 0; k < 8; ++k)
        acc2 = __builtin_elementwise_fma(r2[k], w2[k], acc2);
      float dl = softplus_(acc2.x + acc2.y);
      deltab[base + (size_t)i * 512] = __float2bfloat16(dl);
      dls += dl;
      float du = dl * __bfloat162float(u[base + (size_t)i * 512]);
      f32x2 p[8];
      powpairs_(exp2_(dl * nL), p);
      f32x2 du2; du2.x = du; du2.y = du;
#pragma unroll
      for (int k = 0; k < 8; ++k)
        h2[k] = __builtin_elementwise_fma(p[k], h2[k], du2 * r2[8 + k]);
    }
  } else {
#pragma unroll 2
    for (int i = 0; i < CHL; ++i) {
      const f32x2* r2 = reinterpret_cast<const f32x2*>(rowp + i * 48);
      f32x2 acc2; acc2.x = bdtd; acc2.y = 0.f;
#pragma unroll
      for (int k = 0; k < 8; ++k)
        acc2 = __builtin_elementwise_fma(r2[k], w2[k], acc2);
      float dl = softplus_(acc2.x + acc2.y);
      deltab[base + (size_t)i * 512] = __float2bfloat16(dl);
      dls += dl;
      float du = dl * __bfloat162float(u[base + (size_t)i * 512]);
      f32x2 du2; du2.x = du; du2.y = du;
#pragma unroll
      for (int k = 0; k < 8; ++k) {
        f32x2 a; a.x = exp2_(dl * A2[2 * k]); a.y = exp2_(dl * A2[2 * k + 1]);
        h2[k] = __builtin_elementwise_fma(a, h2[k], du2 * r2[8 + k]);
      }
    }
  }
  size_t sc = (size_t)(b * NCH + c) * 512 + d;
  dlsum[sc] = dls;
  union { __hip_bfloat16 h[4]; short4 s4; } o0, o1, o2, o3;
#pragma unroll
  for (int j = 0; j < 2; ++j) {
    o0.h[2*j] = __float2bfloat16(h2[j].x);   o0.h[2*j+1] = __float2bfloat16(h2[j].y);
    o1.h[2*j] = __float2bfloat16(h2[2+j].x); o1.h[2*j+1] = __float2bfloat16(h2[2+j].y);
    o2.h[2*j] = __float2bfloat16(h2[4+j].x); o2.h[2*j+1] = __float2bfloat16(h2[4+j].y);
    o3.h[2*j] = __float2bfloat16(h2[6+j].x); o3.h[2*j+1] = __float2bfloat16(h2[6+j].y);
  }
  short4* hq = reinterpret_cast<short4*>(hp + sc * 16);
  hq[0] = o0.s4; hq[1] = o1.s4; hq[2] = o2.s4; hq[3] = o3.s4;
}

// In-place: Hc overwrites hp (in-thread read-before-write per idx).
__global__ __launch_bounds__(256) void scan_p2(
    __hip_bfloat16* hp, const float* __restrict__ dlsum,
    const float* __restrict__ A_log) {
  int g = xcdswz_(blockIdx.x, gridDim.x) * 256 + threadIdx.x;
  int b = g >> 13;
  int dn = g & 8191;
  int d = dn >> 4;
  float A2n = -exp2_(A_log[dn] * L2E) * L2E;
  float H = 0.f;
  for (int c = 0; c < NCH; ++c) {
    float ds = dlsum[(size_t)(b * NCH + c) * 512 + d];
    size_t idx = (size_t)(b * NCH + c) * 8192 + dn;
    float p = __bfloat162float(hp[idx]);
    float a = exp2_(A2n * ds);
    hp[idx] = __float2bfloat16(H);
    H = fmaf(a, H, p);
  }
}

__global__ __launch_bounds__(256) void scan_p3(
    const __hip_bfloat16* u,  // aliases y (same-thread read-before-write)
    const float* __restrict__ A_log,
    const __hip_bfloat16* __restrict__ deltab, const float* __restrict__ xdbl,
    const __hip_bfloat16* __restrict__ Hc, const float* __restrict__ Dp,
    const __hip_bfloat16* __restrict__ xz, __hip_bfloat16* y) {
  const int w = xcdswz_(blockIdx.x, gridDim.x);
  const int b = w >> 7;
  const int c = (w >> 1) & 63;
  const int d = ((w & 1) << 8) + threadIdx.x;
  const int l0 = c * CHL;
  float A2[16];
  {
    const float4* aq = reinterpret_cast<const float4*>(&A_log[d * 16]);
#pragma unroll
    for (int q = 0; q < 4; ++q) {
      float4 v = aq[q];
      A2[q * 4 + 0] = -exp2_(v.x * L2E) * L2E;
      A2[q * 4 + 1] = -exp2_(v.y * L2E) * L2E;
      A2[q * 4 + 2] = -exp2_(v.z * L2E) * L2E;
      A2[q * 4 + 3] = -exp2_(v.w * L2E) * L2E;
    }
  }
  bool chainok = true;
#pragma unroll
  for (int n = 1; n < 16; ++n)
    chainok = chainok &&
              (fabsf(A2[n] - (float)(n + 1) * A2[0]) <=
               1e-4f * (float)(n + 1) * fabsf(A2[0]));
  const float nL = A2[0];
  f32x2 h2[8];
  {
    const short4* hq =
        reinterpret_cast<const short4*>(Hc + ((size_t)(b * NCH + c) * 512 + d) * 16);
#pragma unroll
    for (int q = 0; q < 4; ++q) {
      union { short4 s4; __hip_bfloat16 h[4]; } iv;
      iv.s4 = hq[q];
      h2[2*q].x = __bfloat162float(iv.h[0]);
      h2[2*q].y = __bfloat162float(iv.h[1]);
      h2[2*q+1].x = __bfloat162float(iv.h[2]);
      h2[2*q+1].y = __bfloat162float(iv.h[3]);
    }
  }
  const float Dpd = Dp[d];
  size_t base = (size_t)(b * SEQ + l0) * 512 + d;
  const float* rowp = xdbl + (size_t)(b * SEQ + l0) * 48;
  const __hip_bfloat16* zp = xz + (size_t)(b * SEQ + l0) * 1024 + 512 + d;
  if (chainok) {
#pragma unroll 4
    for (int i = 0; i < CHL; ++i) {
      const f32x2* r2 = reinterpret_cast<const f32x2*>(rowp + i * 48);
      float dl = __bfloat162float(deltab[base + (size_t)i * 512]);
      float ul = __bfloat162float(u[base + (size_t)i * 512]);
      float du = dl * ul;
      f32x2 p[8];
      powpairs_(exp2_(dl * nL), p);
      f32x2 du2; du2.x = du; du2.y = du;
      f32x2 yv2; yv2.x = 0.f; yv2.y = 0.f;
#pragma unroll
      for (int k = 0; k < 8; ++k) {
        h2[k] = __builtin_elementwise_fma(p[k], h2[k], du2 * r2[8 + k]);
        yv2 = __builtin_elementwise_fma(h2[k], r2[16 + k], yv2);
      }
      float yv = yv2.x + yv2.y;
      float zv = __bfloat162float(zp[(size_t)i * 1024]);
      y[base + (size_t)i * 512] =
          __float2bfloat16((yv + ul * Dpd) * silu_(zv));
    }
  } else {
#pragma unroll 2
    for (int i = 0; i < CHL; ++i) {
      const f32x2* r2 = reinterpret_cast<const f32x2*>(rowp + i * 48);
      float dl = __bfloat162float(deltab[base + (size_t)i * 512]);
      float ul = __bfloat162float(u[base + (size_t)i * 512]);
      float du = dl * ul;
      f32x2 du2; du2.x = du; du2.y = du;
      f32x2 yv2; yv2.x = 0.f; yv2.y = 0.f;
#pragma unroll
      for (int k = 0; k < 8; ++k) {
        f32x2 a; a.x = exp2_(dl * A2[2 * k]); a.y = exp2_(dl * A2[2 * k + 1]);
        h2[k] = __builtin_elementwise_fma(a, h2[k], du2 * r2[8 + k]);
        yv2 = __builtin_elementwise_fma(h2[k], r2[16 + k], yv2);
      }
      float yv = yv2.x + yv2.y;
      float zv = __bfloat162float(zp[(size_t)i * 1024]);
      y[base + (size_t)i * 512] =
          __float2bfloat16((yv + ul * Dpd) * silu_(zv));
    }
  }
}

// ---------------------------------------------------------------------------
__global__ __launch_bounds__(256) void ln_k(
    const __hip_bfloat16* __restrict__ in, const float* __restrict__ g,
    const float* __restrict__ bb, __hip_bfloat16* __restrict__ outb) {
  int row = (xcdswz_(blockIdx.x, gridDim.x) * 256 + threadIdx.x) >> 6;
  int lane = threadIdx.x & 63;
  union { short4 s4; __hip_bfloat16 h[4]; } iv;
  iv.s4 = reinterpret_cast<const short4*>(in)[row * 64 + lane];
  float v0 = __bfloat162float(iv.h[0]), v1 = __bfloat162float(iv.h[1]);
  float v2 = __bfloat162float(iv.h[2]), v3 = __bfloat162float(iv.h[3]);
  float mu = wsum_(v0 + v1 + v2 + v3) * (1.f / 256.f);
  float a0 = v0 - mu, a1 = v1 - mu, a2 = v2 - mu, a3 = v3 - mu;
  float var = wsum_(a0 * a0 + a1 * a1 + a2 * a2 + a3 * a3) * (1.f / 256.f);
  float rs = __builtin_amdgcn_rsqf(var + 1e-5f);
  float4 gg = *reinterpret_cast<const float4*>(&g[lane * 4]);
  float4 bq = *reinterpret_cast<const float4*>(&bb[lane * 4]);
  union { __hip_bfloat16 h[4]; short4 s4; } u;
  u.h[0] = __float2bfloat16(a0 * rs * gg.x + bq.x);
  u.h[1] = __float2bfloat16(a1 * rs * gg.y + bq.y);
  u.h[2] = __float2bfloat16(a2 * rs * gg.z + bq.z);
  u.h[3] = __float2bfloat16(a3 * rs * gg.w + bq.w);
  reinterpret_cast<short4*>(outb)[row * 64 + lane] = u.s4;
}

// ---------------------------------------------------------------------------
__global__ __launch_bounds__(256) void final_k(
    const __hip_bfloat16* __restrict__ t2, const float* __restrict__ g2v,
    const float* __restrict__ b2v, const float* __restrict__ g3v,
    const float* __restrict__ b3v, const float* __restrict__ x,
    float* __restrict__ out) {
  int bx = xcdswz_(blockIdx.x, gridDim.x);
  int half = bx & 1, nv = (bx >> 1) & 31, b = bx >> 6;
  int wave = threadIdx.x >> 6, lane = threadIdx.x & 63;
  __shared__ float sh[32][257];
  float4 gg2 = *reinterpret_cast<const float4*>(&g2v[lane * 4]);
  float4 bb2 = *reinterpret_cast<const float4*>(&b2v[lane * 4]);
  float4 gg3 = *reinterpret_cast<const float4*>(&g3v[lane * 4]);
  float4 bb3 = *reinterpret_cast<const float4*>(&b3v[lane * 4]);
#pragma unroll
  for (int i = 0; i < 8; ++i) {
    int pn = wave * 8 + i;
    int r = ((b * 32 + nv) << 6) + (half << 5) + pn;
    union { short4 s4; __hip_bfloat16 h[4]; } iv;
    iv.s4 = reinterpret_cast<const short4*>(t2)[r * 64 + lane];
    float v0 = __bfloat162float(iv.h[0]), v1 = __bfloat162float(iv.h[1]);
    float v2 = __bfloat162float(iv.h[2]), v3 = __bfloat162float(iv.h[3]);
    float mu = wsum_(v0 + v1 + v2 + v3) * (1.f / 256.f);
    float a0 = v0 - mu, a1 = v1 - mu, a2 = v2 - mu, a3 = v3 - mu;
    float var = wsum_(a0 * a0 + a1 * a1 + a2 * a2 + a3 * a3) * (1.f / 256.f);
    float rs = __builtin_amdgcn_rsqf(var + 1e-5f);
    a0 = a0 * rs * gg2.x + bb2.x; a1 = a1 * rs * gg2.y + bb2.y;
    a2 = a2 * rs * gg2.z + bb2.z; a3 = a3 * rs * gg2.w + bb2.w;
    mu = wsum_(a0 + a1 + a2 + a3) * (1.f / 256.f);
    float c0 = a0 - mu, c1 = a1 - mu, c2 = a2 - mu, c3 = a3 - mu;
    var = wsum_(c0 * c0 + c1 * c1 + c2 * c2 + c3 * c3) * (1.f / 256.f);
    rs = __builtin_amdgcn_rsqf(var + 1e-5f);
    sh[pn][lane * 4 + 0] = c0 * rs * gg3.x + bb3.x;
    sh[pn][lane * 4 + 1] = c1 * rs * gg3.y + bb3.y;
    sh[pn][lane * 4 + 2] = c2 * rs * gg3.z + bb3.z;
    sh[pn][lane * 4 + 3] = c3 * rs * gg3.w + bb3.w;
  }
  __syncthreads();
  int pnl = threadIdx.x & 31;
  int dbase = threadIdx.x >> 5;
  size_t obase = (size_t)((b * 32 + nv) * 256) * 64 + (half << 5) + pnl;
#pragma unroll
  for (int k = 0; k < 32; ++k) {
    int dd = dbase + (k << 3);
    size_t oi = obase + (size_t)dd * 64;
    out[oi] = sh[pnl][dd] + x[oi];
  }
}

// ---------------------------------------------------------------------------
extern "C" void kernel_launch(void* const* d_in, const int* in_sizes, int n_in,
                              void* d_out, int out_size, void* d_ws,
                              size_t ws_size, hipStream_t stream) {
  const float* x    = (const float*)d_in[0];
  const float* w_in = (const float*)d_in[1];
  const float* b_in = (const float*)d_in[2];
  const float* cw   = (const float*)d_in[3];
  const float* cb   = (const float*)d_in[4];
  const float* wx   = (const float*)d_in[5];
  const float* wdt  = (const float*)d_in[6];
  const float* bdt  = (const float*)d_in[7];
  const float* alog = (const float*)d_in[8];
  const float* Dp   = (const float*)d_in[9];
  const float* wout = (const float*)d_in[10];
  const float* g1   = (const float*)d_in[11];
  const float* b1   = (const float*)d_in[12];
  const float* wf1  = (const float*)d_in[13];
  const float* bf1  = (const float*)d_in[14];
  const float* wf2  = (const float*)d_in[15];
  const float* bf2  = (const float*)d_in[16];
  const float* g2   = (const float*)d_in[17];
  const float* b2   = (const float*)d_in[18];
  const float* g3   = (const float*)d_in[19];
  const float* b3   = (const float*)d_in[20];
  float* out = (float*)d_out;

  const size_t MB1 = 1048576;
  char* g = (char*)d_ws;
  __hip_bfloat16* wbf_in  = (__hip_bfloat16*)(g);              // 512 KB
  __hip_bfloat16* wbf_out = (__hip_bfloat16*)(g + 524288);     // 256 KB
  __hip_bfloat16* wbf_f1  = (__hip_bfloat16*)(g + 786432);     // 256 KB
  __hip_bfloat16* wbf_f2  = (__hip_bfloat16*)(g + 1048576);    // 256 KB
  __hip_bfloat16* wbf_xp  = (__hip_bfloat16*)(g + 1310720);    // 128 KB
  const size_t SHARED = 1572864;

  // Regions/batch: RA 4MB (xz|t2b) | RB 1MB (xbf|dlsum) | RC 2MB (xi|ffny)
  //   RD 384KB (xdbl) | RE 2MB (hp bf16 | resb+h1bf) | RF 2MB (deltab)
  const size_t PB = 11 * MB1 + 393216;  // 11,927,552 B/batch
  int nb = (int)((ws_size - SHARED) / PB);
  if (ws_size <= SHARED || nb < 1) return;
  if (nb > NBTOT) nb = NBTOT;

  dim3 blk(256);
  cast_bf16_k<<<dim3(256), blk, 0, stream>>>(w_in, wbf_in, 65536);
  cast_bf16_k<<<dim3(128), blk, 0, stream>>>(wout, wbf_out, 32768);
  cast_bf16_k<<<dim3(128), blk, 0, stream>>>(wf1, wbf_f1, 32768);
  cast_bf16_k<<<dim3(128), blk, 0, stream>>>(wf2, wbf_f2, 32768);
  pad_wx_k<<<dim3(64), blk, 0, stream>>>(wx, wbf_xp);

  for (int b0 = 0; b0 < NBTOT; b0 += nb) {
    int bn = (NBTOT - b0 < nb) ? (NBTOT - b0) : nb;
    char* base = g + SHARED;
    char* RA = base;                          // bn*4MB
    char* RB = base + (size_t)bn * 4 * MB1;   // bn*1MB
    char* RC = base + (size_t)bn * 5 * MB1;   // bn*2MB
    char* RD = base + (size_t)bn * 7 * MB1;   // bn*384KB
    char* RE = RD + (size_t)bn * 393216;      // bn*2MB
    char* RF = RE + (size_t)bn * 2 * MB1;     // bn*2MB

    __hip_bfloat16* xz     = (__hip_bfloat16*)RA;
    __hip_bfloat16* t2b    = (__hip_bfloat16*)RA;
    __hip_bfloat16* xbf    = (__hip_bfloat16*)RB;
    float*          dlsum  = (float*)RB;
    __hip_bfloat16* xibf   = (__hip_bfloat16*)RC;
    __hip_bfloat16* ffnybf = (__hip_bfloat16*)RC;
    float*          xdbl   = (float*)RD;
    __hip_bfloat16* hp     = (__hip_bfloat16*)RE;   // Hc in-place (bf16)
    __hip_bfloat16* resb   = (__hip_bfloat16*)RE;   // after scan
    __hip_bfloat16* h1bf   = (__hip_bfloat16*)(RE + (size_t)bn * MB1);
    __hip_bfloat16* deltab = (__hip_bfloat16*)RF;

    const float* xg = x + (size_t)b0 * SEQ * 256;
    float* outg = out + (size_t)b0 * SEQ * 256;
    int M = bn * SEQ;
    int MT = M / 128;

    cast_bf16_k<<<dim3(M * 64 / 256), blk, 0, stream>>>(xg, xbf, M * 64);
    // in_proj (N=1024, NT=8) -> xz bf16
    gemm_bf16<true, false, false, false, false, true, 3>
        <<<dim3(8 * MT), blk, 0, stream>>>(xbf, wbf_in, b_in, nullptr, nullptr,
                                           nullptr, xz, 1024, 256);
    conv_silu_k<<<dim3(M / 4), blk, 0, stream>>>(xz, cw, cb, xibf);
    // x_proj (N=48 padded, NT=1) -> xdbl f32
    gemm_bf16<false, false, false, false, true, false, 0>
        <<<dim3(MT), blk, 0, stream>>>(xibf, wbf_xp, nullptr, nullptr,
                                       nullptr, xdbl, nullptr, 48, 512);
    scan_p1<<<dim3(bn * 128), blk, 0, stream>>>(xibf, xdbl, alog, wdt, bdt,
                                                dlsum, hp, deltab);
    scan_p2<<<dim3(bn * 32), blk, 0, stream>>>(hp, dlsum, alog);
    scan_p3<<<dim3(bn * 128), blk, 0, stream>>>(xibf, alog, deltab, xdbl,
                                                hp, Dp, xz, xibf);
    // out_proj + residual(x f32) -> resb bf16 (N=256, NT=2)
    gemm_bf16<false, false, true, false, false, true, 1>
        <<<dim3(2 * MT), blk, 0, stream>>>(xibf, wbf_out, nullptr, xg, nullptr,
                                           nullptr, resb, 256, 512);
    ln_k<<<dim3(M / 4), blk, 0, stream>>>(resb, g1, b1, h1bf);
    // ffn1 + relu (N=512, NT=4) -> ffnybf
    gemm_bf16<true, true, false, false, false, true, 2>
        <<<dim3(4 * MT), blk, 0, stream>>>(h1bf, wbf_f1, bf1, nullptr, nullptr,
                                           nullptr, ffnybf, 512, 256);
    // ffn2 + bias + residual(h1 bf16) -> t2b bf16 (N=256, NT=2)
    gemm_bf16<true, false, false, true, false, true, 1>
        <<<dim3(2 * MT), blk, 0, stream>>>(ffnybf, wbf_f2, bf2, nullptr, h1bf,
                                           nullptr, t2b, 256, 512);
    final_k<<<dim3(bn * 64), blk, 0, stream>>>(t2b, g2, b2, g3, b3, xg, outg);
  }
}